// Round 14
// baseline (602.681 us; speedup 1.0000x reference)
//
#include <hip/hip_runtime.h>
#include <math.h>

#define NZc     64
#define EMBEDc  256
#define DMc     256
#define NHc     16
#define HDc     16
#define DFFc    1024
#define NLc     6
#define E1Dc    32
#define PDIMc   64
#define PMAXLc  24
#define NBINSc  49
#define NB      8
#define Lc      512
#define NTOK    (NB * Lc)        // 4096
#define UMDIM   (EMBEDc + E1Dc)  // 288

typedef __attribute__((ext_vector_type(4))) float f4;
typedef __attribute__((ext_vector_type(8))) short bf8;   // 8 bf16 in 4 VGPRs

#define MFMA(a, b, c) __builtin_amdgcn_mfma_f32_16x16x32_bf16((a), (b), (c), 0, 0, 0)

__device__ __forceinline__ short f2bf(float f) {
    unsigned u = __float_as_uint(f);
    u += 0x7FFFu + ((u >> 16) & 1u);   // round-to-nearest-even
    return (short)(u >> 16);
}
__device__ __forceinline__ float bf2f(short s) {
    return __uint_as_float(((unsigned)(unsigned short)s) << 16);
}

// ---------------------------------------------------------------------------
// preamble: weight conversions (x8 vectorized) + bias bins + e_aa + z^T.
__global__ void k_pre(const float* __restrict__ Wq, const float* __restrict__ Wk,
                      const float* __restrict__ Wv, const float* __restrict__ Wo,
                      const float* __restrict__ Wf1, const float* __restrict__ Wf2,
                      const float* __restrict__ exw1, const float* __restrict__ exw2,
                      const float* __restrict__ ow1,
                      const float* __restrict__ pos_emb, const float* __restrict__ W2d,
                      const float* __restrict__ b2d, const float* __restrict__ x,
                      const float* __restrict__ aa_emb, const float* __restrict__ z,
                      short* __restrict__ wqkv_hi, short* __restrict__ wqkv_lo,
                      short* __restrict__ wo_hi, short* __restrict__ wo_lo,
                      short* __restrict__ wf1_hi, short* __restrict__ wf1_lo,
                      short* __restrict__ wf2_hi, short* __restrict__ wf2_lo,
                      short* __restrict__ wex1_hi, short* __restrict__ wex1_lo,
                      short* __restrict__ wex2_hi, short* __restrict__ wex2_lo,
                      short* __restrict__ wo1_hi, short* __restrict__ wo1_lo,
                      float* __restrict__ bb,
                      short* __restrict__ umhi, short* __restrict__ umlo,
                      short* __restrict__ zth, short* __restrict__ ztl) {
    int stride = gridDim.x * blockDim.x;
    int tid = blockIdx.x * blockDim.x + threadIdx.x;
#define CVT(src, hi, lo, per_layer, dstride, doff, scale, total)               \
    for (int i = tid; i < (total) / 8; i += stride) {                          \
        int ib = i * 8;                                                        \
        int ll = ib / (per_layer), rels = ib - ll * (per_layer);               \
        size_t di = (size_t)ll * (dstride) + (doff) + rels;                    \
        f4 v0 = *(const f4*)(src + ib);                                        \
        f4 v1 = *(const f4*)(src + ib + 4);                                    \
        bf8 hv, lv;                                                            \
        _Pragma("unroll")                                                      \
        for (int q = 0; q < 4; ++q) {                                          \
            float v = v0[q] * (scale);                                         \
            short hh = f2bf(v);                                                \
            hv[q] = hh;                                                        \
            lv[q] = f2bf(v - bf2f(hh));                                        \
        }                                                                      \
        _Pragma("unroll")                                                      \
        for (int q = 0; q < 4; ++q) {                                          \
            float v = v1[q] * (scale);                                         \
            short hh = f2bf(v);                                                \
            hv[q + 4] = hh;                                                    \
            lv[q + 4] = f2bf(v - bf2f(hh));                                    \
        }                                                                      \
        *(bf8*)(hi + di) = hv;                                                 \
        *(bf8*)(lo + di) = lv;                                                 \
    }
    CVT(Wq,  wqkv_hi, wqkv_lo, 65536, 196608, 0,      0.0625f, 393216);
    CVT(Wk,  wqkv_hi, wqkv_lo, 65536, 196608, 65536,  1.f,     393216);
    CVT(Wv,  wqkv_hi, wqkv_lo, 65536, 196608, 131072, 1.f,     393216);
    CVT(Wo,  wo_hi,  wo_lo,  65536,  65536,  0, 1.f, 393216);
    CVT(Wf1, wf1_hi, wf1_lo, 294912, 294912, 0, 1.f, 1769472);
    CVT(Wf2, wf2_hi, wf2_lo, 262144, 262144, 0, 1.f, 1572864);
    CVT(exw1, wex1_hi, wex1_lo, 16384, 16384, 0, 1.f, 16384);
    CVT(exw2, wex2_hi, wex2_lo, 65536, 65536, 0, 1.f, 65536);
    CVT(ow1,  wo1_hi,  wo1_lo,  65536, 65536, 0, 1.f, 65536);
#undef CVT
    for (int idx = tid; idx < NLc * NHc * NBINSc; idx += stride) {
        int bin = idx % NBINSc;
        int tmp = idx / NBINSc;
        int hh = tmp % NHc, l = tmp / NHc;
        float s = b2d[l * NHc + hh];
        const float* pe = pos_emb + bin * PDIMc;
        const float* w  = W2d + (l * NHc + hh) * PDIMc;
        for (int p = 0; p < PDIMc; ++p) s += pe[p] * w[p];
        bb[idx] = s;
    }
    for (int tok = tid; tok < NTOK; tok += stride) {
        int n = tok / Lc, l = tok % Lc;
        const float* xp = x + (size_t)n * 20 * Lc + l;
        float best = xp[0];
        int bi = 0;
        for (int c = 1; c < 20; ++c) {
            float v = xp[c * Lc];
            if (v > best) { best = v; bi = c; }
        }
        const float* e = aa_emb + bi * E1Dc;
        bf8 hv, lv;
        for (int c8 = 0; c8 < E1Dc / 8; ++c8) {
#pragma unroll
            for (int q = 0; q < 8; ++q) {
                float v = e[c8 * 8 + q];
                short hh = f2bf(v);
                hv[q] = hh;
                lv[q] = f2bf(v - bf2f(hh));
            }
            *(bf8*)(umhi + (size_t)tok * UMDIM + EMBEDc + c8 * 8) = hv;
            *(bf8*)(umlo + (size_t)tok * UMDIM + EMBEDc + c8 * 8) = lv;
        }
    }
    for (int tok = tid; tok < NTOK; tok += stride) {
        int n = tok >> 9, l = tok & 511;
        bf8 hv, lv;
        for (int c8 = 0; c8 < NZc / 8; ++c8) {
#pragma unroll
            for (int q = 0; q < 8; ++q) {
                float v = z[((size_t)n * NZc + c8 * 8 + q) * Lc + l];
                short hh = f2bf(v);
                hv[q] = hh;
                lv[q] = f2bf(v - bf2f(hh));
            }
            *(bf8*)(zth + (size_t)tok * NZc + c8 * 8) = hv;
            *(bf8*)(ztl + (size_t)tok * NZc + c8 * 8) = lv;
        }
    }
}

// ---------------------------------------------------------------------------
// LDS-staged MFMA GEMM (unchanged)
template <int EPI, int MF, int SKSHIFT, int BK>
__global__ __launch_bounds__(256) void k_gemm3(
    const short* __restrict__ Ahi, const short* __restrict__ Alo, int lda,
    const short* __restrict__ Bhi, const short* __restrict__ Blo, int ldb,
    int K, float* __restrict__ outf, int ldo, short* __restrict__ ohi,
    short* __restrict__ olo, int ldh, const float* __restrict__ bias,
    int gx, int gypx) {
    constexpr int PAD = BK + 8;
    __shared__ __align__(16) short Ah[MF * 64][PAD];
    __shared__ __align__(16) short Al[MF * 64][PAD];
    __shared__ __align__(16) short Bh[64][PAD];
    __shared__ __align__(16) short Bl[64][PAD];

    int bid = blockIdx.x;
    int koff = 0;
    if (SKSHIFT) {
        int kh = bid >> SKSHIFT;
        bid &= (1 << SKSHIFT) - 1;
        koff = kh * K;
        outf += (size_t)kh * NTOK * EMBEDc;
    }
    int xcd = bid & 7, j = bid >> 3;
    int bx = j % gx, by = xcd * gypx + j / gx;

    int t = threadIdx.x;
    int w = t >> 6, l = t & 63, lr = l & 15, lk = l >> 4;
    int m0 = by * (MF * 64);
    int n0 = bx * 64;

    constexpr int TPR = BK / 8;
    constexpr int RP  = 256 / TPR;
    constexpr int AP  = MF * 64 / RP;
    constexpr int BP  = 64 / RP;
    int srow = t / TPR, scol = (t % TPR) * 8;

    const short* pa  = Ahi + (size_t)(m0 + srow) * lda + koff + scol;
    const short* pal = Alo + (size_t)(m0 + srow) * lda + koff + scol;
    const short* pb  = Bhi + (size_t)(n0 + srow) * ldb + koff + scol;
    const short* pbl = Blo + (size_t)(n0 + srow) * ldb + koff + scol;

    bf8 ra[AP], rla[AP], rb[BP], rlb[BP];
#pragma unroll
    for (int p = 0; p < AP; ++p) {
        ra[p]  = *(const bf8*)(pa  + (size_t)p * RP * lda);
        rla[p] = *(const bf8*)(pal + (size_t)p * RP * lda);
    }
#pragma unroll
    for (int p = 0; p < BP; ++p) {
        rb[p]  = *(const bf8*)(pb  + (size_t)p * RP * ldb);
        rlb[p] = *(const bf8*)(pbl + (size_t)p * RP * ldb);
    }

    f4 acc[MF][4];
#pragma unroll
    for (int mf = 0; mf < MF; ++mf)
#pragma unroll
        for (int nf = 0; nf < 4; ++nf) acc[mf][nf] = (f4){0.f, 0.f, 0.f, 0.f};

    for (int ks = 0; ks < K; ks += BK) {
        __syncthreads();
#pragma unroll
        for (int p = 0; p < AP; ++p) {
            *(bf8*)&Ah[p * RP + srow][scol] = ra[p];
            *(bf8*)&Al[p * RP + srow][scol] = rla[p];
        }
#pragma unroll
        for (int p = 0; p < BP; ++p) {
            *(bf8*)&Bh[p * RP + srow][scol] = rb[p];
            *(bf8*)&Bl[p * RP + srow][scol] = rlb[p];
        }
        __syncthreads();
        if (ks + BK < K) {
#pragma unroll
            for (int p = 0; p < AP; ++p) {
                ra[p]  = *(const bf8*)(pa  + (size_t)p * RP * lda + ks + BK);
                rla[p] = *(const bf8*)(pal + (size_t)p * RP * lda + ks + BK);
            }
#pragma unroll
            for (int p = 0; p < BP; ++p) {
                rb[p]  = *(const bf8*)(pb  + (size_t)p * RP * ldb + ks + BK);
                rlb[p] = *(const bf8*)(pbl + (size_t)p * RP * ldb + ks + BK);
            }
        }
#pragma unroll
        for (int kc = 0; kc < BK / 32; ++kc) {
            bf8 bhf[4], blf[4];
#pragma unroll
            for (int nf = 0; nf < 4; ++nf) {
                bhf[nf] = *(const bf8*)&Bh[nf * 16 + lr][kc * 32 + lk * 8];
                blf[nf] = *(const bf8*)&Bl[nf * 16 + lr][kc * 32 + lk * 8];
            }
#pragma unroll
            for (int mf = 0; mf < MF; ++mf) {
                bf8 ah = *(const bf8*)&Ah[w * MF * 16 + mf * 16 + lr][kc * 32 + lk * 8];
                bf8 al = *(const bf8*)&Al[w * MF * 16 + mf * 16 + lr][kc * 32 + lk * 8];
#pragma unroll
                for (int nf = 0; nf < 4; ++nf) {
                    acc[mf][nf] = MFMA(ah, bhf[nf], acc[mf][nf]);
                    acc[mf][nf] = MFMA(ah, blf[nf], acc[mf][nf]);
                    acc[mf][nf] = MFMA(al, bhf[nf], acc[mf][nf]);
                }
            }
        }
    }

#pragma unroll
    for (int mf = 0; mf < MF; ++mf) {
#pragma unroll
        for (int nf = 0; nf < 4; ++nf) {
            int n = n0 + nf * 16 + lr;
            int mbase = m0 + w * MF * 16 + mf * 16 + lk * 4;
            if (EPI == 0) {
#pragma unroll
                for (int r = 0; r < 4; ++r)
                    outf[(size_t)(mbase + r) * ldo + n] = acc[mf][nf][r];
            } else if (EPI == 1) {
                float bv = bias[n];
#pragma unroll
                for (int r = 0; r < 4; ++r) {
                    float y = fmaxf(acc[mf][nf][r] + bv, 0.f);
                    short hv = f2bf(y);
                    size_t oi = (size_t)(mbase + r) * ldh + n;
                    ohi[oi] = hv;
                    olo[oi] = f2bf(y - bf2f(hv));
                }
            } else if (EPI == 2) {
#pragma unroll
                for (int r = 0; r < 4; ++r) {
                    float y = acc[mf][nf][r];
                    short hv = f2bf(y);
                    size_t oi = (size_t)(mbase + r) * ldh + n;
                    ohi[oi] = hv;
                    olo[oi] = f2bf(y - bf2f(hv));
                }
            } else {
                float bv = bias[n];
#pragma unroll
                for (int r = 0; r < 4; ++r) {
                    float y = acc[mf][nf][r] + bv;
                    outf[(size_t)(mbase + r) * ldo + n] = y;
                    short hv = f2bf(y);
                    size_t oi = (size_t)(mbase + r) * ldh + n;
                    ohi[oi] = hv;
                    olo[oi] = f2bf(y - bf2f(hv));
                }
            }
        }
    }
}

// ---------------------------------------------------------------------------
// MFMA flash attention, key-split x2: 512 thr = 8 waves = 4 q-groups x 2
// key-halves. K read direct from global (L2-resident); V staged transposed in
// LDS (33.3 KB) + merge buffer (6 KB) -> 4 blocks/CU = 32 waves/CU, grid 1024.
__global__ __launch_bounds__(512, 8) void k_attn(const short* __restrict__ qh,
                                                 const short* __restrict__ ql,
                                                 const float* __restrict__ bb,
                                                 short* __restrict__ ohi,
                                                 short* __restrict__ olo) {
    int bx = blockIdx.x;
    int qt = bx >> 7;            // 0..7; blocks sharing (n,head) same XCD
    int head = bx & 15;
    int n = (bx >> 4) & 7;
    int t = threadIdx.x;
    int w = t >> 6, l = t & 63;
    int qgrp = w >> 1, s = w & 1;    // 4 q-groups x 2 key-split waves
    int lq = l & 15, lk = l >> 4;

    __shared__ __align__(16) short vth[16][520];   // V^T hi: [d][key 0..511]
    __shared__ __align__(16) short vtl[16][520];   // V^T lo
    __shared__ float mrg[4][64][6];                // per-qgroup merge: m,l,acc4
    __shared__ float biasr[64];

    if (t < NBINSc) biasr[t] = bb[head * NBINSc + t];
    float bL = bb[head * NBINSc];
    float bR = bb[head * NBINSc + 48];

    size_t base = (size_t)n * Lc * 768 + head * 16;

    // stage full V transposed, pair-packed b32 writes (2 items/thread)
    for (int v = t; v < 1024; v += 512) {
        int u = v & 255;             // key pair -> keys 2u, 2u+1
        int dhalf = (v >> 8) & 1;    // d 0..7 / 8..15
        int hl = (v >> 9) & 1;       // hi / lo
        const short* vs = (hl ? ql : qh) + base + 512 + (size_t)(u * 2) * 768 + dhalf * 8;
        bf8 A = *(const bf8*)vs;
        bf8 B = *(const bf8*)(vs + 768);
        unsigned* vw = (unsigned*)(hl ? &vtl[0][0] : &vth[0][0]);  // row stride 260 words
#pragma unroll
        for (int i = 0; i < 8; ++i)
            vw[(dhalf * 8 + i) * 260 + u] =
                (unsigned)(unsigned short)A[i] | ((unsigned)(unsigned short)B[i] << 16);
    }
    __syncthreads();

    int qg = qt * 64 + qgrp * 16 + lq;           // this lane's q column
    size_t qrow = ((size_t)n * Lc + qg) * 768 + head * 16;
    bf8 B1 = *(const bf8*)(qh + qrow + (lk & 1) * 8);   // [Qh|Qh]
    bf8 B2;
    if (lk < 2) B2 = *(const bf8*)(ql + qrow + lk * 8);  // [Ql|0]
    else {
#pragma unroll
        for (int i = 0; i < 8; ++i) B2[i] = 0;
    }

    // direct-global K fragment pointer (L2-resident); per tile += 16*768
    const short* kptr = (lk < 2 ? qh : ql) + base + 256
                      + (size_t)(s * 256 + lq) * 768 + (lk & 1) * 8;

    f4 acc = (f4){0.f, 0.f, 0.f, 0.f};
    float m = -1e30f, lsum = 0.f;
    int rel0 = s * 256 + lk * 4 - qg;   // rel of s[0] at kt=0; += 16 per tile

    bf8 A1 = *(const bf8*)kptr;         // prefetch tile 0
    for (int kt = 0; kt < 16; ++kt, rel0 += 16) {
        bf8 Acur = A1;
        if (kt < 15) A1 = *(const bf8*)(kptr + (size_t)(kt + 1) * 16 * 768);
        f4 sv = (f4){0.f, 0.f, 0.f, 0.f};
        __builtin_amdgcn_s_setprio(1);
        sv = MFMA(Acur, B1, sv);    // KhQh + KlQh
        sv = MFMA(Acur, B2, sv);    // KhQl
        __builtin_amdgcn_s_setprio(0);
        if (rel0 >= PMAXLc) {
            sv[0] += bR; sv[1] += bR; sv[2] += bR; sv[3] += bR;
        } else if (rel0 + 3 <= -PMAXLc) {
            sv[0] += bL; sv[1] += bL; sv[2] += bL; sv[3] += bL;
        } else {
#pragma unroll
            for (int r = 0; r < 4; ++r) {
                int rel = rel0 + r;
                rel = rel < -PMAXLc ? -PMAXLc : (rel > PMAXLc ? PMAXLc : rel);
                sv[r] += biasr[rel + PMAXLc];
            }
        }
        float mt = fmaxf(fmaxf(sv[0], sv[1]), fmaxf(sv[2], sv[3]));
        mt = fmaxf(mt, __shfl_xor(mt, 16));
        mt = fmaxf(mt, __shfl_xor(mt, 32));
        if (__any(mt > m + 8.0f)) {
            float mn = fmaxf(m, mt);
            float alpha = __expf(m - mn);
            m = mn;
            lsum *= alpha;
#pragma unroll
            for (int r = 0; r < 4; ++r) acc[r] *= __shfl(alpha, lk * 4 + r);
        }
        f4 p;
#pragma unroll
        for (int r = 0; r < 4; ++r) p[r] = __expf(sv[r] - m);
        lsum += p[0] + p[1] + p[2] + p[3];
        int src0 = (lk & 1) * 32 + lq;
        int src1 = src0 + 16;
        float g[8];
#pragma unroll
        for (int jj = 0; jj < 4; ++jj) {
            g[jj]     = __shfl(p[jj], src0);
            g[jj + 4] = __shfl(p[jj], src1);
        }
        bf8 PA;
        if (lk < 2) {
#pragma unroll
            for (int jj = 0; jj < 8; ++jj)
                PA[jj] = (short)(__float_as_uint(g[jj]) >> 16);
        } else {
#pragma unroll
            for (int jj = 0; jj < 8; ++jj) {
                unsigned hu = __float_as_uint(g[jj]) & 0xFFFF0000u;
                PA[jj] = (short)(__float_as_uint(g[jj] - __uint_as_float(hu)) >> 16);
            }
        }
        int vkey = s * 256 + kt * 16;
        bf8 VB1 = *(const bf8*)&vth[lq][vkey + (lk & 1) * 8];  // [Vh|Vh]
        bf8 VB2;
        if (lk < 2) VB2 = *(const bf8*)&vtl[lq][vkey + lk * 8];  // [Vl|0]
        else {
#pragma unroll
            for (int i = 0; i < 8; ++i) VB2[i] = 0;
        }
        __builtin_amdgcn_s_setprio(1);
        acc = MFMA(PA, VB1, acc);   // PhVh + PlVh
        acc = MFMA(PA, VB2, acc);   // PhVl
        __builtin_amdgcn_s_setprio(0);
    }

    // per-wave l reduction (per-q totals replicated across lk)
    float lred = lsum + __shfl_xor(lsum, 16);
    lred += __shfl_xor(lred, 32);

    // merge the two key-split waves of this q-group
    if (s == 1) {
        mrg[qgrp][l][0] = m;
        mrg[qgrp][l][1] = lred;
        mrg[qgrp][l][2] = acc[0];
        mrg[qgrp][l][3] = acc[1];
        mrg[qgrp][l][4] = acc[2];
        mrg[qgrp][l][5] = acc[3];
    }
    __syncthreads();
    if (s == 0) {
        float m1 = mrg[qgrp][l][0];
        float l1 = mrg[qgrp][l][1];
        float mm = fmaxf(m, m1);
        float sc0 = __expf(m - mm);
        float sc1 = __expf(m1 - mm);
        float ltot = lred * sc0 + l1 * sc1;
        float inv = 1.0f / ltot;
#pragma unroll
        for (int r = 0; r < 4; ++r) {
            float s0r = __shfl(sc0, lk * 4 + r);
            float s1r = __shfl(sc1, lk * 4 + r);
            float iq  = __shfl(inv, lk * 4 + r);
            float a1v = mrg[qgrp][l][2 + r];
            float y = (acc[r] * s0r + a1v * s1r) * iq;
            int qo = qt * 64 + qgrp * 16 + lk * 4 + r;
            size_t oi = ((size_t)n * Lc + qo) * DMc + head * 16 + lq;
            unsigned hu = __float_as_uint(y) & 0xFFFF0000u;
            ohi[oi] = (short)(hu >> 16);
            olo[oi] = (short)(__float_as_uint(y - __uint_as_float(hu)) >> 16);
        }
    }
}

// ---------------------------------------------------------------------------
// LN over h + s2a + s2b + sbias, fully f4-vectorized.
__global__ __launch_bounds__(256) void k_ln(const float* __restrict__ s2a,
                                            const float* __restrict__ s2b,
                                            const float* __restrict__ sbias,
                                            const float* __restrict__ g,
                                            const float* __restrict__ bta,
                                            float* __restrict__ h,
                                            short* __restrict__ umhi,
                                            short* __restrict__ umlo) {
    int t = threadIdx.x;
    int tl = t >> 5, j = t & 31;
    size_t gtok = (size_t)blockIdx.x * 8 + tl;
    int d0 = j * 8;
    size_t off = gtok * EMBEDc + d0;
    f4 h0 = *(const f4*)(h + off);
    f4 h1 = *(const f4*)(h + off + 4);
    f4 a0 = *(const f4*)(s2a + off);
    f4 a1 = *(const f4*)(s2a + off + 4);
    f4 b0 = *(const f4*)(s2b + off);
    f4 b1 = *(const f4*)(s2b + off + 4);
    f4 sb0 = *(const f4*)(sbias + d0);
    f4 sb1 = *(const f4*)(sbias + d0 + 4);
    f4 v0 = h0 + a0 + b0 + sb0;
    f4 v1 = h1 + a1 + b1 + sb1;
    float sum = v0[0] + v0[1] + v0[2] + v0[3] + v1[0] + v1[1] + v1[2] + v1[3];
    float ssq = v0[0]*v0[0] + v0[1]*v0[1] + v0[2]*v0[2] + v0[3]*v0[3]
              + v1[0]*v1[0] + v1[1]*v1[1] + v1[2]*v1[2] + v1[3]*v1[3];
#pragma unroll
    for (int off5 = 16; off5; off5 >>= 1) {
        sum += __shfl_xor(sum, off5, 32);
        ssq += __shfl_xor(ssq, off5, 32);
    }
    float mean = sum * (1.f / EMBEDc);
    float var = ssq * (1.f / EMBEDc) - mean * mean;
    float inv = rsqrtf(var + 1e-5f);
    f4 g0 = *(const f4*)(g + d0);
    f4 g1 = *(const f4*)(g + d0 + 4);
    f4 t0 = *(const f4*)(bta + d0);
    f4 t1 = *(const f4*)(bta + d0 + 4);
    f4 y0, y1;
    bf8 hv, lv;
#pragma unroll
    for (int q = 0; q < 4; ++q) {
        float y = (v0[q] - mean) * inv * g0[q] + t0[q];
        y0[q] = y;
        short hh = f2bf(y);
        hv[q] = hh;
        lv[q] = f2bf(y - bf2f(hh));
    }
#pragma unroll
    for (int q = 0; q < 4; ++q) {
        float y = (v1[q] - mean) * inv * g1[q] + t1[q];
        y1[q] = y;
        short hh = f2bf(y);
        hv[q + 4] = hh;
        lv[q + 4] = f2bf(y - bf2f(hh));
    }
    *(f4*)(h + off) = y0;
    *(f4*)(h + off + 4) = y1;
    *(bf8*)(umhi + gtok * UMDIM + d0) = hv;
    *(bf8*)(umlo + gtok * UMDIM + d0) = lv;
}

// ---------------------------------------------------------------------------
__global__ __launch_bounds__(256) void k_r(const short* __restrict__ fh,
                                           const short* __restrict__ fl,
                                           const float* __restrict__ w2,
                                           const float* __restrict__ b2,
                                           float* __restrict__ r) {
    __shared__ float w[3][EMBEDc];
    int t = threadIdx.x;
    for (int u = t; u < 3 * EMBEDc; u += 256) w[u >> 8][u & 255] = w2[u];
    __syncthreads();
    int tok = blockIdx.x * 64 + (t >> 2), o = t & 3;
    if (o < 3) {
        const short* ph = fh + (size_t)tok * EMBEDc;
        const short* pl = fl + (size_t)tok * EMBEDc;
        float s = b2[o];
        for (int c8 = 0; c8 < EMBEDc / 8; ++c8) {
            bf8 vh = *(const bf8*)(ph + c8 * 8);
            bf8 vl = *(const bf8*)(pl + c8 * 8);
#pragma unroll
            for (int j = 0; j < 8; ++j)
                s += (bf2f(vh[j]) + bf2f(vl[j])) * w[o][c8 * 8 + j];
        }
        r[(size_t)tok * 3 + o] = s;
    }
}

// ---------------------------------------------------------------------------
__global__ __launch_bounds__(256) void k_dmap(const float* __restrict__ r,
                                              float* __restrict__ d) {
    int b = blockIdx.x;
    int n = b / Lc;
    float xi = r[(size_t)b * 3], yi = r[(size_t)b * 3 + 1], zi = r[(size_t)b * 3 + 2];
    const float* rn = r + (size_t)n * Lc * 3;
    for (int j = threadIdx.x; j < Lc; j += 256) {
        float dx = xi - rn[j * 3];
        float dy = yi - rn[j * 3 + 1];
        float dz = zi - rn[j * 3 + 2];
        d[(size_t)b * Lc + j] = sqrtf(dx * dx + dy * dy + dz * dz + 1e-12f);
    }
}

// ---------------------------------------------------------------------------
extern "C" void kernel_launch(void* const* d_in, const int* in_sizes, int n_in,
                              void* d_out, int out_size, void* d_ws, size_t ws_size,
                              hipStream_t stream) {
    const float* z       = (const float*)d_in[0];
    const float* x       = (const float*)d_in[1];
    const float* pos_emb = (const float*)d_in[2];
    const float* aa_emb  = (const float*)d_in[3];
    const float* ex_w1   = (const float*)d_in[4];
    const float* ex_b1   = (const float*)d_in[5];
    const float* ex_w2   = (const float*)d_in[6];
    const float* ex_b2   = (const float*)d_in[7];
    const float* Wq      = (const float*)d_in[8];
    const float* Wk      = (const float*)d_in[9];
    const float* Wv      = (const float*)d_in[10];
    const float* Wo      = (const float*)d_in[11];
    const float* bo      = (const float*)d_in[12];
    const float* W2d     = (const float*)d_in[13];
    const float* b2d     = (const float*)d_in[14];
    const float* Wf1     = (const float*)d_in[15];
    const float* bf1     = (const float*)d_in[16];
    const float* Wf2     = (const float*)d_in[17];
    const float* bf2     = (const float*)d_in[18];
    const float* ln1_g   = (const float*)d_in[19];
    const float* ln1_b   = (const float*)d_in[20];
    const float* ln2_g   = (const float*)d_in[21];
    const float* ln2_b   = (const float*)d_in[22];
    const float* o_w1    = (const float*)d_in[23];
    const float* o_b1    = (const float*)d_in[24];
    const float* o_w2    = (const float*)d_in[25];
    const float* o_b2    = (const float*)d_in[26];

    float* h    = (float*)d_ws;                    // 4096*256
    float* s2a  = h + (size_t)NTOK * EMBEDc;
    float* s2b  = s2a + (size_t)NTOK * EMBEDc;
    float* bbuf = s2b + (size_t)NTOK * EMBEDc;     // pad 8192
    float* r    = bbuf + 8192;                     // pad 16384
    short* qkvh = (short*)(r + 16384);             // 4096*768
    short* qkvl = qkvh + (size_t)NTOK * 768;
    short* um_hi = qkvl + (size_t)NTOK * 768;      // 4096*288
    short* um_lo = um_hi + (size_t)NTOK * UMDIM;
    short* o_hi  = um_lo + (size_t)NTOK * UMDIM;   // 4096*256
    short* o_lo  = o_hi + (size_t)NTOK * EMBEDc;
    short* f1_hi = o_lo + (size_t)NTOK * EMBEDc;   // 4096*1024
    short* f1_lo = f1_hi + (size_t)NTOK * DFFc;
    short* wqkv_hi = f1_lo + (size_t)NTOK * DFFc;  // 6*768*256
    short* wqkv_lo = wqkv_hi + (size_t)NLc * 768 * EMBEDc;
    short* wo_hi   = wqkv_lo + (size_t)NLc * 768 * EMBEDc;   // 6*256*256
    short* wo_lo   = wo_hi + (size_t)NLc * EMBEDc * DMc;
    short* wf1_hi  = wo_lo + (size_t)NLc * EMBEDc * DMc;     // 6*1024*288
    short* wf1_lo  = wf1_hi + (size_t)NLc * DFFc * UMDIM;
    short* wf2_hi  = wf1_lo + (size_t)NLc * DFFc * UMDIM;    // 6*256*1024
    short* wf2_lo  = wf2_hi + (size_t)NLc * EMBEDc * DFFc;
    short* wex1_hi = wf2_lo + (size_t)NLc * EMBEDc * DFFc;   // 256*64
    short* wex1_lo = wex1_hi + EMBEDc * NZc;
    short* wex2_hi = wex1_lo + EMBEDc * NZc;                 // 256*256
    short* wex2_lo = wex2_hi + EMBEDc * EMBEDc;
    short* wo1_hi  = wex2_lo + EMBEDc * EMBEDc;              // 256*256
    short* wo1_lo  = wo1_hi + EMBEDc * EMBEDc;
    // zt aliases the o buffer (only used in preamble, before k_attn writes o)
    short* zt_hi = o_hi;
    short* zt_lo = o_lo;

    k_pre<<<1024, 256, 0, stream>>>(Wq, Wk, Wv, Wo, Wf1, Wf2, ex_w1, ex_w2, o_w1,
                                    pos_emb, W2d, b2d, x, aa_emb, z,
                                    wqkv_hi, wqkv_lo, wo_hi, wo_lo,
                                    wf1_hi, wf1_lo, wf2_hi, wf2_lo,
                                    wex1_hi, wex1_lo, wex2_hi, wex2_lo,
                                    wo1_hi, wo1_lo, bbuf, um_hi, um_lo,
                                    zt_hi, zt_lo);

    // embed: relu GEMM -> GEMM (fp32 h + bf16 um)
    k_gemm3<1, 1, 0, 64><<<256, 256, 0, stream>>>(
        zt_hi, zt_lo, NZc, wex1_hi, wex1_lo, NZc, NZc,
        nullptr, 0, f1_hi, f1_lo, EMBEDc, ex_b1, 4, 8);
    k_gemm3<3, 1, 0, 64><<<256, 256, 0, stream>>>(
        f1_hi, f1_lo, EMBEDc, wex2_hi, wex2_lo, EMBEDc, EMBEDc,
        h, EMBEDc, um_hi, um_lo, UMDIM, ex_b2, 4, 8);

    for (int l = 0; l < NLc; ++l) {
        k_gemm3<2, 2, 0, 64><<<384, 256, 0, stream>>>(
            um_hi, um_lo, UMDIM,
            wqkv_hi + (size_t)l * 768 * EMBEDc, wqkv_lo + (size_t)l * 768 * EMBEDc, EMBEDc,
            EMBEDc, nullptr, 0, qkvh, qkvl, 768, nullptr, 12, 4);
        k_attn<<<NB * NHc * 8, 512, 0, stream>>>(qkvh, qkvl, bbuf + (size_t)l * NHc * NBINSc, o_hi, o_lo);
        k_gemm3<0, 1, 8, 64><<<512, 256, 0, stream>>>(
            o_hi, o_lo, EMBEDc,
            wo_hi + (size_t)l * EMBEDc * DMc, wo_lo + (size_t)l * EMBEDc * DMc, DMc,
            128, s2a, EMBEDc, nullptr, nullptr, 0, nullptr, 4, 8);
        k_ln<<<NTOK / 8, 256, 0, stream>>>(s2a, s2b, bo + (size_t)l * EMBEDc,
                                           ln1_g + (size_t)l * EMBEDc, ln1_b + (size_t)l * EMBEDc,
                                           h, um_hi, um_lo);
        k_gemm3<1, 2, 0, 32><<<512, 256, 0, stream>>>(
            um_hi, um_lo, UMDIM,
            wf1_hi + (size_t)l * DFFc * UMDIM, wf1_lo + (size_t)l * DFFc * UMDIM, UMDIM,
            UMDIM, nullptr, 0, f1_hi, f1_lo, DFFc, bf1 + (size_t)l * DFFc, 16, 4);
        k_gemm3<0, 1, 8, 64><<<512, 256, 0, stream>>>(
            f1_hi, f1_lo, DFFc,
            wf2_hi + (size_t)l * EMBEDc * DFFc, wf2_lo + (size_t)l * EMBEDc * DFFc, DFFc,
            512, s2a, EMBEDc, nullptr, nullptr, 0, nullptr, 4, 8);
        k_ln<<<NTOK / 8, 256, 0, stream>>>(s2a, s2b, bf2 + (size_t)l * EMBEDc,
                                           ln2_g + (size_t)l * EMBEDc, ln2_b + (size_t)l * EMBEDc,
                                           h, um_hi, um_lo);
    }

    // final: f = relu(um @ o_w1^T + o_b1) (um cols 0..255 hold h in bf16)
    k_gemm3<1, 1, 0, 64><<<256, 256, 0, stream>>>(
        um_hi, um_lo, UMDIM, wo1_hi, wo1_lo, EMBEDc, EMBEDc,
        nullptr, 0, f1_hi, f1_lo, EMBEDc, o_b1, 4, 8);
    k_r<<<NTOK / 64, 256, 0, stream>>>(f1_hi, f1_lo, o_w2, o_b2, r);
    k_dmap<<<NB * Lc, 256, 0, stream>>>(r, (float*)d_out);
}

// Round 15
// 577.696 us; speedup vs baseline: 1.0433x; 1.0433x over previous
//
#include <hip/hip_runtime.h>
#include <math.h>

#define NZc     64
#define EMBEDc  256
#define DMc     256
#define NHc     16
#define HDc     16
#define DFFc    1024
#define NLc     6
#define E1Dc    32
#define PDIMc   64
#define PMAXLc  24
#define NBINSc  49
#define NB      8
#define Lc      512
#define NTOK    (NB * Lc)        // 4096
#define UMDIM   288              // logical um width
#define UMLD    320              // padded leading dim (zeros in 288..319)

typedef __attribute__((ext_vector_type(4))) float f4;
typedef __attribute__((ext_vector_type(8))) short bf8;   // 8 bf16 in 4 VGPRs

#define MFMA(a, b, c) __builtin_amdgcn_mfma_f32_16x16x32_bf16((a), (b), (c), 0, 0, 0)

__device__ __forceinline__ short f2bf(float f) {
    unsigned u = __float_as_uint(f);
    u += 0x7FFFu + ((u >> 16) & 1u);   // round-to-nearest-even
    return (short)(u >> 16);
}
__device__ __forceinline__ float bf2f(short s) {
    return __uint_as_float(((unsigned)(unsigned short)s) << 16);
}

// ---------------------------------------------------------------------------
// preamble: weight conversions (x8 vectorized) + bias bins + e_aa + z^T.
// Wf1 rows remapped 288 -> 320 stride; pad cols zero-filled (um + wf1).
__global__ void k_pre(const float* __restrict__ Wq, const float* __restrict__ Wk,
                      const float* __restrict__ Wv, const float* __restrict__ Wo,
                      const float* __restrict__ Wf1, const float* __restrict__ Wf2,
                      const float* __restrict__ exw1, const float* __restrict__ exw2,
                      const float* __restrict__ ow1,
                      const float* __restrict__ pos_emb, const float* __restrict__ W2d,
                      const float* __restrict__ b2d, const float* __restrict__ x,
                      const float* __restrict__ aa_emb, const float* __restrict__ z,
                      short* __restrict__ wqkv_hi, short* __restrict__ wqkv_lo,
                      short* __restrict__ wo_hi, short* __restrict__ wo_lo,
                      short* __restrict__ wf1_hi, short* __restrict__ wf1_lo,
                      short* __restrict__ wf2_hi, short* __restrict__ wf2_lo,
                      short* __restrict__ wex1_hi, short* __restrict__ wex1_lo,
                      short* __restrict__ wex2_hi, short* __restrict__ wex2_lo,
                      short* __restrict__ wo1_hi, short* __restrict__ wo1_lo,
                      float* __restrict__ bb,
                      short* __restrict__ umhi, short* __restrict__ umlo,
                      short* __restrict__ zth, short* __restrict__ ztl) {
    int stride = gridDim.x * blockDim.x;
    int tid = blockIdx.x * blockDim.x + threadIdx.x;
#define CVT(src, hi, lo, per_layer, dstride, doff, scale, total)               \
    for (int i = tid; i < (total) / 8; i += stride) {                          \
        int ib = i * 8;                                                        \
        int ll = ib / (per_layer), rels = ib - ll * (per_layer);               \
        size_t di = (size_t)ll * (dstride) + (doff) + rels;                    \
        f4 v0 = *(const f4*)(src + ib);                                        \
        f4 v1 = *(const f4*)(src + ib + 4);                                    \
        bf8 hv, lv;                                                            \
        _Pragma("unroll")                                                      \
        for (int q = 0; q < 4; ++q) {                                          \
            float v = v0[q] * (scale);                                         \
            short hh = f2bf(v);                                                \
            hv[q] = hh;                                                        \
            lv[q] = f2bf(v - bf2f(hh));                                        \
        }                                                                      \
        _Pragma("unroll")                                                      \
        for (int q = 0; q < 4; ++q) {                                          \
            float v = v1[q] * (scale);                                         \
            short hh = f2bf(v);                                                \
            hv[q + 4] = hh;                                                    \
            lv[q + 4] = f2bf(v - bf2f(hh));                                    \
        }                                                                      \
        *(bf8*)(hi + di) = hv;                                                 \
        *(bf8*)(lo + di) = lv;                                                 \
    }
    CVT(Wq,  wqkv_hi, wqkv_lo, 65536, 196608, 0,      0.0625f, 393216);
    CVT(Wk,  wqkv_hi, wqkv_lo, 65536, 196608, 65536,  1.f,     393216);
    CVT(Wv,  wqkv_hi, wqkv_lo, 65536, 196608, 131072, 1.f,     393216);
    CVT(Wo,  wo_hi,  wo_lo,  65536,  65536,  0, 1.f, 393216);
    CVT(Wf2, wf2_hi, wf2_lo, 262144, 262144, 0, 1.f, 1572864);
    CVT(exw1, wex1_hi, wex1_lo, 16384, 16384, 0, 1.f, 16384);
    CVT(exw2, wex2_hi, wex2_lo, 65536, 65536, 0, 1.f, 65536);
    CVT(ow1,  wo1_hi,  wo1_lo,  65536, 65536, 0, 1.f, 65536);
#undef CVT
    // Wf1: src rows of 288 -> dest rows of 320 (row boundary 8-aligned)
    for (int i = tid; i < 1769472 / 8; i += stride) {
        int ib = i * 8;
        int ll = ib / 294912, rels = ib - ll * 294912;
        int row = rels / 288, col = rels - row * 288;
        size_t di = (size_t)ll * (1024 * UMLD) + (size_t)row * UMLD + col;
        f4 v0 = *(const f4*)(Wf1 + ib);
        f4 v1 = *(const f4*)(Wf1 + ib + 4);
        bf8 hv, lv;
#pragma unroll
        for (int q = 0; q < 4; ++q) {
            float v = v0[q];
            short hh = f2bf(v);
            hv[q] = hh;
            lv[q] = f2bf(v - bf2f(hh));
        }
#pragma unroll
        for (int q = 0; q < 4; ++q) {
            float v = v1[q];
            short hh = f2bf(v);
            hv[q + 4] = hh;
            lv[q + 4] = f2bf(v - bf2f(hh));
        }
        *(bf8*)(wf1_hi + di) = hv;
        *(bf8*)(wf1_lo + di) = lv;
    }
    // zero pad cols 288..319: wf1 (6144 rows) and um (4096 rows)
    {
        bf8 zz;
#pragma unroll
        for (int q = 0; q < 8; ++q) zz[q] = 0;
        for (int i = tid; i < 6144 * 4; i += stride) {
            int row = i >> 2, seg = i & 3;
            size_t di = (size_t)row * UMLD + UMDIM + seg * 8;
            *(bf8*)(wf1_hi + di) = zz;
            *(bf8*)(wf1_lo + di) = zz;
        }
        for (int i = tid; i < 4096 * 4; i += stride) {
            int row = i >> 2, seg = i & 3;
            size_t di = (size_t)row * UMLD + UMDIM + seg * 8;
            *(bf8*)(umhi + di) = zz;
            *(bf8*)(umlo + di) = zz;
        }
    }
    for (int idx = tid; idx < NLc * NHc * NBINSc; idx += stride) {
        int bin = idx % NBINSc;
        int tmp = idx / NBINSc;
        int hh = tmp % NHc, l = tmp / NHc;
        float s = b2d[l * NHc + hh];
        const float* pe = pos_emb + bin * PDIMc;
        const float* w  = W2d + (l * NHc + hh) * PDIMc;
        for (int p = 0; p < PDIMc; ++p) s += pe[p] * w[p];
        bb[idx] = s;
    }
    for (int tok = tid; tok < NTOK; tok += stride) {
        int n = tok / Lc, l = tok % Lc;
        const float* xp = x + (size_t)n * 20 * Lc + l;
        float best = xp[0];
        int bi = 0;
        for (int c = 1; c < 20; ++c) {
            float v = xp[c * Lc];
            if (v > best) { best = v; bi = c; }
        }
        const float* e = aa_emb + bi * E1Dc;
        bf8 hv, lv;
        for (int c8 = 0; c8 < E1Dc / 8; ++c8) {
#pragma unroll
            for (int q = 0; q < 8; ++q) {
                float v = e[c8 * 8 + q];
                short hh = f2bf(v);
                hv[q] = hh;
                lv[q] = f2bf(v - bf2f(hh));
            }
            *(bf8*)(umhi + (size_t)tok * UMLD + EMBEDc + c8 * 8) = hv;
            *(bf8*)(umlo + (size_t)tok * UMLD + EMBEDc + c8 * 8) = lv;
        }
    }
    for (int tok = tid; tok < NTOK; tok += stride) {
        int n = tok >> 9, l = tok & 511;
        bf8 hv, lv;
        for (int c8 = 0; c8 < NZc / 8; ++c8) {
#pragma unroll
            for (int q = 0; q < 8; ++q) {
                float v = z[((size_t)n * NZc + c8 * 8 + q) * Lc + l];
                short hh = f2bf(v);
                hv[q] = hh;
                lv[q] = f2bf(v - bf2f(hh));
            }
            *(bf8*)(zth + (size_t)tok * NZc + c8 * 8) = hv;
            *(bf8*)(ztl + (size_t)tok * NZc + c8 * 8) = lv;
        }
    }
}

// ---------------------------------------------------------------------------
// LDS-staged MFMA GEMM (round-12 structure)
template <int EPI, int MF, int SKSHIFT, int BK>
__global__ __launch_bounds__(256) void k_gemm3(
    const short* __restrict__ Ahi, const short* __restrict__ Alo, int lda,
    const short* __restrict__ Bhi, const short* __restrict__ Blo, int ldb,
    int K, float* __restrict__ outf, int ldo, short* __restrict__ ohi,
    short* __restrict__ olo, int ldh, const float* __restrict__ bias,
    int gx, int gypx) {
    constexpr int PAD = BK + 8;
    __shared__ __align__(16) short Ah[MF * 64][PAD];
    __shared__ __align__(16) short Al[MF * 64][PAD];
    __shared__ __align__(16) short Bh[64][PAD];
    __shared__ __align__(16) short Bl[64][PAD];

    int bid = blockIdx.x;
    int koff = 0;
    if (SKSHIFT) {
        int kh = bid >> SKSHIFT;
        bid &= (1 << SKSHIFT) - 1;
        koff = kh * K;
        outf += (size_t)kh * NTOK * EMBEDc;
    }
    int xcd = bid & 7, j = bid >> 3;
    int bx = j % gx, by = xcd * gypx + j / gx;

    int t = threadIdx.x;
    int w = t >> 6, l = t & 63, lr = l & 15, lk = l >> 4;
    int m0 = by * (MF * 64);
    int n0 = bx * 64;

    constexpr int TPR = BK / 8;
    constexpr int RP  = 256 / TPR;
    constexpr int AP  = MF * 64 / RP;
    constexpr int BP  = 64 / RP;
    int srow = t / TPR, scol = (t % TPR) * 8;

    const short* pa  = Ahi + (size_t)(m0 + srow) * lda + koff + scol;
    const short* pal = Alo + (size_t)(m0 + srow) * lda + koff + scol;
    const short* pb  = Bhi + (size_t)(n0 + srow) * ldb + koff + scol;
    const short* pbl = Blo + (size_t)(n0 + srow) * ldb + koff + scol;

    bf8 ra[AP], rla[AP], rb[BP], rlb[BP];
#pragma unroll
    for (int p = 0; p < AP; ++p) {
        ra[p]  = *(const bf8*)(pa  + (size_t)p * RP * lda);
        rla[p] = *(const bf8*)(pal + (size_t)p * RP * lda);
    }
#pragma unroll
    for (int p = 0; p < BP; ++p) {
        rb[p]  = *(const bf8*)(pb  + (size_t)p * RP * ldb);
        rlb[p] = *(const bf8*)(pbl + (size_t)p * RP * ldb);
    }

    f4 acc[MF][4];
#pragma unroll
    for (int mf = 0; mf < MF; ++mf)
#pragma unroll
        for (int nf = 0; nf < 4; ++nf) acc[mf][nf] = (f4){0.f, 0.f, 0.f, 0.f};

    for (int ks = 0; ks < K; ks += BK) {
        __syncthreads();
#pragma unroll
        for (int p = 0; p < AP; ++p) {
            *(bf8*)&Ah[p * RP + srow][scol] = ra[p];
            *(bf8*)&Al[p * RP + srow][scol] = rla[p];
        }
#pragma unroll
        for (int p = 0; p < BP; ++p) {
            *(bf8*)&Bh[p * RP + srow][scol] = rb[p];
            *(bf8*)&Bl[p * RP + srow][scol] = rlb[p];
        }
        __syncthreads();
        if (ks + BK < K) {
#pragma unroll
            for (int p = 0; p < AP; ++p) {
                ra[p]  = *(const bf8*)(pa  + (size_t)p * RP * lda + ks + BK);
                rla[p] = *(const bf8*)(pal + (size_t)p * RP * lda + ks + BK);
            }
#pragma unroll
            for (int p = 0; p < BP; ++p) {
                rb[p]  = *(const bf8*)(pb  + (size_t)p * RP * ldb + ks + BK);
                rlb[p] = *(const bf8*)(pbl + (size_t)p * RP * ldb + ks + BK);
            }
        }
#pragma unroll
        for (int kc = 0; kc < BK / 32; ++kc) {
            bf8 bhf[4], blf[4];
#pragma unroll
            for (int nf = 0; nf < 4; ++nf) {
                bhf[nf] = *(const bf8*)&Bh[nf * 16 + lr][kc * 32 + lk * 8];
                blf[nf] = *(const bf8*)&Bl[nf * 16 + lr][kc * 32 + lk * 8];
            }
#pragma unroll
            for (int mf = 0; mf < MF; ++mf) {
                bf8 ah = *(const bf8*)&Ah[w * MF * 16 + mf * 16 + lr][kc * 32 + lk * 8];
                bf8 al = *(const bf8*)&Al[w * MF * 16 + mf * 16 + lr][kc * 32 + lk * 8];
#pragma unroll
                for (int nf = 0; nf < 4; ++nf) {
                    acc[mf][nf] = MFMA(ah, bhf[nf], acc[mf][nf]);
                    acc[mf][nf] = MFMA(ah, blf[nf], acc[mf][nf]);
                    acc[mf][nf] = MFMA(al, bhf[nf], acc[mf][nf]);
                }
            }
        }
    }

#pragma unroll
    for (int mf = 0; mf < MF; ++mf) {
#pragma unroll
        for (int nf = 0; nf < 4; ++nf) {
            int n = n0 + nf * 16 + lr;
            int mbase = m0 + w * MF * 16 + mf * 16 + lk * 4;
            if (EPI == 0) {
#pragma unroll
                for (int r = 0; r < 4; ++r)
                    outf[(size_t)(mbase + r) * ldo + n] = acc[mf][nf][r];
            } else if (EPI == 1) {
                float bv = bias[n];
#pragma unroll
                for (int r = 0; r < 4; ++r) {
                    float y = fmaxf(acc[mf][nf][r] + bv, 0.f);
                    short hv = f2bf(y);
                    size_t oi = (size_t)(mbase + r) * ldh + n;
                    ohi[oi] = hv;
                    olo[oi] = f2bf(y - bf2f(hv));
                }
            } else if (EPI == 2) {
#pragma unroll
                for (int r = 0; r < 4; ++r) {
                    float y = acc[mf][nf][r];
                    short hv = f2bf(y);
                    size_t oi = (size_t)(mbase + r) * ldh + n;
                    ohi[oi] = hv;
                    olo[oi] = f2bf(y - bf2f(hv));
                }
            } else {
                float bv = bias[n];
#pragma unroll
                for (int r = 0; r < 4; ++r) {
                    float y = acc[mf][nf][r] + bv;
                    outf[(size_t)(mbase + r) * ldo + n] = y;
                    short hv = f2bf(y);
                    size_t oi = (size_t)(mbase + r) * ldh + n;
                    ohi[oi] = hv;
                    olo[oi] = f2bf(y - bf2f(hv));
                }
            }
        }
    }
}

// ---------------------------------------------------------------------------
// MFMA flash attention (round-12 best config): 512 threads, K/V staged in two
// 256-key halves (37.6 KB LDS), grid 512.
__global__ __launch_bounds__(512, 8) void k_attn(const short* __restrict__ qh,
                                                 const short* __restrict__ ql,
                                                 const float* __restrict__ bb,
                                                 short* __restrict__ ohi,
                                                 short* __restrict__ olo) {
    int bx = blockIdx.x;
    int qt = bx >> 7;            // 0..3; blocks sharing (n,head) same XCD
    int head = bx & 15;
    int n = (bx >> 4) & 7;
    int t = threadIdx.x;
    int w = t >> 6, l = t & 63;
    int lq = l & 15, lk = l >> 4;

    __shared__ __align__(16) short khl[256][40];   // [key][hi0-15|lo16-31|pad]
    __shared__ __align__(16) short vth[16][264];   // V^T hi: [d][key 0..255]
    __shared__ __align__(16) short vtl[16][264];   // V^T lo
    __shared__ float biasr[64];

    if (t < NBINSc) biasr[t] = bb[head * NBINSc + t];
    float bL = bb[head * NBINSc];
    float bR = bb[head * NBINSc + 48];

    size_t base = (size_t)n * Lc * 768 + head * 16;

    int qg = qt * 128 + w * 16 + lq;             // this lane's q column
    size_t qrow = ((size_t)n * Lc + qg) * 768 + head * 16;
    bf8 B1 = *(const bf8*)(qh + qrow + (lk & 1) * 8);   // [Qh|Qh]
    bf8 B2;
    if (lk < 2) B2 = *(const bf8*)(ql + qrow + lk * 8);  // [Ql|0]
    else {
#pragma unroll
        for (int i = 0; i < 8; ++i) B2[i] = 0;
    }

    f4 acc = (f4){0.f, 0.f, 0.f, 0.f};
    float m = -1e30f, lsum = 0.f;
    int rel0 = lk * 4 - qg;      // rel of s[0] at global kt=0; += 16 per tile

    for (int half = 0; half < 2; ++half) {
        __syncthreads();          // previous half fully consumed
        // stage K half (256 keys)
        for (int u = t; u < 1024; u += 512) {
            int key = u >> 2, seg = u & 3;
            const short* src = (seg < 2 ? qh : ql) + base + 256
                             + (size_t)(half * 256 + key) * 768 + (seg & 1) * 8;
            *(bf8*)&khl[key][seg * 8] = *(const bf8*)src;
        }
        // stage V half transposed, pair-packed b32 writes (1 item/thread)
        {
            int u = t & 127;             // key pair
            int dhalf = (t >> 7) & 1;    // d 0..7 / 8..15
            int hl = (t >> 8) & 1;       // hi / lo
            int gkey = half * 256 + u * 2;
            const short* vs = (hl ? ql : qh) + base + 512 + (size_t)gkey * 768 + dhalf * 8;
            bf8 A = *(const bf8*)vs;
            bf8 B = *(const bf8*)(vs + 768);
            unsigned* vw = (unsigned*)(hl ? &vtl[0][0] : &vth[0][0]);  // stride 132 words
#pragma unroll
            for (int i = 0; i < 8; ++i)
                vw[(dhalf * 8 + i) * 132 + u] =
                    (unsigned)(unsigned short)A[i] | ((unsigned)(unsigned short)B[i] << 16);
        }
        __syncthreads();

        for (int kt = 0; kt < 16; ++kt, rel0 += 16) {
            bf8 A1 = *(const bf8*)&khl[kt * 16 + lq][lk * 8];  // [Kh|Kl]
            f4 s = (f4){0.f, 0.f, 0.f, 0.f};
            __builtin_amdgcn_s_setprio(1);
            s = MFMA(A1, B1, s);      // KhQh + KlQh
            s = MFMA(A1, B2, s);      // KhQl
            __builtin_amdgcn_s_setprio(0);
            if (rel0 >= PMAXLc) {
                s[0] += bR; s[1] += bR; s[2] += bR; s[3] += bR;
            } else if (rel0 + 3 <= -PMAXLc) {
                s[0] += bL; s[1] += bL; s[2] += bL; s[3] += bL;
            } else {
#pragma unroll
                for (int r = 0; r < 4; ++r) {
                    int rel = rel0 + r;
                    rel = rel < -PMAXLc ? -PMAXLc : (rel > PMAXLc ? PMAXLc : rel);
                    s[r] += biasr[rel + PMAXLc];
                }
            }
            float mt = fmaxf(fmaxf(s[0], s[1]), fmaxf(s[2], s[3]));
            mt = fmaxf(mt, __shfl_xor(mt, 16));
            mt = fmaxf(mt, __shfl_xor(mt, 32));
            if (__any(mt > m + 8.0f)) {
                float mn = fmaxf(m, mt);
                float alpha = __expf(m - mn);
                m = mn;
                lsum *= alpha;
#pragma unroll
                for (int r = 0; r < 4; ++r) acc[r] *= __shfl(alpha, lk * 4 + r);
            }
            f4 p;
#pragma unroll
            for (int r = 0; r < 4; ++r) p[r] = __expf(s[r] - m);
            lsum += p[0] + p[1] + p[2] + p[3];
            int src0 = (lk & 1) * 32 + lq;
            int src1 = src0 + 16;
            float g[8];
#pragma unroll
            for (int jj = 0; jj < 4; ++jj) {
                g[jj]     = __shfl(p[jj], src0);
                g[jj + 4] = __shfl(p[jj], src1);
            }
            bf8 PA;
            if (lk < 2) {
#pragma unroll
                for (int jj = 0; jj < 8; ++jj)
                    PA[jj] = (short)(__float_as_uint(g[jj]) >> 16);
            } else {
#pragma unroll
                for (int jj = 0; jj < 8; ++jj) {
                    unsigned hu = __float_as_uint(g[jj]) & 0xFFFF0000u;
                    PA[jj] = (short)(__float_as_uint(g[jj] - __uint_as_float(hu)) >> 16);
                }
            }
            bf8 VB1 = *(const bf8*)&vth[lq][kt * 16 + (lk & 1) * 8];  // [Vh|Vh]
            bf8 VB2;
            if (lk < 2) VB2 = *(const bf8*)&vtl[lq][kt * 16 + lk * 8];  // [Vl|0]
            else {
#pragma unroll
                for (int i = 0; i < 8; ++i) VB2[i] = 0;
            }
            __builtin_amdgcn_s_setprio(1);
            acc = MFMA(PA, VB1, acc);   // PhVh + PlVh
            acc = MFMA(PA, VB2, acc);   // PhVl
            __builtin_amdgcn_s_setprio(0);
        }
    }

    float lred = lsum + __shfl_xor(lsum, 16);
    lred += __shfl_xor(lred, 32);
    float inv = 1.0f / lred;
#pragma unroll
    for (int r = 0; r < 4; ++r) {
        float iq = __shfl(inv, lk * 4 + r);
        float y = acc[r] * iq;
        int qo = qt * 128 + w * 16 + lk * 4 + r;
        size_t oi = ((size_t)n * Lc + qo) * DMc + head * 16 + lq;
        unsigned hu = __float_as_uint(y) & 0xFFFF0000u;
        ohi[oi] = (short)(hu >> 16);
        olo[oi] = (short)(__float_as_uint(y - __uint_as_float(hu)) >> 16);
    }
}

// ---------------------------------------------------------------------------
// LN over h + s2a + s2b + sbias, fully f4-vectorized. um stride = UMLD.
__global__ __launch_bounds__(256) void k_ln(const float* __restrict__ s2a,
                                            const float* __restrict__ s2b,
                                            const float* __restrict__ sbias,
                                            const float* __restrict__ g,
                                            const float* __restrict__ bta,
                                            float* __restrict__ h,
                                            short* __restrict__ umhi,
                                            short* __restrict__ umlo) {
    int t = threadIdx.x;
    int tl = t >> 5, j = t & 31;
    size_t gtok = (size_t)blockIdx.x * 8 + tl;
    int d0 = j * 8;
    size_t off = gtok * EMBEDc + d0;
    f4 h0 = *(const f4*)(h + off);
    f4 h1 = *(const f4*)(h + off + 4);
    f4 a0 = *(const f4*)(s2a + off);
    f4 a1 = *(const f4*)(s2a + off + 4);
    f4 b0 = *(const f4*)(s2b + off);
    f4 b1 = *(const f4*)(s2b + off + 4);
    f4 sb0 = *(const f4*)(sbias + d0);
    f4 sb1 = *(const f4*)(sbias + d0 + 4);
    f4 v0 = h0 + a0 + b0 + sb0;
    f4 v1 = h1 + a1 + b1 + sb1;
    float sum = v0[0] + v0[1] + v0[2] + v0[3] + v1[0] + v1[1] + v1[2] + v1[3];
    float ssq = v0[0]*v0[0] + v0[1]*v0[1] + v0[2]*v0[2] + v0[3]*v0[3]
              + v1[0]*v1[0] + v1[1]*v1[1] + v1[2]*v1[2] + v1[3]*v1[3];
#pragma unroll
    for (int off5 = 16; off5; off5 >>= 1) {
        sum += __shfl_xor(sum, off5, 32);
        ssq += __shfl_xor(ssq, off5, 32);
    }
    float mean = sum * (1.f / EMBEDc);
    float var = ssq * (1.f / EMBEDc) - mean * mean;
    float inv = rsqrtf(var + 1e-5f);
    f4 g0 = *(const f4*)(g + d0);
    f4 g1 = *(const f4*)(g + d0 + 4);
    f4 t0 = *(const f4*)(bta + d0);
    f4 t1 = *(const f4*)(bta + d0 + 4);
    f4 y0, y1;
    bf8 hv, lv;
#pragma unroll
    for (int q = 0; q < 4; ++q) {
        float y = (v0[q] - mean) * inv * g0[q] + t0[q];
        y0[q] = y;
        short hh = f2bf(y);
        hv[q] = hh;
        lv[q] = f2bf(y - bf2f(hh));
    }
#pragma unroll
    for (int q = 0; q < 4; ++q) {
        float y = (v1[q] - mean) * inv * g1[q] + t1[q];
        y1[q] = y;
        short hh = f2bf(y);
        hv[q + 4] = hh;
        lv[q + 4] = f2bf(y - bf2f(hh));
    }
    *(f4*)(h + off) = y0;
    *(f4*)(h + off + 4) = y1;
    *(bf8*)(umhi + gtok * UMLD + d0) = hv;
    *(bf8*)(umlo + gtok * UMLD + d0) = lv;
}

// ---------------------------------------------------------------------------
__global__ __launch_bounds__(256) void k_r(const short* __restrict__ fh,
                                           const short* __restrict__ fl,
                                           const float* __restrict__ w2,
                                           const float* __restrict__ b2,
                                           float* __restrict__ r) {
    __shared__ float w[3][EMBEDc];
    int t = threadIdx.x;
    for (int u = t; u < 3 * EMBEDc; u += 256) w[u >> 8][u & 255] = w2[u];
    __syncthreads();
    int tok = blockIdx.x * 64 + (t >> 2), o = t & 3;
    if (o < 3) {
        const short* ph = fh + (size_t)tok * EMBEDc;
        const short* pl = fl + (size_t)tok * EMBEDc;
        float s = b2[o];
        for (int c8 = 0; c8 < EMBEDc / 8; ++c8) {
            bf8 vh = *(const bf8*)(ph + c8 * 8);
            bf8 vl = *(const bf8*)(pl + c8 * 8);
#pragma unroll
            for (int j = 0; j < 8; ++j)
                s += (bf2f(vh[j]) + bf2f(vl[j])) * w[o][c8 * 8 + j];
        }
        r[(size_t)tok * 3 + o] = s;
    }
}

// ---------------------------------------------------------------------------
__global__ __launch_bounds__(256) void k_dmap(const float* __restrict__ r,
                                              float* __restrict__ d) {
    int b = blockIdx.x;
    int n = b / Lc;
    float xi = r[(size_t)b * 3], yi = r[(size_t)b * 3 + 1], zi = r[(size_t)b * 3 + 2];
    const float* rn = r + (size_t)n * Lc * 3;
    for (int j = threadIdx.x; j < Lc; j += 256) {
        float dx = xi - rn[j * 3];
        float dy = yi - rn[j * 3 + 1];
        float dz = zi - rn[j * 3 + 2];
        d[(size_t)b * Lc + j] = sqrtf(dx * dx + dy * dy + dz * dz + 1e-12f);
    }
}

// ---------------------------------------------------------------------------
extern "C" void kernel_launch(void* const* d_in, const int* in_sizes, int n_in,
                              void* d_out, int out_size, void* d_ws, size_t ws_size,
                              hipStream_t stream) {
    const float* z       = (const float*)d_in[0];
    const float* x       = (const float*)d_in[1];
    const float* pos_emb = (const float*)d_in[2];
    const float* aa_emb  = (const float*)d_in[3];
    const float* ex_w1   = (const float*)d_in[4];
    const float* ex_b1   = (const float*)d_in[5];
    const float* ex_w2   = (const float*)d_in[6];
    const float* ex_b2   = (const float*)d_in[7];
    const float* Wq      = (const float*)d_in[8];
    const float* Wk      = (const float*)d_in[9];
    const float* Wv      = (const float*)d_in[10];
    const float* Wo      = (const float*)d_in[11];
    const float* bo      = (const float*)d_in[12];
    const float* W2d     = (const float*)d_in[13];
    const float* b2d     = (const float*)d_in[14];
    const float* Wf1     = (const float*)d_in[15];
    const float* bf1     = (const float*)d_in[16];
    const float* Wf2     = (const float*)d_in[17];
    const float* bf2     = (const float*)d_in[18];
    const float* ln1_g   = (const float*)d_in[19];
    const float* ln1_b   = (const float*)d_in[20];
    const float* ln2_g   = (const float*)d_in[21];
    const float* ln2_b   = (const float*)d_in[22];
    const float* o_w1    = (const float*)d_in[23];
    const float* o_b1    = (const float*)d_in[24];
    const float* o_w2    = (const float*)d_in[25];
    const float* o_b2    = (const float*)d_in[26];

    float* h    = (float*)d_ws;                    // 4096*256
    float* s2a  = h + (size_t)NTOK * EMBEDc;
    float* s2b  = s2a + (size_t)NTOK * EMBEDc;
    float* bbuf = s2b + (size_t)NTOK * EMBEDc;     // pad 8192
    float* r    = bbuf + 8192;                     // pad 16384
    short* qkvh = (short*)(r + 16384);             // 4096*768
    short* qkvl = qkvh + (size_t)NTOK * 768;
    short* um_hi = qkvl + (size_t)NTOK * 768;      // 4096*320 (padded)
    short* um_lo = um_hi + (size_t)NTOK * UMLD;
    short* o_hi  = um_lo + (size_t)NTOK * UMLD;    // 4096*256
    short* o_lo  = o_hi + (size_t)NTOK * EMBEDc;
    short* f1_hi = o_lo + (size_t)NTOK * EMBEDc;   // 4096*1024
    short* f1_lo = f1_hi + (size_t)NTOK * DFFc;
    short* wqkv_hi = f1_lo + (size_t)NTOK * DFFc;  // 6*768*256
    short* wqkv_lo = wqkv_hi + (size_t)NLc * 768 * EMBEDc;
    short* wo_hi   = wqkv_lo + (size_t)NLc * 768 * EMBEDc;   // 6*256*256
    short* wo_lo   = wo_hi + (size_t)NLc * EMBEDc * DMc;
    short* wf1_hi  = wo_lo + (size_t)NLc * EMBEDc * DMc;     // 6*1024*320 (padded)
    short* wf1_lo  = wf1_hi + (size_t)NLc * DFFc * UMLD;
    short* wf2_hi  = wf1_lo + (size_t)NLc * DFFc * UMLD;     // 6*256*1024
    short* wf2_lo  = wf2_hi + (size_t)NLc * EMBEDc * DFFc;
    short* wex1_hi = wf2_lo + (size_t)NLc * EMBEDc * DFFc;   // 256*64
    short* wex1_lo = wex1_hi + EMBEDc * NZc;
    short* wex2_hi = wex1_lo + EMBEDc * NZc;                 // 256*256
    short* wex2_lo = wex2_hi + EMBEDc * EMBEDc;
    short* wo1_hi  = wex2_lo + EMBEDc * EMBEDc;              // 256*256
    short* wo1_lo  = wo1_hi + EMBEDc * EMBEDc;
    // zt aliases the o buffer (only used in preamble, before k_attn writes o)
    short* zt_hi = o_hi;
    short* zt_lo = o_lo;

    k_pre<<<1024, 256, 0, stream>>>(Wq, Wk, Wv, Wo, Wf1, Wf2, ex_w1, ex_w2, o_w1,
                                    pos_emb, W2d, b2d, x, aa_emb, z,
                                    wqkv_hi, wqkv_lo, wo_hi, wo_lo,
                                    wf1_hi, wf1_lo, wf2_hi, wf2_lo,
                                    wex1_hi, wex1_lo, wex2_hi, wex2_lo,
                                    wo1_hi, wo1_lo, bbuf, um_hi, um_lo,
                                    zt_hi, zt_lo);

    // embed: relu GEMM -> GEMM (fp32 h + bf16 um, ldh = UMLD)
    k_gemm3<1, 1, 0, 64><<<256, 256, 0, stream>>>(
        zt_hi, zt_lo, NZc, wex1_hi, wex1_lo, NZc, NZc,
        nullptr, 0, f1_hi, f1_lo, EMBEDc, ex_b1, 4, 8);
    k_gemm3<3, 1, 0, 64><<<256, 256, 0, stream>>>(
        f1_hi, f1_lo, EMBEDc, wex2_hi, wex2_lo, EMBEDc, EMBEDc,
        h, EMBEDc, um_hi, um_lo, UMLD, ex_b2, 4, 8);

    for (int l = 0; l < NLc; ++l) {
        k_gemm3<2, 2, 0, 64><<<384, 256, 0, stream>>>(
            um_hi, um_lo, UMLD,
            wqkv_hi + (size_t)l * 768 * EMBEDc, wqkv_lo + (size_t)l * 768 * EMBEDc, EMBEDc,
            EMBEDc, nullptr, 0, qkvh, qkvl, 768, nullptr, 12, 4);
        k_attn<<<NB * NHc * 4, 512, 0, stream>>>(qkvh, qkvl, bbuf + (size_t)l * NHc * NBINSc, o_hi, o_lo);
        k_gemm3<0, 1, 8, 64><<<512, 256, 0, stream>>>(
            o_hi, o_lo, EMBEDc,
            wo_hi + (size_t)l * EMBEDc * DMc, wo_lo + (size_t)l * EMBEDc * DMc, DMc,
            128, s2a, EMBEDc, nullptr, nullptr, 0, nullptr, 4, 8);
        k_ln<<<NTOK / 8, 256, 0, stream>>>(s2a, s2b, bo + (size_t)l * EMBEDc,
                                           ln1_g + (size_t)l * EMBEDc, ln1_b + (size_t)l * EMBEDc,
                                           h, um_hi, um_lo);
        // ffn1: K padded 288->320, BK=64 (zero pad cols contribute 0 exactly)
        k_gemm3<1, 2, 0, 64><<<512, 256, 0, stream>>>(
            um_hi, um_lo, UMLD,
            wf1_hi + (size_t)l * DFFc * UMLD, wf1_lo + (size_t)l * DFFc * UMLD, UMLD,
            UMLD, nullptr, 0, f1_hi, f1_lo, DFFc, bf1 + (size_t)l * DFFc, 16, 4);
        k_gemm3<0, 1, 8, 64><<<512, 256, 0, stream>>>(
            f1_hi, f1_lo, DFFc,
            wf2_hi + (size_t)l * EMBEDc * DFFc, wf2_lo + (size_t)l * EMBEDc * DFFc, DFFc,
            512, s2a, EMBEDc, nullptr, nullptr, 0, nullptr, 4, 8);
        k_ln<<<NTOK / 8, 256, 0, stream>>>(s2a, s2b, bf2 + (size_t)l * EMBEDc,
                                           ln2_g + (size_t)l * EMBEDc, ln2_b + (size_t)l * EMBEDc,
                                           h, um_hi, um_lo);
    }

    // final: f = relu(um @ o_w1^T + o_b1) (um cols 0..255 hold h in bf16)
    k_gemm3<1, 1, 0, 64><<<256, 256, 0, stream>>>(
        um_hi, um_lo, UMLD, wo1_hi, wo1_lo, EMBEDc, EMBEDc,
        nullptr, 0, f1_hi, f1_lo, EMBEDc, o_b1, 4, 8);
    k_r<<<NTOK / 64, 256, 0, stream>>>(f1_hi, f1_lo, o_w2, o_b2, r);
    k_dmap<<<NB * Lc, 256, 0, stream>>>(r, (float*)d_out);
}

// Round 16
// 551.544 us; speedup vs baseline: 1.0927x; 1.0474x over previous
//
#include <hip/hip_runtime.h>
#include <math.h>

#define NZc     64
#define EMBEDc  256
#define DMc     256
#define NHc     16
#define HDc     16
#define DFFc    1024
#define NLc     6
#define E1Dc    32
#define PDIMc   64
#define PMAXLc  24
#define NBINSc  49
#define NB      8
#define Lc      512
#define NTOK    (NB * Lc)        // 4096
#define UMDIM   288              // logical um width
#define UMLD    320              // padded leading dim (zeros in 288..319)

typedef __attribute__((ext_vector_type(4))) float f4;
typedef __attribute__((ext_vector_type(8))) short bf8;   // 8 bf16 in 4 VGPRs

#define MFMA(a, b, c) __builtin_amdgcn_mfma_f32_16x16x32_bf16((a), (b), (c), 0, 0, 0)

__device__ __forceinline__ short f2bf(float f) {
    unsigned u = __float_as_uint(f);
    u += 0x7FFFu + ((u >> 16) & 1u);   // round-to-nearest-even
    return (short)(u >> 16);
}
__device__ __forceinline__ float bf2f(short s) {
    return __uint_as_float(((unsigned)(unsigned short)s) << 16);
}

// ---------------------------------------------------------------------------
// preamble: weight conversions (x8 vectorized) + bias bins + e_aa + z^T.
// Wf1 rows remapped 288 -> 320 stride; pad cols zero-filled (um + wf1).
__global__ void k_pre(const float* __restrict__ Wq, const float* __restrict__ Wk,
                      const float* __restrict__ Wv, const float* __restrict__ Wo,
                      const float* __restrict__ Wf1, const float* __restrict__ Wf2,
                      const float* __restrict__ exw1, const float* __restrict__ exw2,
                      const float* __restrict__ ow1,
                      const float* __restrict__ pos_emb, const float* __restrict__ W2d,
                      const float* __restrict__ b2d, const float* __restrict__ x,
                      const float* __restrict__ aa_emb, const float* __restrict__ z,
                      short* __restrict__ wqkv_hi, short* __restrict__ wqkv_lo,
                      short* __restrict__ wo_hi, short* __restrict__ wo_lo,
                      short* __restrict__ wf1_hi, short* __restrict__ wf1_lo,
                      short* __restrict__ wf2_hi, short* __restrict__ wf2_lo,
                      short* __restrict__ wex1_hi, short* __restrict__ wex1_lo,
                      short* __restrict__ wex2_hi, short* __restrict__ wex2_lo,
                      short* __restrict__ wo1_hi, short* __restrict__ wo1_lo,
                      float* __restrict__ bb,
                      short* __restrict__ umhi, short* __restrict__ umlo,
                      short* __restrict__ zth, short* __restrict__ ztl) {
    int stride = gridDim.x * blockDim.x;
    int tid = blockIdx.x * blockDim.x + threadIdx.x;
#define CVT(src, hi, lo, per_layer, dstride, doff, scale, total)               \
    for (int i = tid; i < (total) / 8; i += stride) {                          \
        int ib = i * 8;                                                        \
        int ll = ib / (per_layer), rels = ib - ll * (per_layer);               \
        size_t di = (size_t)ll * (dstride) + (doff) + rels;                    \
        f4 v0 = *(const f4*)(src + ib);                                        \
        f4 v1 = *(const f4*)(src + ib + 4);                                    \
        bf8 hv, lv;                                                            \
        _Pragma("unroll")                                                      \
        for (int q = 0; q < 4; ++q) {                                          \
            float v = v0[q] * (scale);                                         \
            short hh = f2bf(v);                                                \
            hv[q] = hh;                                                        \
            lv[q] = f2bf(v - bf2f(hh));                                        \
        }                                                                      \
        _Pragma("unroll")                                                      \
        for (int q = 0; q < 4; ++q) {                                          \
            float v = v1[q] * (scale);                                         \
            short hh = f2bf(v);                                                \
            hv[q + 4] = hh;                                                    \
            lv[q + 4] = f2bf(v - bf2f(hh));                                    \
        }                                                                      \
        *(bf8*)(hi + di) = hv;                                                 \
        *(bf8*)(lo + di) = lv;                                                 \
    }
    CVT(Wq,  wqkv_hi, wqkv_lo, 65536, 196608, 0,      0.0625f, 393216);
    CVT(Wk,  wqkv_hi, wqkv_lo, 65536, 196608, 65536,  1.f,     393216);
    CVT(Wv,  wqkv_hi, wqkv_lo, 65536, 196608, 131072, 1.f,     393216);
    CVT(Wo,  wo_hi,  wo_lo,  65536,  65536,  0, 1.f, 393216);
    CVT(Wf2, wf2_hi, wf2_lo, 262144, 262144, 0, 1.f, 1572864);
    CVT(exw1, wex1_hi, wex1_lo, 16384, 16384, 0, 1.f, 16384);
    CVT(exw2, wex2_hi, wex2_lo, 65536, 65536, 0, 1.f, 65536);
    CVT(ow1,  wo1_hi,  wo1_lo,  65536, 65536, 0, 1.f, 65536);
#undef CVT
    // Wf1: src rows of 288 -> dest rows of 320 (row boundary 8-aligned)
    for (int i = tid; i < 1769472 / 8; i += stride) {
        int ib = i * 8;
        int ll = ib / 294912, rels = ib - ll * 294912;
        int row = rels / 288, col = rels - row * 288;
        size_t di = (size_t)ll * (1024 * UMLD) + (size_t)row * UMLD + col;
        f4 v0 = *(const f4*)(Wf1 + ib);
        f4 v1 = *(const f4*)(Wf1 + ib + 4);
        bf8 hv, lv;
#pragma unroll
        for (int q = 0; q < 4; ++q) {
            float v = v0[q];
            short hh = f2bf(v);
            hv[q] = hh;
            lv[q] = f2bf(v - bf2f(hh));
        }
#pragma unroll
        for (int q = 0; q < 4; ++q) {
            float v = v1[q];
            short hh = f2bf(v);
            hv[q + 4] = hh;
            lv[q + 4] = f2bf(v - bf2f(hh));
        }
        *(bf8*)(wf1_hi + di) = hv;
        *(bf8*)(wf1_lo + di) = lv;
    }
    // zero pad cols 288..319: wf1 (6144 rows) and um (4096 rows)
    {
        bf8 zz;
#pragma unroll
        for (int q = 0; q < 8; ++q) zz[q] = 0;
        for (int i = tid; i < 6144 * 4; i += stride) {
            int row = i >> 2, seg = i & 3;
            size_t di = (size_t)row * UMLD + UMDIM + seg * 8;
            *(bf8*)(wf1_hi + di) = zz;
            *(bf8*)(wf1_lo + di) = zz;
        }
        for (int i = tid; i < 4096 * 4; i += stride) {
            int row = i >> 2, seg = i & 3;
            size_t di = (size_t)row * UMLD + UMDIM + seg * 8;
            *(bf8*)(umhi + di) = zz;
            *(bf8*)(umlo + di) = zz;
        }
    }
    for (int idx = tid; idx < NLc * NHc * NBINSc; idx += stride) {
        int bin = idx % NBINSc;
        int tmp = idx / NBINSc;
        int hh = tmp % NHc, l = tmp / NHc;
        float s = b2d[l * NHc + hh];
        const float* pe = pos_emb + bin * PDIMc;
        const float* w  = W2d + (l * NHc + hh) * PDIMc;
        for (int p = 0; p < PDIMc; ++p) s += pe[p] * w[p];
        bb[idx] = s;
    }
    for (int tok = tid; tok < NTOK; tok += stride) {
        int n = tok / Lc, l = tok % Lc;
        const float* xp = x + (size_t)n * 20 * Lc + l;
        float best = xp[0];
        int bi = 0;
        for (int c = 1; c < 20; ++c) {
            float v = xp[c * Lc];
            if (v > best) { best = v; bi = c; }
        }
        const float* e = aa_emb + bi * E1Dc;
        bf8 hv, lv;
        for (int c8 = 0; c8 < E1Dc / 8; ++c8) {
#pragma unroll
            for (int q = 0; q < 8; ++q) {
                float v = e[c8 * 8 + q];
                short hh = f2bf(v);
                hv[q] = hh;
                lv[q] = f2bf(v - bf2f(hh));
            }
            *(bf8*)(umhi + (size_t)tok * UMLD + EMBEDc + c8 * 8) = hv;
            *(bf8*)(umlo + (size_t)tok * UMLD + EMBEDc + c8 * 8) = lv;
        }
    }
    for (int tok = tid; tok < NTOK; tok += stride) {
        int n = tok >> 9, l = tok & 511;
        bf8 hv, lv;
        for (int c8 = 0; c8 < NZc / 8; ++c8) {
#pragma unroll
            for (int q = 0; q < 8; ++q) {
                float v = z[((size_t)n * NZc + c8 * 8 + q) * Lc + l];
                short hh = f2bf(v);
                hv[q] = hh;
                lv[q] = f2bf(v - bf2f(hh));
            }
            *(bf8*)(zth + (size_t)tok * NZc + c8 * 8) = hv;
            *(bf8*)(ztl + (size_t)tok * NZc + c8 * 8) = lv;
        }
    }
}

// ---------------------------------------------------------------------------
// LDS-staged MFMA GEMM (round-12 structure)
template <int EPI, int MF, int SKSHIFT, int BK>
__global__ __launch_bounds__(256) void k_gemm3(
    const short* __restrict__ Ahi, const short* __restrict__ Alo, int lda,
    const short* __restrict__ Bhi, const short* __restrict__ Blo, int ldb,
    int K, float* __restrict__ outf, int ldo, short* __restrict__ ohi,
    short* __restrict__ olo, int ldh, const float* __restrict__ bias,
    int gx, int gypx) {
    constexpr int PAD = BK + 8;
    __shared__ __align__(16) short Ah[MF * 64][PAD];
    __shared__ __align__(16) short Al[MF * 64][PAD];
    __shared__ __align__(16) short Bh[64][PAD];
    __shared__ __align__(16) short Bl[64][PAD];

    int bid = blockIdx.x;
    int koff = 0;
    if (SKSHIFT) {
        int kh = bid >> SKSHIFT;
        bid &= (1 << SKSHIFT) - 1;
        koff = kh * K;
        outf += (size_t)kh * NTOK * EMBEDc;
    }
    int xcd = bid & 7, j = bid >> 3;
    int bx = j % gx, by = xcd * gypx + j / gx;

    int t = threadIdx.x;
    int w = t >> 6, l = t & 63, lr = l & 15, lk = l >> 4;
    int m0 = by * (MF * 64);
    int n0 = bx * 64;

    constexpr int TPR = BK / 8;
    constexpr int RP  = 256 / TPR;
    constexpr int AP  = MF * 64 / RP;
    constexpr int BP  = 64 / RP;
    int srow = t / TPR, scol = (t % TPR) * 8;

    const short* pa  = Ahi + (size_t)(m0 + srow) * lda + koff + scol;
    const short* pal = Alo + (size_t)(m0 + srow) * lda + koff + scol;
    const short* pb  = Bhi + (size_t)(n0 + srow) * ldb + koff + scol;
    const short* pbl = Blo + (size_t)(n0 + srow) * ldb + koff + scol;

    bf8 ra[AP], rla[AP], rb[BP], rlb[BP];
#pragma unroll
    for (int p = 0; p < AP; ++p) {
        ra[p]  = *(const bf8*)(pa  + (size_t)p * RP * lda);
        rla[p] = *(const bf8*)(pal + (size_t)p * RP * lda);
    }
#pragma unroll
    for (int p = 0; p < BP; ++p) {
        rb[p]  = *(const bf8*)(pb  + (size_t)p * RP * ldb);
        rlb[p] = *(const bf8*)(pbl + (size_t)p * RP * ldb);
    }

    f4 acc[MF][4];
#pragma unroll
    for (int mf = 0; mf < MF; ++mf)
#pragma unroll
        for (int nf = 0; nf < 4; ++nf) acc[mf][nf] = (f4){0.f, 0.f, 0.f, 0.f};

    for (int ks = 0; ks < K; ks += BK) {
        __syncthreads();
#pragma unroll
        for (int p = 0; p < AP; ++p) {
            *(bf8*)&Ah[p * RP + srow][scol] = ra[p];
            *(bf8*)&Al[p * RP + srow][scol] = rla[p];
        }
#pragma unroll
        for (int p = 0; p < BP; ++p) {
            *(bf8*)&Bh[p * RP + srow][scol] = rb[p];
            *(bf8*)&Bl[p * RP + srow][scol] = rlb[p];
        }
        __syncthreads();
        if (ks + BK < K) {
#pragma unroll
            for (int p = 0; p < AP; ++p) {
                ra[p]  = *(const bf8*)(pa  + (size_t)p * RP * lda + ks + BK);
                rla[p] = *(const bf8*)(pal + (size_t)p * RP * lda + ks + BK);
            }
#pragma unroll
            for (int p = 0; p < BP; ++p) {
                rb[p]  = *(const bf8*)(pb  + (size_t)p * RP * ldb + ks + BK);
                rlb[p] = *(const bf8*)(pbl + (size_t)p * RP * ldb + ks + BK);
            }
        }
#pragma unroll
        for (int kc = 0; kc < BK / 32; ++kc) {
            bf8 bhf[4], blf[4];
#pragma unroll
            for (int nf = 0; nf < 4; ++nf) {
                bhf[nf] = *(const bf8*)&Bh[nf * 16 + lr][kc * 32 + lk * 8];
                blf[nf] = *(const bf8*)&Bl[nf * 16 + lr][kc * 32 + lk * 8];
            }
#pragma unroll
            for (int mf = 0; mf < MF; ++mf) {
                bf8 ah = *(const bf8*)&Ah[w * MF * 16 + mf * 16 + lr][kc * 32 + lk * 8];
                bf8 al = *(const bf8*)&Al[w * MF * 16 + mf * 16 + lr][kc * 32 + lk * 8];
#pragma unroll
                for (int nf = 0; nf < 4; ++nf) {
                    acc[mf][nf] = MFMA(ah, bhf[nf], acc[mf][nf]);
                    acc[mf][nf] = MFMA(ah, blf[nf], acc[mf][nf]);
                    acc[mf][nf] = MFMA(al, bhf[nf], acc[mf][nf]);
                }
            }
        }
    }

#pragma unroll
    for (int mf = 0; mf < MF; ++mf) {
#pragma unroll
        for (int nf = 0; nf < 4; ++nf) {
            int n = n0 + nf * 16 + lr;
            int mbase = m0 + w * MF * 16 + mf * 16 + lk * 4;
            if (EPI == 0) {
#pragma unroll
                for (int r = 0; r < 4; ++r)
                    outf[(size_t)(mbase + r) * ldo + n] = acc[mf][nf][r];
            } else if (EPI == 1) {
                float bv = bias[n];
#pragma unroll
                for (int r = 0; r < 4; ++r) {
                    float y = fmaxf(acc[mf][nf][r] + bv, 0.f);
                    short hv = f2bf(y);
                    size_t oi = (size_t)(mbase + r) * ldh + n;
                    ohi[oi] = hv;
                    olo[oi] = f2bf(y - bf2f(hv));
                }
            } else if (EPI == 2) {
#pragma unroll
                for (int r = 0; r < 4; ++r) {
                    float y = acc[mf][nf][r];
                    short hv = f2bf(y);
                    size_t oi = (size_t)(mbase + r) * ldh + n;
                    ohi[oi] = hv;
                    olo[oi] = f2bf(y - bf2f(hv));
                }
            } else {
                float bv = bias[n];
#pragma unroll
                for (int r = 0; r < 4; ++r) {
                    float y = acc[mf][nf][r] + bv;
                    outf[(size_t)(mbase + r) * ldo + n] = y;
                    short hv = f2bf(y);
                    size_t oi = (size_t)(mbase + r) * ldh + n;
                    ohi[oi] = hv;
                    olo[oi] = f2bf(y - bf2f(hv));
                }
            }
        }
    }
}

// ---------------------------------------------------------------------------
// MFMA flash attention (round-12 config) with P routed through a per-wave
// LDS buffer (1 ds_write_b128 + 2 ds_read_b128) instead of 8 ds_bpermute.
__global__ __launch_bounds__(512, 8) void k_attn(const short* __restrict__ qh,
                                                 const short* __restrict__ ql,
                                                 const float* __restrict__ bb,
                                                 short* __restrict__ ohi,
                                                 short* __restrict__ olo) {
    int bx = blockIdx.x;
    int qt = bx >> 7;            // 0..3; blocks sharing (n,head) same XCD
    int head = bx & 15;
    int n = (bx >> 4) & 7;
    int t = threadIdx.x;
    int w = t >> 6, l = t & 63;
    int lq = l & 15, lk = l >> 4;

    __shared__ __align__(16) short khl[256][40];   // [key][hi0-15|lo16-31|pad]
    __shared__ __align__(16) short vth[16][264];   // V^T hi: [d][key 0..255]
    __shared__ __align__(16) short vtl[16][264];   // V^T lo
    __shared__ __align__(16) float pw[8][16][20];  // per-wave P[q][key] buffer
    __shared__ float biasr[64];

    if (t < NBINSc) biasr[t] = bb[head * NBINSc + t];
    float bL = bb[head * NBINSc];
    float bR = bb[head * NBINSc + 48];

    size_t base = (size_t)n * Lc * 768 + head * 16;

    int qg = qt * 128 + w * 16 + lq;             // this lane's q column
    size_t qrow = ((size_t)n * Lc + qg) * 768 + head * 16;
    bf8 B1 = *(const bf8*)(qh + qrow + (lk & 1) * 8);   // [Qh|Qh]
    bf8 B2;
    if (lk < 2) B2 = *(const bf8*)(ql + qrow + lk * 8);  // [Ql|0]
    else {
#pragma unroll
        for (int i = 0; i < 8; ++i) B2[i] = 0;
    }

    f4 acc = (f4){0.f, 0.f, 0.f, 0.f};
    float m = -1e30f, lsum = 0.f;
    int rel0 = lk * 4 - qg;      // rel of s[0] at global kt=0; += 16 per tile

    for (int half = 0; half < 2; ++half) {
        __syncthreads();          // previous half fully consumed
        // stage K half (256 keys)
        for (int u = t; u < 1024; u += 512) {
            int key = u >> 2, seg = u & 3;
            const short* src = (seg < 2 ? qh : ql) + base + 256
                             + (size_t)(half * 256 + key) * 768 + (seg & 1) * 8;
            *(bf8*)&khl[key][seg * 8] = *(const bf8*)src;
        }
        // stage V half transposed, pair-packed b32 writes (1 item/thread)
        {
            int u = t & 127;             // key pair
            int dhalf = (t >> 7) & 1;    // d 0..7 / 8..15
            int hl = (t >> 8) & 1;       // hi / lo
            int gkey = half * 256 + u * 2;
            const short* vs = (hl ? ql : qh) + base + 512 + (size_t)gkey * 768 + dhalf * 8;
            bf8 A = *(const bf8*)vs;
            bf8 B = *(const bf8*)(vs + 768);
            unsigned* vw = (unsigned*)(hl ? &vtl[0][0] : &vth[0][0]);  // stride 132 words
#pragma unroll
            for (int i = 0; i < 8; ++i)
                vw[(dhalf * 8 + i) * 132 + u] =
                    (unsigned)(unsigned short)A[i] | ((unsigned)(unsigned short)B[i] << 16);
        }
        __syncthreads();

        for (int kt = 0; kt < 16; ++kt, rel0 += 16) {
            bf8 A1 = *(const bf8*)&khl[kt * 16 + lq][lk * 8];  // [Kh|Kl]
            f4 s = (f4){0.f, 0.f, 0.f, 0.f};
            __builtin_amdgcn_s_setprio(1);
            s = MFMA(A1, B1, s);      // KhQh + KlQh
            s = MFMA(A1, B2, s);      // KhQl
            __builtin_amdgcn_s_setprio(0);
            if (rel0 >= PMAXLc) {
                s[0] += bR; s[1] += bR; s[2] += bR; s[3] += bR;
            } else if (rel0 + 3 <= -PMAXLc) {
                s[0] += bL; s[1] += bL; s[2] += bL; s[3] += bL;
            } else {
#pragma unroll
                for (int r = 0; r < 4; ++r) {
                    int rel = rel0 + r;
                    rel = rel < -PMAXLc ? -PMAXLc : (rel > PMAXLc ? PMAXLc : rel);
                    s[r] += biasr[rel + PMAXLc];
                }
            }
            float mt = fmaxf(fmaxf(s[0], s[1]), fmaxf(s[2], s[3]));
            mt = fmaxf(mt, __shfl_xor(mt, 16));
            mt = fmaxf(mt, __shfl_xor(mt, 32));
            if (__any(mt > m + 8.0f)) {
                float mn = fmaxf(m, mt);
                float alpha = __expf(m - mn);
                m = mn;
                lsum *= alpha;
#pragma unroll
                for (int r = 0; r < 4; ++r) acc[r] *= __shfl(alpha, lk * 4 + r);
            }
            f4 p;
#pragma unroll
            for (int r = 0; r < 4; ++r) p[r] = __expf(s[r] - m);
            lsum += p[0] + p[1] + p[2] + p[3];
            // P routed via per-wave LDS: lane (lq,lk) writes P[q=lq][keys lk*4..+4];
            // reads P[q=lq][keys (lk&1)*8..+8] (wave-synchronous, no barrier).
            *(f4*)&pw[w][lq][lk * 4] = p;
            const float* pr = &pw[w][lq][(lk & 1) * 8];
            f4 ga = *(const f4*)pr;
            f4 gb = *(const f4*)(pr + 4);
            bf8 PA;
            if (lk < 2) {
#pragma unroll
                for (int jj = 0; jj < 4; ++jj) {
                    PA[jj]     = (short)(__float_as_uint(ga[jj]) >> 16);
                    PA[jj + 4] = (short)(__float_as_uint(gb[jj]) >> 16);
                }
            } else {
#pragma unroll
                for (int jj = 0; jj < 4; ++jj) {
                    unsigned hu0 = __float_as_uint(ga[jj]) & 0xFFFF0000u;
                    unsigned hu1 = __float_as_uint(gb[jj]) & 0xFFFF0000u;
                    PA[jj]     = (short)(__float_as_uint(ga[jj] - __uint_as_float(hu0)) >> 16);
                    PA[jj + 4] = (short)(__float_as_uint(gb[jj] - __uint_as_float(hu1)) >> 16);
                }
            }
            bf8 VB1 = *(const bf8*)&vth[lq][kt * 16 + (lk & 1) * 8];  // [Vh|Vh]
            bf8 VB2;
            if (lk < 2) VB2 = *(const bf8*)&vtl[lq][kt * 16 + lk * 8];  // [Vl|0]
            else {
#pragma unroll
                for (int i = 0; i < 8; ++i) VB2[i] = 0;
            }
            __builtin_amdgcn_s_setprio(1);
            acc = MFMA(PA, VB1, acc);   // PhVh + PlVh
            acc = MFMA(PA, VB2, acc);   // PhVl
            __builtin_amdgcn_s_setprio(0);
        }
    }

    float lred = lsum + __shfl_xor(lsum, 16);
    lred += __shfl_xor(lred, 32);
    float inv = 1.0f / lred;
#pragma unroll
    for (int r = 0; r < 4; ++r) {
        float iq = __shfl(inv, lk * 4 + r);
        float y = acc[r] * iq;
        int qo = qt * 128 + w * 16 + lk * 4 + r;
        size_t oi = ((size_t)n * Lc + qo) * DMc + head * 16 + lq;
        unsigned hu = __float_as_uint(y) & 0xFFFF0000u;
        ohi[oi] = (short)(hu >> 16);
        olo[oi] = (short)(__float_as_uint(y - __uint_as_float(hu)) >> 16);
    }
}

// ---------------------------------------------------------------------------
// LN over h + s2a + s2b + sbias, fully f4-vectorized. um stride = UMLD.
__global__ __launch_bounds__(256) void k_ln(const float* __restrict__ s2a,
                                            const float* __restrict__ s2b,
                                            const float* __restrict__ sbias,
                                            const float* __restrict__ g,
                                            const float* __restrict__ bta,
                                            float* __restrict__ h,
                                            short* __restrict__ umhi,
                                            short* __restrict__ umlo) {
    int t = threadIdx.x;
    int tl = t >> 5, j = t & 31;
    size_t gtok = (size_t)blockIdx.x * 8 + tl;
    int d0 = j * 8;
    size_t off = gtok * EMBEDc + d0;
    f4 h0 = *(const f4*)(h + off);
    f4 h1 = *(const f4*)(h + off + 4);
    f4 a0 = *(const f4*)(s2a + off);
    f4 a1 = *(const f4*)(s2a + off + 4);
    f4 b0 = *(const f4*)(s2b + off);
    f4 b1 = *(const f4*)(s2b + off + 4);
    f4 sb0 = *(const f4*)(sbias + d0);
    f4 sb1 = *(const f4*)(sbias + d0 + 4);
    f4 v0 = h0 + a0 + b0 + sb0;
    f4 v1 = h1 + a1 + b1 + sb1;
    float sum = v0[0] + v0[1] + v0[2] + v0[3] + v1[0] + v1[1] + v1[2] + v1[3];
    float ssq = v0[0]*v0[0] + v0[1]*v0[1] + v0[2]*v0[2] + v0[3]*v0[3]
              + v1[0]*v1[0] + v1[1]*v1[1] + v1[2]*v1[2] + v1[3]*v1[3];
#pragma unroll
    for (int off5 = 16; off5; off5 >>= 1) {
        sum += __shfl_xor(sum, off5, 32);
        ssq += __shfl_xor(ssq, off5, 32);
    }
    float mean = sum * (1.f / EMBEDc);
    float var = ssq * (1.f / EMBEDc) - mean * mean;
    float inv = rsqrtf(var + 1e-5f);
    f4 g0 = *(const f4*)(g + d0);
    f4 g1 = *(const f4*)(g + d0 + 4);
    f4 t0 = *(const f4*)(bta + d0);
    f4 t1 = *(const f4*)(bta + d0 + 4);
    f4 y0, y1;
    bf8 hv, lv;
#pragma unroll
    for (int q = 0; q < 4; ++q) {
        float y = (v0[q] - mean) * inv * g0[q] + t0[q];
        y0[q] = y;
        short hh = f2bf(y);
        hv[q] = hh;
        lv[q] = f2bf(y - bf2f(hh));
    }
#pragma unroll
    for (int q = 0; q < 4; ++q) {
        float y = (v1[q] - mean) * inv * g1[q] + t1[q];
        y1[q] = y;
        short hh = f2bf(y);
        hv[q + 4] = hh;
        lv[q + 4] = f2bf(y - bf2f(hh));
    }
    *(f4*)(h + off) = y0;
    *(f4*)(h + off + 4) = y1;
    *(bf8*)(umhi + gtok * UMLD + d0) = hv;
    *(bf8*)(umlo + gtok * UMLD + d0) = lv;
}

// ---------------------------------------------------------------------------
__global__ __launch_bounds__(256) void k_r(const short* __restrict__ fh,
                                           const short* __restrict__ fl,
                                           const float* __restrict__ w2,
                                           const float* __restrict__ b2,
                                           float* __restrict__ r) {
    __shared__ float w[3][EMBEDc];
    int t = threadIdx.x;
    for (int u = t; u < 3 * EMBEDc; u += 256) w[u >> 8][u & 255] = w2[u];
    __syncthreads();
    int tok = blockIdx.x * 64 + (t >> 2), o = t & 3;
    if (o < 3) {
        const short* ph = fh + (size_t)tok * EMBEDc;
        const short* pl = fl + (size_t)tok * EMBEDc;
        float s = b2[o];
        for (int c8 = 0; c8 < EMBEDc / 8; ++c8) {
            bf8 vh = *(const bf8*)(ph + c8 * 8);
            bf8 vl = *(const bf8*)(pl + c8 * 8);
#pragma unroll
            for (int j = 0; j < 8; ++j)
                s += (bf2f(vh[j]) + bf2f(vl[j])) * w[o][c8 * 8 + j];
        }
        r[(size_t)tok * 3 + o] = s;
    }
}

// ---------------------------------------------------------------------------
__global__ __launch_bounds__(256) void k_dmap(const float* __restrict__ r,
                                              float* __restrict__ d) {
    int b = blockIdx.x;
    int n = b / Lc;
    float xi = r[(size_t)b * 3], yi = r[(size_t)b * 3 + 1], zi = r[(size_t)b * 3 + 2];
    const float* rn = r + (size_t)n * Lc * 3;
    for (int j = threadIdx.x; j < Lc; j += 256) {
        float dx = xi - rn[j * 3];
        float dy = yi - rn[j * 3 + 1];
        float dz = zi - rn[j * 3 + 2];
        d[(size_t)b * Lc + j] = sqrtf(dx * dx + dy * dy + dz * dz + 1e-12f);
    }
}

// ---------------------------------------------------------------------------
extern "C" void kernel_launch(void* const* d_in, const int* in_sizes, int n_in,
                              void* d_out, int out_size, void* d_ws, size_t ws_size,
                              hipStream_t stream) {
    const float* z       = (const float*)d_in[0];
    const float* x       = (const float*)d_in[1];
    const float* pos_emb = (const float*)d_in[2];
    const float* aa_emb  = (const float*)d_in[3];
    const float* ex_w1   = (const float*)d_in[4];
    const float* ex_b1   = (const float*)d_in[5];
    const float* ex_w2   = (const float*)d_in[6];
    const float* ex_b2   = (const float*)d_in[7];
    const float* Wq      = (const float*)d_in[8];
    const float* Wk      = (const float*)d_in[9];
    const float* Wv      = (const float*)d_in[10];
    const float* Wo      = (const float*)d_in[11];
    const float* bo      = (const float*)d_in[12];
    const float* W2d     = (const float*)d_in[13];
    const float* b2d     = (const float*)d_in[14];
    const float* Wf1     = (const float*)d_in[15];
    const float* bf1     = (const float*)d_in[16];
    const float* Wf2     = (const float*)d_in[17];
    const float* bf2     = (const float*)d_in[18];
    const float* ln1_g   = (const float*)d_in[19];
    const float* ln1_b   = (const float*)d_in[20];
    const float* ln2_g   = (const float*)d_in[21];
    const float* ln2_b   = (const float*)d_in[22];
    const float* o_w1    = (const float*)d_in[23];
    const float* o_b1    = (const float*)d_in[24];
    const float* o_w2    = (const float*)d_in[25];
    const float* o_b2    = (const float*)d_in[26];

    float* h    = (float*)d_ws;                    // 4096*256
    float* s2a  = h + (size_t)NTOK * EMBEDc;
    float* s2b  = s2a + (size_t)NTOK * EMBEDc;
    float* bbuf = s2b + (size_t)NTOK * EMBEDc;     // pad 8192
    float* r    = bbuf + 8192;                     // pad 16384
    short* qkvh = (short*)(r + 16384);             // 4096*768
    short* qkvl = qkvh + (size_t)NTOK * 768;
    short* um_hi = qkvl + (size_t)NTOK * 768;      // 4096*320 (padded)
    short* um_lo = um_hi + (size_t)NTOK * UMLD;
    short* o_hi  = um_lo + (size_t)NTOK * UMLD;    // 4096*256
    short* o_lo  = o_hi + (size_t)NTOK * EMBEDc;
    short* f1_hi = o_lo + (size_t)NTOK * EMBEDc;   // 4096*1024
    short* f1_lo = f1_hi + (size_t)NTOK * DFFc;
    short* wqkv_hi = f1_lo + (size_t)NTOK * DFFc;  // 6*768*256
    short* wqkv_lo = wqkv_hi + (size_t)NLc * 768 * EMBEDc;
    short* wo_hi   = wqkv_lo + (size_t)NLc * 768 * EMBEDc;   // 6*256*256
    short* wo_lo   = wo_hi + (size_t)NLc * EMBEDc * DMc;
    short* wf1_hi  = wo_lo + (size_t)NLc * EMBEDc * DMc;     // 6*1024*320 (padded)
    short* wf1_lo  = wf1_hi + (size_t)NLc * DFFc * UMLD;
    short* wf2_hi  = wf1_lo + (size_t)NLc * DFFc * UMLD;     // 6*256*1024
    short* wf2_lo  = wf2_hi + (size_t)NLc * EMBEDc * DFFc;
    short* wex1_hi = wf2_lo + (size_t)NLc * EMBEDc * DFFc;   // 256*64
    short* wex1_lo = wex1_hi + EMBEDc * NZc;
    short* wex2_hi = wex1_lo + EMBEDc * NZc;                 // 256*256
    short* wex2_lo = wex2_hi + EMBEDc * EMBEDc;
    short* wo1_hi  = wex2_lo + EMBEDc * EMBEDc;              // 256*256
    short* wo1_lo  = wo1_hi + EMBEDc * EMBEDc;
    // zt aliases the o buffer (only used in preamble, before k_attn writes o)
    short* zt_hi = o_hi;
    short* zt_lo = o_lo;

    k_pre<<<1024, 256, 0, stream>>>(Wq, Wk, Wv, Wo, Wf1, Wf2, ex_w1, ex_w2, o_w1,
                                    pos_emb, W2d, b2d, x, aa_emb, z,
                                    wqkv_hi, wqkv_lo, wo_hi, wo_lo,
                                    wf1_hi, wf1_lo, wf2_hi, wf2_lo,
                                    wex1_hi, wex1_lo, wex2_hi, wex2_lo,
                                    wo1_hi, wo1_lo, bbuf, um_hi, um_lo,
                                    zt_hi, zt_lo);

    // embed: relu GEMM -> GEMM (fp32 h + bf16 um, ldh = UMLD)
    k_gemm3<1, 1, 0, 64><<<256, 256, 0, stream>>>(
        zt_hi, zt_lo, NZc, wex1_hi, wex1_lo, NZc, NZc,
        nullptr, 0, f1_hi, f1_lo, EMBEDc, ex_b1, 4, 8);
    k_gemm3<3, 1, 0, 64><<<256, 256, 0, stream>>>(
        f1_hi, f1_lo, EMBEDc, wex2_hi, wex2_lo, EMBEDc, EMBEDc,
        h, EMBEDc, um_hi, um_lo, UMLD, ex_b2, 4, 8);

    for (int l = 0; l < NLc; ++l) {
        // qkv: MF=1, 768 blocks = 3/CU balanced
        k_gemm3<2, 1, 0, 64><<<768, 256, 0, stream>>>(
            um_hi, um_lo, UMLD,
            wqkv_hi + (size_t)l * 768 * EMBEDc, wqkv_lo + (size_t)l * 768 * EMBEDc, EMBEDc,
            EMBEDc, nullptr, 0, qkvh, qkvl, 768, nullptr, 12, 8);
        k_attn<<<NB * NHc * 4, 512, 0, stream>>>(qkvh, qkvl, bbuf + (size_t)l * NHc * NBINSc, o_hi, o_lo);
        k_gemm3<0, 1, 8, 64><<<512, 256, 0, stream>>>(
            o_hi, o_lo, EMBEDc,
            wo_hi + (size_t)l * EMBEDc * DMc, wo_lo + (size_t)l * EMBEDc * DMc, DMc,
            128, s2a, EMBEDc, nullptr, nullptr, 0, nullptr, 4, 8);
        k_ln<<<NTOK / 8, 256, 0, stream>>>(s2a, s2b, bo + (size_t)l * EMBEDc,
                                           ln1_g + (size_t)l * EMBEDc, ln1_b + (size_t)l * EMBEDc,
                                           h, um_hi, um_lo);
        // ffn1: K padded 288->320, BK=64
        k_gemm3<1, 2, 0, 64><<<512, 256, 0, stream>>>(
            um_hi, um_lo, UMLD,
            wf1_hi + (size_t)l * DFFc * UMLD, wf1_lo + (size_t)l * DFFc * UMLD, UMLD,
            UMLD, nullptr, 0, f1_hi, f1_lo, DFFc, bf1 + (size_t)l * DFFc, 16, 4);
        k_gemm3<0, 1, 8, 64><<<512, 256, 0, stream>>>(
            f1_hi, f1_lo, DFFc,
            wf2_hi + (size_t)l * EMBEDc * DFFc, wf2_lo + (size_t)l * EMBEDc * DFFc, DFFc,
            512, s2a, EMBEDc, nullptr, nullptr, 0, nullptr, 4, 8);
        k_ln<<<NTOK / 8, 256, 0, stream>>>(s2a, s2b, bf2 + (size_t)l * EMBEDc,
                                           ln2_g + (size_t)l * EMBEDc, ln2_b + (size_t)l * EMBEDc,
                                           h, um_hi, um_lo);
    }

    // final: f = relu(um @ o_w1^T + o_b1) (um cols 0..255 hold h in bf16)
    k_gemm3<1, 1, 0, 64><<<256, 256, 0, stream>>>(
        um_hi, um_lo, UMLD, wo1_hi, wo1_lo, EMBEDc, EMBEDc,
        nullptr, 0, f1_hi, f1_lo, EMBEDc, o_b1, 4, 8);
    k_r<<<NTOK / 64, 256, 0, stream>>>(f1_hi, f1_lo, o_w2, o_b2, r);
    k_dmap<<<NB * Lc, 256, 0, stream>>>(r, (float*)d_out);
}

// Round 17
// 541.634 us; speedup vs baseline: 1.1127x; 1.0183x over previous
//
#include <hip/hip_runtime.h>
#include <math.h>

#define NZc     64
#define EMBEDc  256
#define DMc     256
#define NHc     16
#define HDc     16
#define DFFc    1024
#define NLc     6
#define E1Dc    32
#define PDIMc   64
#define PMAXLc  24
#define NBINSc  49
#define NB      8
#define Lc      512
#define NTOK    (NB * Lc)        // 4096
#define UMDIM   288              // logical um width
#define UMLD    320              // padded leading dim (zeros in 288..319)

typedef __attribute__((ext_vector_type(4))) float f4;
typedef __attribute__((ext_vector_type(8))) short bf8;   // 8 bf16 in 4 VGPRs

#define MFMA(a, b, c) __builtin_amdgcn_mfma_f32_16x16x32_bf16((a), (b), (c), 0, 0, 0)

__device__ __forceinline__ short f2bf(float f) {
    unsigned u = __float_as_uint(f);
    u += 0x7FFFu + ((u >> 16) & 1u);   // round-to-nearest-even
    return (short)(u >> 16);
}
__device__ __forceinline__ float bf2f(short s) {
    return __uint_as_float(((unsigned)(unsigned short)s) << 16);
}

// ---------------------------------------------------------------------------
// preamble: weight conversions (x8 vectorized) + bias bins + e_aa + z^T.
// Wf1 rows remapped 288 -> 320 stride; pad cols zero-filled (um + wf1).
__global__ void k_pre(const float* __restrict__ Wq, const float* __restrict__ Wk,
                      const float* __restrict__ Wv, const float* __restrict__ Wo,
                      const float* __restrict__ Wf1, const float* __restrict__ Wf2,
                      const float* __restrict__ exw1, const float* __restrict__ exw2,
                      const float* __restrict__ ow1,
                      const float* __restrict__ pos_emb, const float* __restrict__ W2d,
                      const float* __restrict__ b2d, const float* __restrict__ x,
                      const float* __restrict__ aa_emb, const float* __restrict__ z,
                      short* __restrict__ wqkv_hi, short* __restrict__ wqkv_lo,
                      short* __restrict__ wo_hi, short* __restrict__ wo_lo,
                      short* __restrict__ wf1_hi, short* __restrict__ wf1_lo,
                      short* __restrict__ wf2_hi, short* __restrict__ wf2_lo,
                      short* __restrict__ wex1_hi, short* __restrict__ wex1_lo,
                      short* __restrict__ wex2_hi, short* __restrict__ wex2_lo,
                      short* __restrict__ wo1_hi, short* __restrict__ wo1_lo,
                      float* __restrict__ bb,
                      short* __restrict__ umhi, short* __restrict__ umlo,
                      short* __restrict__ zth, short* __restrict__ ztl) {
    int stride = gridDim.x * blockDim.x;
    int tid = blockIdx.x * blockDim.x + threadIdx.x;
#define CVT(src, hi, lo, per_layer, dstride, doff, scale, total)               \
    for (int i = tid; i < (total) / 8; i += stride) {                          \
        int ib = i * 8;                                                        \
        int ll = ib / (per_layer), rels = ib - ll * (per_layer);               \
        size_t di = (size_t)ll * (dstride) + (doff) + rels;                    \
        f4 v0 = *(const f4*)(src + ib);                                        \
        f4 v1 = *(const f4*)(src + ib + 4);                                    \
        bf8 hv, lv;                                                            \
        _Pragma("unroll")                                                      \
        for (int q = 0; q < 4; ++q) {                                          \
            float v = v0[q] * (scale);                                         \
            short hh = f2bf(v);                                                \
            hv[q] = hh;                                                        \
            lv[q] = f2bf(v - bf2f(hh));                                        \
        }                                                                      \
        _Pragma("unroll")                                                      \
        for (int q = 0; q < 4; ++q) {                                          \
            float v = v1[q] * (scale);                                         \
            short hh = f2bf(v);                                                \
            hv[q + 4] = hh;                                                    \
            lv[q + 4] = f2bf(v - bf2f(hh));                                    \
        }                                                                      \
        *(bf8*)(hi + di) = hv;                                                 \
        *(bf8*)(lo + di) = lv;                                                 \
    }
    CVT(Wq,  wqkv_hi, wqkv_lo, 65536, 196608, 0,      0.0625f, 393216);
    CVT(Wk,  wqkv_hi, wqkv_lo, 65536, 196608, 65536,  1.f,     393216);
    CVT(Wv,  wqkv_hi, wqkv_lo, 65536, 196608, 131072, 1.f,     393216);
    CVT(Wo,  wo_hi,  wo_lo,  65536,  65536,  0, 1.f, 393216);
    CVT(Wf2, wf2_hi, wf2_lo, 262144, 262144, 0, 1.f, 1572864);
    CVT(exw1, wex1_hi, wex1_lo, 16384, 16384, 0, 1.f, 16384);
    CVT(exw2, wex2_hi, wex2_lo, 65536, 65536, 0, 1.f, 65536);
    CVT(ow1,  wo1_hi,  wo1_lo,  65536, 65536, 0, 1.f, 65536);
#undef CVT
    // Wf1: src rows of 288 -> dest rows of 320 (row boundary 8-aligned)
    for (int i = tid; i < 1769472 / 8; i += stride) {
        int ib = i * 8;
        int ll = ib / 294912, rels = ib - ll * 294912;
        int row = rels / 288, col = rels - row * 288;
        size_t di = (size_t)ll * (1024 * UMLD) + (size_t)row * UMLD + col;
        f4 v0 = *(const f4*)(Wf1 + ib);
        f4 v1 = *(const f4*)(Wf1 + ib + 4);
        bf8 hv, lv;
#pragma unroll
        for (int q = 0; q < 4; ++q) {
            float v = v0[q];
            short hh = f2bf(v);
            hv[q] = hh;
            lv[q] = f2bf(v - bf2f(hh));
        }
#pragma unroll
        for (int q = 0; q < 4; ++q) {
            float v = v1[q];
            short hh = f2bf(v);
            hv[q + 4] = hh;
            lv[q + 4] = f2bf(v - bf2f(hh));
        }
        *(bf8*)(wf1_hi + di) = hv;
        *(bf8*)(wf1_lo + di) = lv;
    }
    // zero pad cols 288..319: wf1 (6144 rows) and um (4096 rows)
    {
        bf8 zz;
#pragma unroll
        for (int q = 0; q < 8; ++q) zz[q] = 0;
        for (int i = tid; i < 6144 * 4; i += stride) {
            int row = i >> 2, seg = i & 3;
            size_t di = (size_t)row * UMLD + UMDIM + seg * 8;
            *(bf8*)(wf1_hi + di) = zz;
            *(bf8*)(wf1_lo + di) = zz;
        }
        for (int i = tid; i < 4096 * 4; i += stride) {
            int row = i >> 2, seg = i & 3;
            size_t di = (size_t)row * UMLD + UMDIM + seg * 8;
            *(bf8*)(umhi + di) = zz;
            *(bf8*)(umlo + di) = zz;
        }
    }
    for (int idx = tid; idx < NLc * NHc * NBINSc; idx += stride) {
        int bin = idx % NBINSc;
        int tmp = idx / NBINSc;
        int hh = tmp % NHc, l = tmp / NHc;
        float s = b2d[l * NHc + hh];
        const float* pe = pos_emb + bin * PDIMc;
        const float* w  = W2d + (l * NHc + hh) * PDIMc;
        for (int p = 0; p < PDIMc; ++p) s += pe[p] * w[p];
        bb[idx] = s;
    }
    for (int tok = tid; tok < NTOK; tok += stride) {
        int n = tok / Lc, l = tok % Lc;
        const float* xp = x + (size_t)n * 20 * Lc + l;
        float best = xp[0];
        int bi = 0;
        for (int c = 1; c < 20; ++c) {
            float v = xp[c * Lc];
            if (v > best) { best = v; bi = c; }
        }
        const float* e = aa_emb + bi * E1Dc;
        bf8 hv, lv;
        for (int c8 = 0; c8 < E1Dc / 8; ++c8) {
#pragma unroll
            for (int q = 0; q < 8; ++q) {
                float v = e[c8 * 8 + q];
                short hh = f2bf(v);
                hv[q] = hh;
                lv[q] = f2bf(v - bf2f(hh));
            }
            *(bf8*)(umhi + (size_t)tok * UMLD + EMBEDc + c8 * 8) = hv;
            *(bf8*)(umlo + (size_t)tok * UMLD + EMBEDc + c8 * 8) = lv;
        }
    }
    for (int tok = tid; tok < NTOK; tok += stride) {
        int n = tok >> 9, l = tok & 511;
        bf8 hv, lv;
        for (int c8 = 0; c8 < NZc / 8; ++c8) {
#pragma unroll
            for (int q = 0; q < 8; ++q) {
                float v = z[((size_t)n * NZc + c8 * 8 + q) * Lc + l];
                short hh = f2bf(v);
                hv[q] = hh;
                lv[q] = f2bf(v - bf2f(hh));
            }
            *(bf8*)(zth + (size_t)tok * NZc + c8 * 8) = hv;
            *(bf8*)(ztl + (size_t)tok * NZc + c8 * 8) = lv;
        }
    }
}

// ---------------------------------------------------------------------------
// LDS-staged MFMA GEMM. TERMS=3: full compensated (AhBh+AhBl+AlBh).
// TERMS=2: drop AlBh (A effectively bf16) - used for qkv only (softmax-damped).
template <int EPI, int MF, int SKSHIFT, int BK, int TERMS>
__global__ __launch_bounds__(256) void k_gemm3(
    const short* __restrict__ Ahi, const short* __restrict__ Alo, int lda,
    const short* __restrict__ Bhi, const short* __restrict__ Blo, int ldb,
    int K, float* __restrict__ outf, int ldo, short* __restrict__ ohi,
    short* __restrict__ olo, int ldh, const float* __restrict__ bias,
    int gx, int gypx) {
    constexpr int PAD = BK + 8;
    __shared__ __align__(16) short Ah[MF * 64][PAD];
    __shared__ __align__(16) short Al[TERMS == 3 ? MF * 64 : 1][TERMS == 3 ? PAD : 1];
    __shared__ __align__(16) short Bh[64][PAD];
    __shared__ __align__(16) short Bl[64][PAD];

    int bid = blockIdx.x;
    int koff = 0;
    if (SKSHIFT) {
        int kh = bid >> SKSHIFT;
        bid &= (1 << SKSHIFT) - 1;
        koff = kh * K;
        outf += (size_t)kh * NTOK * EMBEDc;
    }
    int xcd = bid & 7, j = bid >> 3;
    int bx = j % gx, by = xcd * gypx + j / gx;

    int t = threadIdx.x;
    int w = t >> 6, l = t & 63, lr = l & 15, lk = l >> 4;
    int m0 = by * (MF * 64);
    int n0 = bx * 64;

    constexpr int TPR = BK / 8;
    constexpr int RP  = 256 / TPR;
    constexpr int AP  = MF * 64 / RP;
    constexpr int BP  = 64 / RP;
    int srow = t / TPR, scol = (t % TPR) * 8;

    const short* pa  = Ahi + (size_t)(m0 + srow) * lda + koff + scol;
    const short* pal = Alo + (size_t)(m0 + srow) * lda + koff + scol;
    const short* pb  = Bhi + (size_t)(n0 + srow) * ldb + koff + scol;
    const short* pbl = Blo + (size_t)(n0 + srow) * ldb + koff + scol;

    bf8 ra[AP], rla[AP], rb[BP], rlb[BP];
#pragma unroll
    for (int p = 0; p < AP; ++p) {
        ra[p] = *(const bf8*)(pa + (size_t)p * RP * lda);
        if (TERMS == 3) rla[p] = *(const bf8*)(pal + (size_t)p * RP * lda);
    }
#pragma unroll
    for (int p = 0; p < BP; ++p) {
        rb[p]  = *(const bf8*)(pb  + (size_t)p * RP * ldb);
        rlb[p] = *(const bf8*)(pbl + (size_t)p * RP * ldb);
    }

    f4 acc[MF][4];
#pragma unroll
    for (int mf = 0; mf < MF; ++mf)
#pragma unroll
        for (int nf = 0; nf < 4; ++nf) acc[mf][nf] = (f4){0.f, 0.f, 0.f, 0.f};

    for (int ks = 0; ks < K; ks += BK) {
        __syncthreads();
#pragma unroll
        for (int p = 0; p < AP; ++p) {
            *(bf8*)&Ah[p * RP + srow][scol] = ra[p];
            if (TERMS == 3) *(bf8*)&Al[p * RP + srow][scol] = rla[p];
        }
#pragma unroll
        for (int p = 0; p < BP; ++p) {
            *(bf8*)&Bh[p * RP + srow][scol] = rb[p];
            *(bf8*)&Bl[p * RP + srow][scol] = rlb[p];
        }
        __syncthreads();
        if (ks + BK < K) {
#pragma unroll
            for (int p = 0; p < AP; ++p) {
                ra[p] = *(const bf8*)(pa + (size_t)p * RP * lda + ks + BK);
                if (TERMS == 3) rla[p] = *(const bf8*)(pal + (size_t)p * RP * lda + ks + BK);
            }
#pragma unroll
            for (int p = 0; p < BP; ++p) {
                rb[p]  = *(const bf8*)(pb  + (size_t)p * RP * ldb + ks + BK);
                rlb[p] = *(const bf8*)(pbl + (size_t)p * RP * ldb + ks + BK);
            }
        }
#pragma unroll
        for (int kc = 0; kc < BK / 32; ++kc) {
            bf8 bhf[4], blf[4];
#pragma unroll
            for (int nf = 0; nf < 4; ++nf) {
                bhf[nf] = *(const bf8*)&Bh[nf * 16 + lr][kc * 32 + lk * 8];
                blf[nf] = *(const bf8*)&Bl[nf * 16 + lr][kc * 32 + lk * 8];
            }
#pragma unroll
            for (int mf = 0; mf < MF; ++mf) {
                bf8 ah = *(const bf8*)&Ah[w * MF * 16 + mf * 16 + lr][kc * 32 + lk * 8];
                bf8 al;
                if (TERMS == 3) al = *(const bf8*)&Al[w * MF * 16 + mf * 16 + lr][kc * 32 + lk * 8];
#pragma unroll
                for (int nf = 0; nf < 4; ++nf) {
                    acc[mf][nf] = MFMA(ah, bhf[nf], acc[mf][nf]);
                    acc[mf][nf] = MFMA(ah, blf[nf], acc[mf][nf]);
                    if (TERMS == 3) acc[mf][nf] = MFMA(al, bhf[nf], acc[mf][nf]);
                }
            }
        }
    }

#pragma unroll
    for (int mf = 0; mf < MF; ++mf) {
#pragma unroll
        for (int nf = 0; nf < 4; ++nf) {
            int n = n0 + nf * 16 + lr;
            int mbase = m0 + w * MF * 16 + mf * 16 + lk * 4;
            if (EPI == 0) {
#pragma unroll
                for (int r = 0; r < 4; ++r)
                    outf[(size_t)(mbase + r) * ldo + n] = acc[mf][nf][r];
            } else if (EPI == 1) {
                float bv = bias[n];
#pragma unroll
                for (int r = 0; r < 4; ++r) {
                    float y = fmaxf(acc[mf][nf][r] + bv, 0.f);
                    short hv = f2bf(y);
                    size_t oi = (size_t)(mbase + r) * ldh + n;
                    ohi[oi] = hv;
                    olo[oi] = f2bf(y - bf2f(hv));
                }
            } else if (EPI == 2) {
#pragma unroll
                for (int r = 0; r < 4; ++r) {
                    float y = acc[mf][nf][r];
                    short hv = f2bf(y);
                    size_t oi = (size_t)(mbase + r) * ldh + n;
                    ohi[oi] = hv;
                    olo[oi] = f2bf(y - bf2f(hv));
                }
            } else {
                float bv = bias[n];
#pragma unroll
                for (int r = 0; r < 4; ++r) {
                    float y = acc[mf][nf][r] + bv;
                    outf[(size_t)(mbase + r) * ldo + n] = y;
                    short hv = f2bf(y);
                    size_t oi = (size_t)(mbase + r) * ldh + n;
                    ohi[oi] = hv;
                    olo[oi] = f2bf(y - bf2f(hv));
                }
            }
        }
    }
}

// ---------------------------------------------------------------------------
// MFMA flash attention (round-16 config): LDS-routed P redistribution.
__global__ __launch_bounds__(512, 8) void k_attn(const short* __restrict__ qh,
                                                 const short* __restrict__ ql,
                                                 const float* __restrict__ bb,
                                                 short* __restrict__ ohi,
                                                 short* __restrict__ olo) {
    int bx = blockIdx.x;
    int qt = bx >> 7;            // 0..3; blocks sharing (n,head) same XCD
    int head = bx & 15;
    int n = (bx >> 4) & 7;
    int t = threadIdx.x;
    int w = t >> 6, l = t & 63;
    int lq = l & 15, lk = l >> 4;

    __shared__ __align__(16) short khl[256][40];   // [key][hi0-15|lo16-31|pad]
    __shared__ __align__(16) short vth[16][264];   // V^T hi: [d][key 0..255]
    __shared__ __align__(16) short vtl[16][264];   // V^T lo
    __shared__ __align__(16) float pw[8][16][20];  // per-wave P[q][key] buffer
    __shared__ float biasr[64];

    if (t < NBINSc) biasr[t] = bb[head * NBINSc + t];
    float bL = bb[head * NBINSc];
    float bR = bb[head * NBINSc + 48];

    size_t base = (size_t)n * Lc * 768 + head * 16;

    int qg = qt * 128 + w * 16 + lq;             // this lane's q column
    size_t qrow = ((size_t)n * Lc + qg) * 768 + head * 16;
    bf8 B1 = *(const bf8*)(qh + qrow + (lk & 1) * 8);   // [Qh|Qh]
    bf8 B2;
    if (lk < 2) B2 = *(const bf8*)(ql + qrow + lk * 8);  // [Ql|0]
    else {
#pragma unroll
        for (int i = 0; i < 8; ++i) B2[i] = 0;
    }

    f4 acc = (f4){0.f, 0.f, 0.f, 0.f};
    float m = -1e30f, lsum = 0.f;
    int rel0 = lk * 4 - qg;      // rel of s[0] at global kt=0; += 16 per tile

    for (int half = 0; half < 2; ++half) {
        __syncthreads();          // previous half fully consumed
        // stage K half (256 keys)
        for (int u = t; u < 1024; u += 512) {
            int key = u >> 2, seg = u & 3;
            const short* src = (seg < 2 ? qh : ql) + base + 256
                             + (size_t)(half * 256 + key) * 768 + (seg & 1) * 8;
            *(bf8*)&khl[key][seg * 8] = *(const bf8*)src;
        }
        // stage V half transposed, pair-packed b32 writes (1 item/thread)
        {
            int u = t & 127;             // key pair
            int dhalf = (t >> 7) & 1;    // d 0..7 / 8..15
            int hl = (t >> 8) & 1;       // hi / lo
            int gkey = half * 256 + u * 2;
            const short* vs = (hl ? ql : qh) + base + 512 + (size_t)gkey * 768 + dhalf * 8;
            bf8 A = *(const bf8*)vs;
            bf8 B = *(const bf8*)(vs + 768);
            unsigned* vw = (unsigned*)(hl ? &vtl[0][0] : &vth[0][0]);  // stride 132 words
#pragma unroll
            for (int i = 0; i < 8; ++i)
                vw[(dhalf * 8 + i) * 132 + u] =
                    (unsigned)(unsigned short)A[i] | ((unsigned)(unsigned short)B[i] << 16);
        }
        __syncthreads();

        for (int kt = 0; kt < 16; ++kt, rel0 += 16) {
            bf8 A1 = *(const bf8*)&khl[kt * 16 + lq][lk * 8];  // [Kh|Kl]
            f4 s = (f4){0.f, 0.f, 0.f, 0.f};
            __builtin_amdgcn_s_setprio(1);
            s = MFMA(A1, B1, s);      // KhQh + KlQh
            s = MFMA(A1, B2, s);      // KhQl
            __builtin_amdgcn_s_setprio(0);
            if (rel0 >= PMAXLc) {
                s[0] += bR; s[1] += bR; s[2] += bR; s[3] += bR;
            } else if (rel0 + 3 <= -PMAXLc) {
                s[0] += bL; s[1] += bL; s[2] += bL; s[3] += bL;
            } else {
#pragma unroll
                for (int r = 0; r < 4; ++r) {
                    int rel = rel0 + r;
                    rel = rel < -PMAXLc ? -PMAXLc : (rel > PMAXLc ? PMAXLc : rel);
                    s[r] += biasr[rel + PMAXLc];
                }
            }
            float mt = fmaxf(fmaxf(s[0], s[1]), fmaxf(s[2], s[3]));
            mt = fmaxf(mt, __shfl_xor(mt, 16));
            mt = fmaxf(mt, __shfl_xor(mt, 32));
            if (__any(mt > m + 8.0f)) {
                float mn = fmaxf(m, mt);
                float alpha = __expf(m - mn);
                m = mn;
                lsum *= alpha;
#pragma unroll
                for (int r = 0; r < 4; ++r) acc[r] *= __shfl(alpha, lk * 4 + r);
            }
            f4 p;
#pragma unroll
            for (int r = 0; r < 4; ++r) p[r] = __expf(s[r] - m);
            lsum += p[0] + p[1] + p[2] + p[3];
            // P routed via per-wave LDS (wave-synchronous, no barrier)
            *(f4*)&pw[w][lq][lk * 4] = p;
            const float* pr = &pw[w][lq][(lk & 1) * 8];
            f4 ga = *(const f4*)pr;
            f4 gb = *(const f4*)(pr + 4);
            bf8 PA;
            if (lk < 2) {
#pragma unroll
                for (int jj = 0; jj < 4; ++jj) {
                    PA[jj]     = (short)(__float_as_uint(ga[jj]) >> 16);
                    PA[jj + 4] = (short)(__float_as_uint(gb[jj]) >> 16);
                }
            } else {
#pragma unroll
                for (int jj = 0; jj < 4; ++jj) {
                    unsigned hu0 = __float_as_uint(ga[jj]) & 0xFFFF0000u;
                    unsigned hu1 = __float_as_uint(gb[jj]) & 0xFFFF0000u;
                    PA[jj]     = (short)(__float_as_uint(ga[jj] - __uint_as_float(hu0)) >> 16);
                    PA[jj + 4] = (short)(__float_as_uint(gb[jj] - __uint_as_float(hu1)) >> 16);
                }
            }
            bf8 VB1 = *(const bf8*)&vth[lq][kt * 16 + (lk & 1) * 8];  // [Vh|Vh]
            bf8 VB2;
            if (lk < 2) VB2 = *(const bf8*)&vtl[lq][kt * 16 + lk * 8];  // [Vl|0]
            else {
#pragma unroll
                for (int i = 0; i < 8; ++i) VB2[i] = 0;
            }
            __builtin_amdgcn_s_setprio(1);
            acc = MFMA(PA, VB1, acc);   // PhVh + PlVh
            acc = MFMA(PA, VB2, acc);   // PhVl
            __builtin_amdgcn_s_setprio(0);
        }
    }

    float lred = lsum + __shfl_xor(lsum, 16);
    lred += __shfl_xor(lred, 32);
    float inv = 1.0f / lred;
#pragma unroll
    for (int r = 0; r < 4; ++r) {
        float iq = __shfl(inv, lk * 4 + r);
        float y = acc[r] * iq;
        int qo = qt * 128 + w * 16 + lk * 4 + r;
        size_t oi = ((size_t)n * Lc + qo) * DMc + head * 16 + lq;
        unsigned hu = __float_as_uint(y) & 0xFFFF0000u;
        ohi[oi] = (short)(hu >> 16);
        olo[oi] = (short)(__float_as_uint(y - __uint_as_float(hu)) >> 16);
    }
}

// ---------------------------------------------------------------------------
// LN over h + s2a + s2b + sbias, fully f4-vectorized. um stride = UMLD.
__global__ __launch_bounds__(256) void k_ln(const float* __restrict__ s2a,
                                            const float* __restrict__ s2b,
                                            const float* __restrict__ sbias,
                                            const float* __restrict__ g,
                                            const float* __restrict__ bta,
                                            float* __restrict__ h,
                                            short* __restrict__ umhi,
                                            short* __restrict__ umlo) {
    int t = threadIdx.x;
    int tl = t >> 5, j = t & 31;
    size_t gtok = (size_t)blockIdx.x * 8 + tl;
    int d0 = j * 8;
    size_t off = gtok * EMBEDc + d0;
    f4 h0 = *(const f4*)(h + off);
    f4 h1 = *(const f4*)(h + off + 4);
    f4 a0 = *(const f4*)(s2a + off);
    f4 a1 = *(const f4*)(s2a + off + 4);
    f4 b0 = *(const f4*)(s2b + off);
    f4 b1 = *(const f4*)(s2b + off + 4);
    f4 sb0 = *(const f4*)(sbias + d0);
    f4 sb1 = *(const f4*)(sbias + d0 + 4);
    f4 v0 = h0 + a0 + b0 + sb0;
    f4 v1 = h1 + a1 + b1 + sb1;
    float sum = v0[0] + v0[1] + v0[2] + v0[3] + v1[0] + v1[1] + v1[2] + v1[3];
    float ssq = v0[0]*v0[0] + v0[1]*v0[1] + v0[2]*v0[2] + v0[3]*v0[3]
              + v1[0]*v1[0] + v1[1]*v1[1] + v1[2]*v1[2] + v1[3]*v1[3];
#pragma unroll
    for (int off5 = 16; off5; off5 >>= 1) {
        sum += __shfl_xor(sum, off5, 32);
        ssq += __shfl_xor(ssq, off5, 32);
    }
    float mean = sum * (1.f / EMBEDc);
    float var = ssq * (1.f / EMBEDc) - mean * mean;
    float inv = rsqrtf(var + 1e-5f);
    f4 g0 = *(const f4*)(g + d0);
    f4 g1 = *(const f4*)(g + d0 + 4);
    f4 t0 = *(const f4*)(bta + d0);
    f4 t1 = *(const f4*)(bta + d0 + 4);
    f4 y0, y1;
    bf8 hv, lv;
#pragma unroll
    for (int q = 0; q < 4; ++q) {
        float y = (v0[q] - mean) * inv * g0[q] + t0[q];
        y0[q] = y;
        short hh = f2bf(y);
        hv[q] = hh;
        lv[q] = f2bf(y - bf2f(hh));
    }
#pragma unroll
    for (int q = 0; q < 4; ++q) {
        float y = (v1[q] - mean) * inv * g1[q] + t1[q];
        y1[q] = y;
        short hh = f2bf(y);
        hv[q + 4] = hh;
        lv[q + 4] = f2bf(y - bf2f(hh));
    }
    *(f4*)(h + off) = y0;
    *(f4*)(h + off + 4) = y1;
    *(bf8*)(umhi + gtok * UMLD + d0) = hv;
    *(bf8*)(umlo + gtok * UMLD + d0) = lv;
}

// ---------------------------------------------------------------------------
__global__ __launch_bounds__(256) void k_r(const short* __restrict__ fh,
                                           const short* __restrict__ fl,
                                           const float* __restrict__ w2,
                                           const float* __restrict__ b2,
                                           float* __restrict__ r) {
    __shared__ float w[3][EMBEDc];
    int t = threadIdx.x;
    for (int u = t; u < 3 * EMBEDc; u += 256) w[u >> 8][u & 255] = w2[u];
    __syncthreads();
    int tok = blockIdx.x * 64 + (t >> 2), o = t & 3;
    if (o < 3) {
        const short* ph = fh + (size_t)tok * EMBEDc;
        const short* pl = fl + (size_t)tok * EMBEDc;
        float s = b2[o];
        for (int c8 = 0; c8 < EMBEDc / 8; ++c8) {
            bf8 vh = *(const bf8*)(ph + c8 * 8);
            bf8 vl = *(const bf8*)(pl + c8 * 8);
#pragma unroll
            for (int j = 0; j < 8; ++j)
                s += (bf2f(vh[j]) + bf2f(vl[j])) * w[o][c8 * 8 + j];
        }
        r[(size_t)tok * 3 + o] = s;
    }
}

// ---------------------------------------------------------------------------
__global__ __launch_bounds__(256) void k_dmap(const float* __restrict__ r,
                                              float* __restrict__ d) {
    int b = blockIdx.x;
    int n = b / Lc;
    float xi = r[(size_t)b * 3], yi = r[(size_t)b * 3 + 1], zi = r[(size_t)b * 3 + 2];
    const float* rn = r + (size_t)n * Lc * 3;
    for (int j = threadIdx.x; j < Lc; j += 256) {
        float dx = xi - rn[j * 3];
        float dy = yi - rn[j * 3 + 1];
        float dz = zi - rn[j * 3 + 2];
        d[(size_t)b * Lc + j] = sqrtf(dx * dx + dy * dy + dz * dz + 1e-12f);
    }
}

// ---------------------------------------------------------------------------
extern "C" void kernel_launch(void* const* d_in, const int* in_sizes, int n_in,
                              void* d_out, int out_size, void* d_ws, size_t ws_size,
                              hipStream_t stream) {
    const float* z       = (const float*)d_in[0];
    const float* x       = (const float*)d_in[1];
    const float* pos_emb = (const float*)d_in[2];
    const float* aa_emb  = (const float*)d_in[3];
    const float* ex_w1   = (const float*)d_in[4];
    const float* ex_b1   = (const float*)d_in[5];
    const float* ex_w2   = (const float*)d_in[6];
    const float* ex_b2   = (const float*)d_in[7];
    const float* Wq      = (const float*)d_in[8];
    const float* Wk      = (const float*)d_in[9];
    const float* Wv      = (const float*)d_in[10];
    const float* Wo      = (const float*)d_in[11];
    const float* bo      = (const float*)d_in[12];
    const float* W2d     = (const float*)d_in[13];
    const float* b2d     = (const float*)d_in[14];
    const float* Wf1     = (const float*)d_in[15];
    const float* bf1     = (const float*)d_in[16];
    const float* Wf2     = (const float*)d_in[17];
    const float* bf2     = (const float*)d_in[18];
    const float* ln1_g   = (const float*)d_in[19];
    const float* ln1_b   = (const float*)d_in[20];
    const float* ln2_g   = (const float*)d_in[21];
    const float* ln2_b   = (const float*)d_in[22];
    const float* o_w1    = (const float*)d_in[23];
    const float* o_b1    = (const float*)d_in[24];
    const float* o_w2    = (const float*)d_in[25];
    const float* o_b2    = (const float*)d_in[26];

    float* h    = (float*)d_ws;                    // 4096*256
    float* s2a  = h + (size_t)NTOK * EMBEDc;
    float* s2b  = s2a + (size_t)NTOK * EMBEDc;
    float* bbuf = s2b + (size_t)NTOK * EMBEDc;     // pad 8192
    float* r    = bbuf + 8192;                     // pad 16384
    short* qkvh = (short*)(r + 16384);             // 4096*768
    short* qkvl = qkvh + (size_t)NTOK * 768;
    short* um_hi = qkvl + (size_t)NTOK * 768;      // 4096*320 (padded)
    short* um_lo = um_hi + (size_t)NTOK * UMLD;
    short* o_hi  = um_lo + (size_t)NTOK * UMLD;    // 4096*256
    short* o_lo  = o_hi + (size_t)NTOK * EMBEDc;
    short* f1_hi = o_lo + (size_t)NTOK * EMBEDc;   // 4096*1024
    short* f1_lo = f1_hi + (size_t)NTOK * DFFc;
    short* wqkv_hi = f1_lo + (size_t)NTOK * DFFc;  // 6*768*256
    short* wqkv_lo = wqkv_hi + (size_t)NLc * 768 * EMBEDc;
    short* wo_hi   = wqkv_lo + (size_t)NLc * 768 * EMBEDc;   // 6*256*256
    short* wo_lo   = wo_hi + (size_t)NLc * EMBEDc * DMc;
    short* wf1_hi  = wo_lo + (size_t)NLc * EMBEDc * DMc;     // 6*1024*320 (padded)
    short* wf1_lo  = wf1_hi + (size_t)NLc * DFFc * UMLD;
    short* wf2_hi  = wf1_lo + (size_t)NLc * DFFc * UMLD;     // 6*256*1024
    short* wf2_lo  = wf2_hi + (size_t)NLc * EMBEDc * DFFc;
    short* wex1_hi = wf2_lo + (size_t)NLc * EMBEDc * DFFc;   // 256*64
    short* wex1_lo = wex1_hi + EMBEDc * NZc;
    short* wex2_hi = wex1_lo + EMBEDc * NZc;                 // 256*256
    short* wex2_lo = wex2_hi + EMBEDc * EMBEDc;
    short* wo1_hi  = wex2_lo + EMBEDc * EMBEDc;              // 256*256
    short* wo1_lo  = wo1_hi + EMBEDc * EMBEDc;
    // zt aliases the o buffer (only used in preamble, before k_attn writes o)
    short* zt_hi = o_hi;
    short* zt_lo = o_lo;

    k_pre<<<1024, 256, 0, stream>>>(Wq, Wk, Wv, Wo, Wf1, Wf2, ex_w1, ex_w2, o_w1,
                                    pos_emb, W2d, b2d, x, aa_emb, z,
                                    wqkv_hi, wqkv_lo, wo_hi, wo_lo,
                                    wf1_hi, wf1_lo, wf2_hi, wf2_lo,
                                    wex1_hi, wex1_lo, wex2_hi, wex2_lo,
                                    wo1_hi, wo1_lo, bbuf, um_hi, um_lo,
                                    zt_hi, zt_lo);

    // embed: relu GEMM -> GEMM (fp32 h + bf16 um, ldh = UMLD)
    k_gemm3<1, 1, 0, 64, 3><<<256, 256, 0, stream>>>(
        zt_hi, zt_lo, NZc, wex1_hi, wex1_lo, NZc, NZc,
        nullptr, 0, f1_hi, f1_lo, EMBEDc, ex_b1, 4, 8);
    k_gemm3<3, 1, 0, 64, 3><<<256, 256, 0, stream>>>(
        f1_hi, f1_lo, EMBEDc, wex2_hi, wex2_lo, EMBEDc, EMBEDc,
        h, EMBEDc, um_hi, um_lo, UMLD, ex_b2, 4, 8);

    for (int l = 0; l < NLc; ++l) {
        // qkv: TERMS=2 (A bf16-rounded; downstream softmax damps the error)
        k_gemm3<2, 1, 0, 64, 2><<<768, 256, 0, stream>>>(
            um_hi, um_lo, UMLD,
            wqkv_hi + (size_t)l * 768 * EMBEDc, wqkv_lo + (size_t)l * 768 * EMBEDc, EMBEDc,
            EMBEDc, nullptr, 0, qkvh, qkvl, 768, nullptr, 12, 8);
        k_attn<<<NB * NHc * 4, 512, 0, stream>>>(qkvh, qkvl, bbuf + (size_t)l * NHc * NBINSc, o_hi, o_lo);
        k_gemm3<0, 1, 8, 64, 3><<<512, 256, 0, stream>>>(
            o_hi, o_lo, EMBEDc,
            wo_hi + (size_t)l * EMBEDc * DMc, wo_lo + (size_t)l * EMBEDc * DMc, DMc,
            128, s2a, EMBEDc, nullptr, nullptr, 0, nullptr, 4, 8);
        k_ln<<<NTOK / 8, 256, 0, stream>>>(s2a, s2b, bo + (size_t)l * EMBEDc,
                                           ln1_g + (size_t)l * EMBEDc, ln1_b + (size_t)l * EMBEDc,
                                           h, um_hi, um_lo);
        // ffn1: K padded 288->320, BK=64
        k_gemm3<1, 2, 0, 64, 3><<<512, 256, 0, stream>>>(
            um_hi, um_lo, UMLD,
            wf1_hi + (size_t)l * DFFc * UMLD, wf1_lo + (size_t)l * DFFc * UMLD, UMLD,
            UMLD, nullptr, 0, f1_hi, f1_lo, DFFc, bf1 + (size_t)l * DFFc, 16, 4);
        k_gemm3<0, 1, 8, 64, 3><<<512, 256, 0, stream>>>(
            f1_hi, f1_lo, DFFc,
            wf2_hi + (size_t)l * EMBEDc * DFFc, wf2_lo + (size_t)l * EMBEDc * DFFc, DFFc,
            512, s2a, EMBEDc, nullptr, nullptr, 0, nullptr, 4, 8);
        k_ln<<<NTOK / 8, 256, 0, stream>>>(s2a, s2b, bf2 + (size_t)l * EMBEDc,
                                           ln2_g + (size_t)l * EMBEDc, ln2_b + (size_t)l * EMBEDc,
                                           h, um_hi, um_lo);
    }

    // final: f = relu(um @ o_w1^T + o_b1) (um cols 0..255 hold h in bf16)
    k_gemm3<1, 1, 0, 64, 3><<<256, 256, 0, stream>>>(
        um_hi, um_lo, UMLD, wo1_hi, wo1_lo, EMBEDc, EMBEDc,
        nullptr, 0, f1_hi, f1_lo, EMBEDc, o_b1, 4, 8);
    k_r<<<NTOK / 64, 256, 0, stream>>>(f1_hi, f1_lo, o_w2, o_b2, r);
    k_dmap<<<NB * Lc, 256, 0, stream>>>(r, (float*)d_out);
}

// Round 18
// 527.579 us; speedup vs baseline: 1.1424x; 1.0266x over previous
//
#include <hip/hip_runtime.h>
#include <math.h>

#define NZc     64
#define EMBEDc  256
#define DMc     256
#define NHc     16
#define HDc     16
#define DFFc    1024
#define NLc     6
#define E1Dc    32
#define PDIMc   64
#define PMAXLc  24
#define NBINSc  49
#define NB      8
#define Lc      512
#define NTOK    (NB * Lc)        // 4096
#define UMDIM   288              // logical um width
#define UMLD    320              // padded leading dim (zeros in 288..319)

typedef __attribute__((ext_vector_type(4))) float f4;
typedef __attribute__((ext_vector_type(8))) short bf8;   // 8 bf16 in 4 VGPRs

#define MFMA(a, b, c) __builtin_amdgcn_mfma_f32_16x16x32_bf16((a), (b), (c), 0, 0, 0)

__device__ __forceinline__ short f2bf(float f) {
    unsigned u = __float_as_uint(f);
    u += 0x7FFFu + ((u >> 16) & 1u);   // round-to-nearest-even
    return (short)(u >> 16);
}
__device__ __forceinline__ float bf2f(short s) {
    return __uint_as_float(((unsigned)(unsigned short)s) << 16);
}

// ---------------------------------------------------------------------------
// preamble: weight conversions (x8 vectorized) + bias bins + e_aa + z^T.
// Wf1 rows remapped 288 -> 320 stride; pad cols zero-filled (um + wf1).
__global__ void k_pre(const float* __restrict__ Wq, const float* __restrict__ Wk,
                      const float* __restrict__ Wv, const float* __restrict__ Wo,
                      const float* __restrict__ Wf1, const float* __restrict__ Wf2,
                      const float* __restrict__ exw1, const float* __restrict__ exw2,
                      const float* __restrict__ ow1,
                      const float* __restrict__ pos_emb, const float* __restrict__ W2d,
                      const float* __restrict__ b2d, const float* __restrict__ x,
                      const float* __restrict__ aa_emb, const float* __restrict__ z,
                      short* __restrict__ wqkv_hi, short* __restrict__ wqkv_lo,
                      short* __restrict__ wo_hi, short* __restrict__ wo_lo,
                      short* __restrict__ wf1_hi, short* __restrict__ wf1_lo,
                      short* __restrict__ wf2_hi, short* __restrict__ wf2_lo,
                      short* __restrict__ wex1_hi, short* __restrict__ wex1_lo,
                      short* __restrict__ wex2_hi, short* __restrict__ wex2_lo,
                      short* __restrict__ wo1_hi, short* __restrict__ wo1_lo,
                      float* __restrict__ bb,
                      short* __restrict__ umhi, short* __restrict__ umlo,
                      short* __restrict__ zth, short* __restrict__ ztl) {
    int stride = gridDim.x * blockDim.x;
    int tid = blockIdx.x * blockDim.x + threadIdx.x;
#define CVT(src, hi, lo, per_layer, dstride, doff, scale, total)               \
    for (int i = tid; i < (total) / 8; i += stride) {                          \
        int ib = i * 8;                                                        \
        int ll = ib / (per_layer), rels = ib - ll * (per_layer);               \
        size_t di = (size_t)ll * (dstride) + (doff) + rels;                    \
        f4 v0 = *(const f4*)(src + ib);                                        \
        f4 v1 = *(const f4*)(src + ib + 4);                                    \
        bf8 hv, lv;                                                            \
        _Pragma("unroll")                                                      \
        for (int q = 0; q < 4; ++q) {                                          \
            float v = v0[q] * (scale);                                         \
            short hh = f2bf(v);                                                \
            hv[q] = hh;                                                        \
            lv[q] = f2bf(v - bf2f(hh));                                        \
        }                                                                      \
        _Pragma("unroll")                                                      \
        for (int q = 0; q < 4; ++q) {                                          \
            float v = v1[q] * (scale);                                         \
            short hh = f2bf(v);                                                \
            hv[q + 4] = hh;                                                    \
            lv[q + 4] = f2bf(v - bf2f(hh));                                    \
        }                                                                      \
        *(bf8*)(hi + di) = hv;                                                 \
        *(bf8*)(lo + di) = lv;                                                 \
    }
    CVT(Wq,  wqkv_hi, wqkv_lo, 65536, 196608, 0,      0.0625f, 393216);
    CVT(Wk,  wqkv_hi, wqkv_lo, 65536, 196608, 65536,  1.f,     393216);
    CVT(Wv,  wqkv_hi, wqkv_lo, 65536, 196608, 131072, 1.f,     393216);
    CVT(Wo,  wo_hi,  wo_lo,  65536,  65536,  0, 1.f, 393216);
    CVT(Wf2, wf2_hi, wf2_lo, 262144, 262144, 0, 1.f, 1572864);
    CVT(exw1, wex1_hi, wex1_lo, 16384, 16384, 0, 1.f, 16384);
    CVT(exw2, wex2_hi, wex2_lo, 65536, 65536, 0, 1.f, 65536);
    CVT(ow1,  wo1_hi,  wo1_lo,  65536, 65536, 0, 1.f, 65536);
#undef CVT
    // Wf1: src rows of 288 -> dest rows of 320 (row boundary 8-aligned)
    for (int i = tid; i < 1769472 / 8; i += stride) {
        int ib = i * 8;
        int ll = ib / 294912, rels = ib - ll * 294912;
        int row = rels / 288, col = rels - row * 288;
        size_t di = (size_t)ll * (1024 * UMLD) + (size_t)row * UMLD + col;
        f4 v0 = *(const f4*)(Wf1 + ib);
        f4 v1 = *(const f4*)(Wf1 + ib + 4);
        bf8 hv, lv;
#pragma unroll
        for (int q = 0; q < 4; ++q) {
            float v = v0[q];
            short hh = f2bf(v);
            hv[q] = hh;
            lv[q] = f2bf(v - bf2f(hh));
        }
#pragma unroll
        for (int q = 0; q < 4; ++q) {
            float v = v1[q];
            short hh = f2bf(v);
            hv[q + 4] = hh;
            lv[q + 4] = f2bf(v - bf2f(hh));
        }
        *(bf8*)(wf1_hi + di) = hv;
        *(bf8*)(wf1_lo + di) = lv;
    }
    // zero pad cols 288..319: wf1 (6144 rows) and um (4096 rows)
    {
        bf8 zz;
#pragma unroll
        for (int q = 0; q < 8; ++q) zz[q] = 0;
        for (int i = tid; i < 6144 * 4; i += stride) {
            int row = i >> 2, seg = i & 3;
            size_t di = (size_t)row * UMLD + UMDIM + seg * 8;
            *(bf8*)(wf1_hi + di) = zz;
            *(bf8*)(wf1_lo + di) = zz;
        }
        for (int i = tid; i < 4096 * 4; i += stride) {
            int row = i >> 2, seg = i & 3;
            size_t di = (size_t)row * UMLD + UMDIM + seg * 8;
            *(bf8*)(umhi + di) = zz;
            *(bf8*)(umlo + di) = zz;
        }
    }
    for (int idx = tid; idx < NLc * NHc * NBINSc; idx += stride) {
        int bin = idx % NBINSc;
        int tmp = idx / NBINSc;
        int hh = tmp % NHc, l = tmp / NHc;
        float s = b2d[l * NHc + hh];
        const float* pe = pos_emb + bin * PDIMc;
        const float* w  = W2d + (l * NHc + hh) * PDIMc;
        for (int p = 0; p < PDIMc; ++p) s += pe[p] * w[p];
        bb[idx] = s;
    }
    for (int tok = tid; tok < NTOK; tok += stride) {
        int n = tok / Lc, l = tok % Lc;
        const float* xp = x + (size_t)n * 20 * Lc + l;
        float best = xp[0];
        int bi = 0;
        for (int c = 1; c < 20; ++c) {
            float v = xp[c * Lc];
            if (v > best) { best = v; bi = c; }
        }
        const float* e = aa_emb + bi * E1Dc;
        bf8 hv, lv;
        for (int c8 = 0; c8 < E1Dc / 8; ++c8) {
#pragma unroll
            for (int q = 0; q < 8; ++q) {
                float v = e[c8 * 8 + q];
                short hh = f2bf(v);
                hv[q] = hh;
                lv[q] = f2bf(v - bf2f(hh));
            }
            *(bf8*)(umhi + (size_t)tok * UMLD + EMBEDc + c8 * 8) = hv;
            *(bf8*)(umlo + (size_t)tok * UMLD + EMBEDc + c8 * 8) = lv;
        }
    }
    for (int tok = tid; tok < NTOK; tok += stride) {
        int n = tok >> 9, l = tok & 511;
        bf8 hv, lv;
        for (int c8 = 0; c8 < NZc / 8; ++c8) {
#pragma unroll
            for (int q = 0; q < 8; ++q) {
                float v = z[((size_t)n * NZc + c8 * 8 + q) * Lc + l];
                short hh = f2bf(v);
                hv[q] = hh;
                lv[q] = f2bf(v - bf2f(hh));
            }
            *(bf8*)(zth + (size_t)tok * NZc + c8 * 8) = hv;
            *(bf8*)(ztl + (size_t)tok * NZc + c8 * 8) = lv;
        }
    }
}

// ---------------------------------------------------------------------------
// LDS-staged MFMA GEMM. TERMS=3: full compensated (AhBh+AhBl+AlBh).
// TERMS=2: drop AlBh (A bf16 RNE) - qkv/oproj/ffn2 (softmax- or LN-damped).
template <int EPI, int MF, int SKSHIFT, int BK, int TERMS>
__global__ __launch_bounds__(256) void k_gemm3(
    const short* __restrict__ Ahi, const short* __restrict__ Alo, int lda,
    const short* __restrict__ Bhi, const short* __restrict__ Blo, int ldb,
    int K, float* __restrict__ outf, int ldo, short* __restrict__ ohi,
    short* __restrict__ olo, int ldh, const float* __restrict__ bias,
    int gx, int gypx) {
    constexpr int PAD = BK + 8;
    __shared__ __align__(16) short Ah[MF * 64][PAD];
    __shared__ __align__(16) short Al[TERMS == 3 ? MF * 64 : 1][TERMS == 3 ? PAD : 1];
    __shared__ __align__(16) short Bh[64][PAD];
    __shared__ __align__(16) short Bl[64][PAD];

    int bid = blockIdx.x;
    int koff = 0;
    if (SKSHIFT) {
        int kh = bid >> SKSHIFT;
        bid &= (1 << SKSHIFT) - 1;
        koff = kh * K;
        outf += (size_t)kh * NTOK * EMBEDc;
    }
    int xcd = bid & 7, j = bid >> 3;
    int bx = j % gx, by = xcd * gypx + j / gx;

    int t = threadIdx.x;
    int w = t >> 6, l = t & 63, lr = l & 15, lk = l >> 4;
    int m0 = by * (MF * 64);
    int n0 = bx * 64;

    constexpr int TPR = BK / 8;
    constexpr int RP  = 256 / TPR;
    constexpr int AP  = MF * 64 / RP;
    constexpr int BP  = 64 / RP;
    int srow = t / TPR, scol = (t % TPR) * 8;

    const short* pa  = Ahi + (size_t)(m0 + srow) * lda + koff + scol;
    const short* pal = Alo + (size_t)(m0 + srow) * lda + koff + scol;
    const short* pb  = Bhi + (size_t)(n0 + srow) * ldb + koff + scol;
    const short* pbl = Blo + (size_t)(n0 + srow) * ldb + koff + scol;

    bf8 ra[AP], rla[AP], rb[BP], rlb[BP];
#pragma unroll
    for (int p = 0; p < AP; ++p) {
        ra[p] = *(const bf8*)(pa + (size_t)p * RP * lda);
        if (TERMS == 3) rla[p] = *(const bf8*)(pal + (size_t)p * RP * lda);
    }
#pragma unroll
    for (int p = 0; p < BP; ++p) {
        rb[p]  = *(const bf8*)(pb  + (size_t)p * RP * ldb);
        rlb[p] = *(const bf8*)(pbl + (size_t)p * RP * ldb);
    }

    f4 acc[MF][4];
#pragma unroll
    for (int mf = 0; mf < MF; ++mf)
#pragma unroll
        for (int nf = 0; nf < 4; ++nf) acc[mf][nf] = (f4){0.f, 0.f, 0.f, 0.f};

    for (int ks = 0; ks < K; ks += BK) {
        __syncthreads();
#pragma unroll
        for (int p = 0; p < AP; ++p) {
            *(bf8*)&Ah[p * RP + srow][scol] = ra[p];
            if (TERMS == 3) *(bf8*)&Al[p * RP + srow][scol] = rla[p];
        }
#pragma unroll
        for (int p = 0; p < BP; ++p) {
            *(bf8*)&Bh[p * RP + srow][scol] = rb[p];
            *(bf8*)&Bl[p * RP + srow][scol] = rlb[p];
        }
        __syncthreads();
        if (ks + BK < K) {
#pragma unroll
            for (int p = 0; p < AP; ++p) {
                ra[p] = *(const bf8*)(pa + (size_t)p * RP * lda + ks + BK);
                if (TERMS == 3) rla[p] = *(const bf8*)(pal + (size_t)p * RP * lda + ks + BK);
            }
#pragma unroll
            for (int p = 0; p < BP; ++p) {
                rb[p]  = *(const bf8*)(pb  + (size_t)p * RP * ldb + ks + BK);
                rlb[p] = *(const bf8*)(pbl + (size_t)p * RP * ldb + ks + BK);
            }
        }
#pragma unroll
        for (int kc = 0; kc < BK / 32; ++kc) {
            bf8 bhf[4], blf[4];
#pragma unroll
            for (int nf = 0; nf < 4; ++nf) {
                bhf[nf] = *(const bf8*)&Bh[nf * 16 + lr][kc * 32 + lk * 8];
                blf[nf] = *(const bf8*)&Bl[nf * 16 + lr][kc * 32 + lk * 8];
            }
#pragma unroll
            for (int mf = 0; mf < MF; ++mf) {
                bf8 ah = *(const bf8*)&Ah[w * MF * 16 + mf * 16 + lr][kc * 32 + lk * 8];
                bf8 al;
                if (TERMS == 3) al = *(const bf8*)&Al[w * MF * 16 + mf * 16 + lr][kc * 32 + lk * 8];
#pragma unroll
                for (int nf = 0; nf < 4; ++nf) {
                    acc[mf][nf] = MFMA(ah, bhf[nf], acc[mf][nf]);
                    acc[mf][nf] = MFMA(ah, blf[nf], acc[mf][nf]);
                    if (TERMS == 3) acc[mf][nf] = MFMA(al, bhf[nf], acc[mf][nf]);
                }
            }
        }
    }

#pragma unroll
    for (int mf = 0; mf < MF; ++mf) {
#pragma unroll
        for (int nf = 0; nf < 4; ++nf) {
            int n = n0 + nf * 16 + lr;
            int mbase = m0 + w * MF * 16 + mf * 16 + lk * 4;
            if (EPI == 0) {
#pragma unroll
                for (int r = 0; r < 4; ++r)
                    outf[(size_t)(mbase + r) * ldo + n] = acc[mf][nf][r];
            } else if (EPI == 1) {
                float bv = bias[n];
#pragma unroll
                for (int r = 0; r < 4; ++r) {
                    float y = fmaxf(acc[mf][nf][r] + bv, 0.f);
                    short hv = f2bf(y);
                    size_t oi = (size_t)(mbase + r) * ldh + n;
                    ohi[oi] = hv;
                    olo[oi] = f2bf(y - bf2f(hv));
                }
            } else if (EPI == 2) {
#pragma unroll
                for (int r = 0; r < 4; ++r) {
                    float y = acc[mf][nf][r];
                    short hv = f2bf(y);
                    size_t oi = (size_t)(mbase + r) * ldh + n;
                    ohi[oi] = hv;
                    olo[oi] = f2bf(y - bf2f(hv));
                }
            } else {
                float bv = bias[n];
#pragma unroll
                for (int r = 0; r < 4; ++r) {
                    float y = acc[mf][nf][r] + bv;
                    outf[(size_t)(mbase + r) * ldo + n] = y;
                    short hv = f2bf(y);
                    size_t oi = (size_t)(mbase + r) * ldh + n;
                    ohi[oi] = hv;
                    olo[oi] = f2bf(y - bf2f(hv));
                }
            }
        }
    }
}

// ---------------------------------------------------------------------------
// MFMA flash attention (round-16 config): LDS-routed P redistribution.
// o hi-split now RNE (unbiased) so the 2-term oproj sees rounded bf16.
__global__ __launch_bounds__(512, 8) void k_attn(const short* __restrict__ qh,
                                                 const short* __restrict__ ql,
                                                 const float* __restrict__ bb,
                                                 short* __restrict__ ohi,
                                                 short* __restrict__ olo) {
    int bx = blockIdx.x;
    int qt = bx >> 7;            // 0..3; blocks sharing (n,head) same XCD
    int head = bx & 15;
    int n = (bx >> 4) & 7;
    int t = threadIdx.x;
    int w = t >> 6, l = t & 63;
    int lq = l & 15, lk = l >> 4;

    __shared__ __align__(16) short khl[256][40];   // [key][hi0-15|lo16-31|pad]
    __shared__ __align__(16) short vth[16][264];   // V^T hi: [d][key 0..255]
    __shared__ __align__(16) short vtl[16][264];   // V^T lo
    __shared__ __align__(16) float pw[8][16][20];  // per-wave P[q][key] buffer
    __shared__ float biasr[64];

    if (t < NBINSc) biasr[t] = bb[head * NBINSc + t];
    float bL = bb[head * NBINSc];
    float bR = bb[head * NBINSc + 48];

    size_t base = (size_t)n * Lc * 768 + head * 16;

    int qg = qt * 128 + w * 16 + lq;             // this lane's q column
    size_t qrow = ((size_t)n * Lc + qg) * 768 + head * 16;
    bf8 B1 = *(const bf8*)(qh + qrow + (lk & 1) * 8);   // [Qh|Qh]
    bf8 B2;
    if (lk < 2) B2 = *(const bf8*)(ql + qrow + lk * 8);  // [Ql|0]
    else {
#pragma unroll
        for (int i = 0; i < 8; ++i) B2[i] = 0;
    }

    f4 acc = (f4){0.f, 0.f, 0.f, 0.f};
    float m = -1e30f, lsum = 0.f;
    int rel0 = lk * 4 - qg;      // rel of s[0] at global kt=0; += 16 per tile

    for (int half = 0; half < 2; ++half) {
        __syncthreads();          // previous half fully consumed
        // stage K half (256 keys)
        for (int u = t; u < 1024; u += 512) {
            int key = u >> 2, seg = u & 3;
            const short* src = (seg < 2 ? qh : ql) + base + 256
                             + (size_t)(half * 256 + key) * 768 + (seg & 1) * 8;
            *(bf8*)&khl[key][seg * 8] = *(const bf8*)src;
        }
        // stage V half transposed, pair-packed b32 writes (1 item/thread)
        {
            int u = t & 127;             // key pair
            int dhalf = (t >> 7) & 1;    // d 0..7 / 8..15
            int hl = (t >> 8) & 1;       // hi / lo
            int gkey = half * 256 + u * 2;
            const short* vs = (hl ? ql : qh) + base + 512 + (size_t)gkey * 768 + dhalf * 8;
            bf8 A = *(const bf8*)vs;
            bf8 B = *(const bf8*)(vs + 768);
            unsigned* vw = (unsigned*)(hl ? &vtl[0][0] : &vth[0][0]);  // stride 132 words
#pragma unroll
            for (int i = 0; i < 8; ++i)
                vw[(dhalf * 8 + i) * 132 + u] =
                    (unsigned)(unsigned short)A[i] | ((unsigned)(unsigned short)B[i] << 16);
        }
        __syncthreads();

        for (int kt = 0; kt < 16; ++kt, rel0 += 16) {
            bf8 A1 = *(const bf8*)&khl[kt * 16 + lq][lk * 8];  // [Kh|Kl]
            f4 s = (f4){0.f, 0.f, 0.f, 0.f};
            __builtin_amdgcn_s_setprio(1);
            s = MFMA(A1, B1, s);      // KhQh + KlQh
            s = MFMA(A1, B2, s);      // KhQl
            __builtin_amdgcn_s_setprio(0);
            if (rel0 >= PMAXLc) {
                s[0] += bR; s[1] += bR; s[2] += bR; s[3] += bR;
            } else if (rel0 + 3 <= -PMAXLc) {
                s[0] += bL; s[1] += bL; s[2] += bL; s[3] += bL;
            } else {
#pragma unroll
                for (int r = 0; r < 4; ++r) {
                    int rel = rel0 + r;
                    rel = rel < -PMAXLc ? -PMAXLc : (rel > PMAXLc ? PMAXLc : rel);
                    s[r] += biasr[rel + PMAXLc];
                }
            }
            float mt = fmaxf(fmaxf(s[0], s[1]), fmaxf(s[2], s[3]));
            mt = fmaxf(mt, __shfl_xor(mt, 16));
            mt = fmaxf(mt, __shfl_xor(mt, 32));
            if (__any(mt > m + 8.0f)) {
                float mn = fmaxf(m, mt);
                float alpha = __expf(m - mn);
                m = mn;
                lsum *= alpha;
#pragma unroll
                for (int r = 0; r < 4; ++r) acc[r] *= __shfl(alpha, lk * 4 + r);
            }
            f4 p;
#pragma unroll
            for (int r = 0; r < 4; ++r) p[r] = __expf(s[r] - m);
            lsum += p[0] + p[1] + p[2] + p[3];
            // P routed via per-wave LDS (wave-synchronous, no barrier)
            *(f4*)&pw[w][lq][lk * 4] = p;
            const float* pr = &pw[w][lq][(lk & 1) * 8];
            f4 ga = *(const f4*)pr;
            f4 gb = *(const f4*)(pr + 4);
            bf8 PA;
            if (lk < 2) {
#pragma unroll
                for (int jj = 0; jj < 4; ++jj) {
                    PA[jj]     = (short)(__float_as_uint(ga[jj]) >> 16);
                    PA[jj + 4] = (short)(__float_as_uint(gb[jj]) >> 16);
                }
            } else {
#pragma unroll
                for (int jj = 0; jj < 4; ++jj) {
                    unsigned hu0 = __float_as_uint(ga[jj]) & 0xFFFF0000u;
                    unsigned hu1 = __float_as_uint(gb[jj]) & 0xFFFF0000u;
                    PA[jj]     = (short)(__float_as_uint(ga[jj] - __uint_as_float(hu0)) >> 16);
                    PA[jj + 4] = (short)(__float_as_uint(gb[jj] - __uint_as_float(hu1)) >> 16);
                }
            }
            bf8 VB1 = *(const bf8*)&vth[lq][kt * 16 + (lk & 1) * 8];  // [Vh|Vh]
            bf8 VB2;
            if (lk < 2) VB2 = *(const bf8*)&vtl[lq][kt * 16 + lk * 8];  // [Vl|0]
            else {
#pragma unroll
                for (int i = 0; i < 8; ++i) VB2[i] = 0;
            }
            __builtin_amdgcn_s_setprio(1);
            acc = MFMA(PA, VB1, acc);   // PhVh + PlVh
            acc = MFMA(PA, VB2, acc);   // PhVl
            __builtin_amdgcn_s_setprio(0);
        }
    }

    float lred = lsum + __shfl_xor(lsum, 16);
    lred += __shfl_xor(lred, 32);
    float inv = 1.0f / lred;
#pragma unroll
    for (int r = 0; r < 4; ++r) {
        float iq = __shfl(inv, lk * 4 + r);
        float y = acc[r] * iq;
        int qo = qt * 128 + w * 16 + lk * 4 + r;
        size_t oi = ((size_t)n * Lc + qo) * DMc + head * 16 + lq;
        short hv = f2bf(y);               // RNE hi (unbiased for 2-term oproj)
        ohi[oi] = hv;
        olo[oi] = f2bf(y - bf2f(hv));
    }
}

// ---------------------------------------------------------------------------
// LN over h + s2a + s2b + sbias, fully f4-vectorized. um stride = UMLD.
__global__ __launch_bounds__(256) void k_ln(const float* __restrict__ s2a,
                                            const float* __restrict__ s2b,
                                            const float* __restrict__ sbias,
                                            const float* __restrict__ g,
                                            const float* __restrict__ bta,
                                            float* __restrict__ h,
                                            short* __restrict__ umhi,
                                            short* __restrict__ umlo) {
    int t = threadIdx.x;
    int tl = t >> 5, j = t & 31;
    size_t gtok = (size_t)blockIdx.x * 8 + tl;
    int d0 = j * 8;
    size_t off = gtok * EMBEDc + d0;
    f4 h0 = *(const f4*)(h + off);
    f4 h1 = *(const f4*)(h + off + 4);
    f4 a0 = *(const f4*)(s2a + off);
    f4 a1 = *(const f4*)(s2a + off + 4);
    f4 b0 = *(const f4*)(s2b + off);
    f4 b1 = *(const f4*)(s2b + off + 4);
    f4 sb0 = *(const f4*)(sbias + d0);
    f4 sb1 = *(const f4*)(sbias + d0 + 4);
    f4 v0 = h0 + a0 + b0 + sb0;
    f4 v1 = h1 + a1 + b1 + sb1;
    float sum = v0[0] + v0[1] + v0[2] + v0[3] + v1[0] + v1[1] + v1[2] + v1[3];
    float ssq = v0[0]*v0[0] + v0[1]*v0[1] + v0[2]*v0[2] + v0[3]*v0[3]
              + v1[0]*v1[0] + v1[1]*v1[1] + v1[2]*v1[2] + v1[3]*v1[3];
#pragma unroll
    for (int off5 = 16; off5; off5 >>= 1) {
        sum += __shfl_xor(sum, off5, 32);
        ssq += __shfl_xor(ssq, off5, 32);
    }
    float mean = sum * (1.f / EMBEDc);
    float var = ssq * (1.f / EMBEDc) - mean * mean;
    float inv = rsqrtf(var + 1e-5f);
    f4 g0 = *(const f4*)(g + d0);
    f4 g1 = *(const f4*)(g + d0 + 4);
    f4 t0 = *(const f4*)(bta + d0);
    f4 t1 = *(const f4*)(bta + d0 + 4);
    f4 y0, y1;
    bf8 hv, lv;
#pragma unroll
    for (int q = 0; q < 4; ++q) {
        float y = (v0[q] - mean) * inv * g0[q] + t0[q];
        y0[q] = y;
        short hh = f2bf(y);
        hv[q] = hh;
        lv[q] = f2bf(y - bf2f(hh));
    }
#pragma unroll
    for (int q = 0; q < 4; ++q) {
        float y = (v1[q] - mean) * inv * g1[q] + t1[q];
        y1[q] = y;
        short hh = f2bf(y);
        hv[q + 4] = hh;
        lv[q + 4] = f2bf(y - bf2f(hh));
    }
    *(f4*)(h + off) = y0;
    *(f4*)(h + off + 4) = y1;
    *(bf8*)(umhi + gtok * UMLD + d0) = hv;
    *(bf8*)(umlo + gtok * UMLD + d0) = lv;
}

// ---------------------------------------------------------------------------
__global__ __launch_bounds__(256) void k_r(const short* __restrict__ fh,
                                           const short* __restrict__ fl,
                                           const float* __restrict__ w2,
                                           const float* __restrict__ b2,
                                           float* __restrict__ r) {
    __shared__ float w[3][EMBEDc];
    int t = threadIdx.x;
    for (int u = t; u < 3 * EMBEDc; u += 256) w[u >> 8][u & 255] = w2[u];
    __syncthreads();
    int tok = blockIdx.x * 64 + (t >> 2), o = t & 3;
    if (o < 3) {
        const short* ph = fh + (size_t)tok * EMBEDc;
        const short* pl = fl + (size_t)tok * EMBEDc;
        float s = b2[o];
        for (int c8 = 0; c8 < EMBEDc / 8; ++c8) {
            bf8 vh = *(const bf8*)(ph + c8 * 8);
            bf8 vl = *(const bf8*)(pl + c8 * 8);
#pragma unroll
            for (int j = 0; j < 8; ++j)
                s += (bf2f(vh[j]) + bf2f(vl[j])) * w[o][c8 * 8 + j];
        }
        r[(size_t)tok * 3 + o] = s;
    }
}

// ---------------------------------------------------------------------------
__global__ __launch_bounds__(256) void k_dmap(const float* __restrict__ r,
                                              float* __restrict__ d) {
    int b = blockIdx.x;
    int n = b / Lc;
    float xi = r[(size_t)b * 3], yi = r[(size_t)b * 3 + 1], zi = r[(size_t)b * 3 + 2];
    const float* rn = r + (size_t)n * Lc * 3;
    for (int j = threadIdx.x; j < Lc; j += 256) {
        float dx = xi - rn[j * 3];
        float dy = yi - rn[j * 3 + 1];
        float dz = zi - rn[j * 3 + 2];
        d[(size_t)b * Lc + j] = sqrtf(dx * dx + dy * dy + dz * dz + 1e-12f);
    }
}

// ---------------------------------------------------------------------------
extern "C" void kernel_launch(void* const* d_in, const int* in_sizes, int n_in,
                              void* d_out, int out_size, void* d_ws, size_t ws_size,
                              hipStream_t stream) {
    const float* z       = (const float*)d_in[0];
    const float* x       = (const float*)d_in[1];
    const float* pos_emb = (const float*)d_in[2];
    const float* aa_emb  = (const float*)d_in[3];
    const float* ex_w1   = (const float*)d_in[4];
    const float* ex_b1   = (const float*)d_in[5];
    const float* ex_w2   = (const float*)d_in[6];
    const float* ex_b2   = (const float*)d_in[7];
    const float* Wq      = (const float*)d_in[8];
    const float* Wk      = (const float*)d_in[9];
    const float* Wv      = (const float*)d_in[10];
    const float* Wo      = (const float*)d_in[11];
    const float* bo      = (const float*)d_in[12];
    const float* W2d     = (const float*)d_in[13];
    const float* b2d     = (const float*)d_in[14];
    const float* Wf1     = (const float*)d_in[15];
    const float* bf1     = (const float*)d_in[16];
    const float* Wf2     = (const float*)d_in[17];
    const float* bf2     = (const float*)d_in[18];
    const float* ln1_g   = (const float*)d_in[19];
    const float* ln1_b   = (const float*)d_in[20];
    const float* ln2_g   = (const float*)d_in[21];
    const float* ln2_b   = (const float*)d_in[22];
    const float* o_w1    = (const float*)d_in[23];
    const float* o_b1    = (const float*)d_in[24];
    const float* o_w2    = (const float*)d_in[25];
    const float* o_b2    = (const float*)d_in[26];

    float* h    = (float*)d_ws;                    // 4096*256
    float* s2a  = h + (size_t)NTOK * EMBEDc;
    float* s2b  = s2a + (size_t)NTOK * EMBEDc;
    float* bbuf = s2b + (size_t)NTOK * EMBEDc;     // pad 8192
    float* r    = bbuf + 8192;                     // pad 16384
    short* qkvh = (short*)(r + 16384);             // 4096*768
    short* qkvl = qkvh + (size_t)NTOK * 768;
    short* um_hi = qkvl + (size_t)NTOK * 768;      // 4096*320 (padded)
    short* um_lo = um_hi + (size_t)NTOK * UMLD;
    short* o_hi  = um_lo + (size_t)NTOK * UMLD;    // 4096*256
    short* o_lo  = o_hi + (size_t)NTOK * EMBEDc;
    short* f1_hi = o_lo + (size_t)NTOK * EMBEDc;   // 4096*1024
    short* f1_lo = f1_hi + (size_t)NTOK * DFFc;
    short* wqkv_hi = f1_lo + (size_t)NTOK * DFFc;  // 6*768*256
    short* wqkv_lo = wqkv_hi + (size_t)NLc * 768 * EMBEDc;
    short* wo_hi   = wqkv_lo + (size_t)NLc * 768 * EMBEDc;   // 6*256*256
    short* wo_lo   = wo_hi + (size_t)NLc * EMBEDc * DMc;
    short* wf1_hi  = wo_lo + (size_t)NLc * EMBEDc * DMc;     // 6*1024*320 (padded)
    short* wf1_lo  = wf1_hi + (size_t)NLc * DFFc * UMLD;
    short* wf2_hi  = wf1_lo + (size_t)NLc * DFFc * UMLD;     // 6*256*1024
    short* wf2_lo  = wf2_hi + (size_t)NLc * EMBEDc * DFFc;
    short* wex1_hi = wf2_lo + (size_t)NLc * EMBEDc * DFFc;   // 256*64
    short* wex1_lo = wex1_hi + EMBEDc * NZc;
    short* wex2_hi = wex1_lo + EMBEDc * NZc;                 // 256*256
    short* wex2_lo = wex2_hi + EMBEDc * EMBEDc;
    short* wo1_hi  = wex2_lo + EMBEDc * EMBEDc;              // 256*256
    short* wo1_lo  = wo1_hi + EMBEDc * EMBEDc;
    // zt aliases the o buffer (only used in preamble, before k_attn writes o)
    short* zt_hi = o_hi;
    short* zt_lo = o_lo;

    k_pre<<<1024, 256, 0, stream>>>(Wq, Wk, Wv, Wo, Wf1, Wf2, ex_w1, ex_w2, o_w1,
                                    pos_emb, W2d, b2d, x, aa_emb, z,
                                    wqkv_hi, wqkv_lo, wo_hi, wo_lo,
                                    wf1_hi, wf1_lo, wf2_hi, wf2_lo,
                                    wex1_hi, wex1_lo, wex2_hi, wex2_lo,
                                    wo1_hi, wo1_lo, bbuf, um_hi, um_lo,
                                    zt_hi, zt_lo);

    // embed: relu GEMM -> GEMM (fp32 h + bf16 um, ldh = UMLD)
    k_gemm3<1, 1, 0, 64, 3><<<256, 256, 0, stream>>>(
        zt_hi, zt_lo, NZc, wex1_hi, wex1_lo, NZc, NZc,
        nullptr, 0, f1_hi, f1_lo, EMBEDc, ex_b1, 4, 8);
    k_gemm3<3, 1, 0, 64, 3><<<256, 256, 0, stream>>>(
        f1_hi, f1_lo, EMBEDc, wex2_hi, wex2_lo, EMBEDc, EMBEDc,
        h, EMBEDc, um_hi, um_lo, UMLD, ex_b2, 4, 8);

    for (int l = 0; l < NLc; ++l) {
        // qkv: TERMS=2 (A bf16; softmax damps the error)
        k_gemm3<2, 1, 0, 64, 2><<<768, 256, 0, stream>>>(
            um_hi, um_lo, UMLD,
            wqkv_hi + (size_t)l * 768 * EMBEDc, wqkv_lo + (size_t)l * 768 * EMBEDc, EMBEDc,
            EMBEDc, nullptr, 0, qkvh, qkvl, 768, nullptr, 12, 8);
        k_attn<<<NB * NHc * 4, 512, 0, stream>>>(qkvh, qkvl, bbuf + (size_t)l * NHc * NBINSc, o_hi, o_lo);
        // oproj: TERMS=2 (o RNE bf16; LN damps the error)
        k_gemm3<0, 1, 8, 64, 2><<<512, 256, 0, stream>>>(
            o_hi, o_lo, EMBEDc,
            wo_hi + (size_t)l * EMBEDc * DMc, wo_lo + (size_t)l * EMBEDc * DMc, DMc,
            128, s2a, EMBEDc, nullptr, nullptr, 0, nullptr, 4, 8);
        k_ln<<<NTOK / 8, 256, 0, stream>>>(s2a, s2b, bo + (size_t)l * EMBEDc,
                                           ln1_g + (size_t)l * EMBEDc, ln1_b + (size_t)l * EMBEDc,
                                           h, um_hi, um_lo);
        // ffn1: K padded 288->320, BK=64 (3-term)
        k_gemm3<1, 2, 0, 64, 3><<<512, 256, 0, stream>>>(
            um_hi, um_lo, UMLD,
            wf1_hi + (size_t)l * DFFc * UMLD, wf1_lo + (size_t)l * DFFc * UMLD, UMLD,
            UMLD, nullptr, 0, f1_hi, f1_lo, DFFc, bf1 + (size_t)l * DFFc, 16, 4);
        // ffn2: TERMS=2 (f1 RNE bf16; LN damps the error)
        k_gemm3<0, 1, 8, 64, 2><<<512, 256, 0, stream>>>(
            f1_hi, f1_lo, DFFc,
            wf2_hi + (size_t)l * EMBEDc * DFFc, wf2_lo + (size_t)l * EMBEDc * DFFc, DFFc,
            512, s2a, EMBEDc, nullptr, nullptr, 0, nullptr, 4, 8);
        k_ln<<<NTOK / 8, 256, 0, stream>>>(s2a, s2b, bf2 + (size_t)l * EMBEDc,
                                           ln2_g + (size_t)l * EMBEDc, ln2_b + (size_t)l * EMBEDc,
                                           h, um_hi, um_lo);
    }

    // final: f = relu(um @ o_w1^T + o_b1) (um cols 0..255 hold h in bf16)
    k_gemm3<1, 1, 0, 64, 3><<<256, 256, 0, stream>>>(
        um_hi, um_lo, UMLD, wo1_hi, wo1_lo, EMBEDc, EMBEDc,
        nullptr, 0, f1_hi, f1_lo, EMBEDc, o_b1, 4, 8);
    k_r<<<NTOK / 64, 256, 0, stream>>>(f1_hi, f1_lo, o_w2, o_b2, r);
    k_dmap<<<NB * Lc, 256, 0, stream>>>(r, (float*)d_out);
}

// Round 19
// 499.833 us; speedup vs baseline: 1.2058x; 1.0555x over previous
//
#include <hip/hip_runtime.h>
#include <math.h>

#define NZc     64
#define EMBEDc  256
#define DMc     256
#define NHc     16
#define HDc     16
#define DFFc    1024
#define NLc     6
#define E1Dc    32
#define PDIMc   64
#define PMAXLc  24
#define NBINSc  49
#define NB      8
#define Lc      512
#define NTOK    (NB * Lc)        // 4096
#define UMDIM   288              // logical um width
#define UMLD    320              // padded leading dim (zeros in 288..319)

typedef __attribute__((ext_vector_type(4))) float f4;
typedef __attribute__((ext_vector_type(8))) short bf8;   // 8 bf16 in 4 VGPRs

#define MFMA(a, b, c) __builtin_amdgcn_mfma_f32_16x16x32_bf16((a), (b), (c), 0, 0, 0)

__device__ __forceinline__ short f2bf(float f) {
    unsigned u = __float_as_uint(f);
    u += 0x7FFFu + ((u >> 16) & 1u);   // round-to-nearest-even
    return (short)(u >> 16);
}
__device__ __forceinline__ float bf2f(short s) {
    return __uint_as_float(((unsigned)(unsigned short)s) << 16);
}

// ---------------------------------------------------------------------------
// preamble: weight conversions (x8 vectorized) + bias bins + e_aa + z^T.
// Wf1 rows remapped 288 -> 320 stride; pad cols zero-filled (um + wf1).
__global__ void k_pre(const float* __restrict__ Wq, const float* __restrict__ Wk,
                      const float* __restrict__ Wv, const float* __restrict__ Wo,
                      const float* __restrict__ Wf1, const float* __restrict__ Wf2,
                      const float* __restrict__ exw1, const float* __restrict__ exw2,
                      const float* __restrict__ ow1,
                      const float* __restrict__ pos_emb, const float* __restrict__ W2d,
                      const float* __restrict__ b2d, const float* __restrict__ x,
                      const float* __restrict__ aa_emb, const float* __restrict__ z,
                      short* __restrict__ wqkv_hi, short* __restrict__ wqkv_lo,
                      short* __restrict__ wo_hi, short* __restrict__ wo_lo,
                      short* __restrict__ wf1_hi, short* __restrict__ wf1_lo,
                      short* __restrict__ wf2_hi, short* __restrict__ wf2_lo,
                      short* __restrict__ wex1_hi, short* __restrict__ wex1_lo,
                      short* __restrict__ wex2_hi, short* __restrict__ wex2_lo,
                      short* __restrict__ wo1_hi, short* __restrict__ wo1_lo,
                      float* __restrict__ bb,
                      short* __restrict__ umhi, short* __restrict__ umlo,
                      short* __restrict__ zth, short* __restrict__ ztl) {
    int stride = gridDim.x * blockDim.x;
    int tid = blockIdx.x * blockDim.x + threadIdx.x;
#define CVT(src, hi, lo, per_layer, dstride, doff, scale, total)               \
    for (int i = tid; i < (total) / 8; i += stride) {                          \
        int ib = i * 8;                                                        \
        int ll = ib / (per_layer), rels = ib - ll * (per_layer);               \
        size_t di = (size_t)ll * (dstride) + (doff) + rels;                    \
        f4 v0 = *(const f4*)(src + ib);                                        \
        f4 v1 = *(const f4*)(src + ib + 4);                                    \
        bf8 hv, lv;                                                            \
        _Pragma("unroll")                                                      \
        for (int q = 0; q < 4; ++q) {                                          \
            float v = v0[q] * (scale);                                         \
            short hh = f2bf(v);                                                \
            hv[q] = hh;                                                        \
            lv[q] = f2bf(v - bf2f(hh));                                        \
        }                                                                      \
        _Pragma("unroll")                                                      \
        for (int q = 0; q < 4; ++q) {                                          \
            float v = v1[q] * (scale);                                         \
            short hh = f2bf(v);                                                \
            hv[q + 4] = hh;                                                    \
            lv[q + 4] = f2bf(v - bf2f(hh));                                    \
        }                                                                      \
        *(bf8*)(hi + di) = hv;                                                 \
        *(bf8*)(lo + di) = lv;                                                 \
    }
    CVT(Wq,  wqkv_hi, wqkv_lo, 65536, 196608, 0,      0.0625f, 393216);
    CVT(Wk,  wqkv_hi, wqkv_lo, 65536, 196608, 65536,  1.f,     393216);
    CVT(Wv,  wqkv_hi, wqkv_lo, 65536, 196608, 131072, 1.f,     393216);
    CVT(Wo,  wo_hi,  wo_lo,  65536,  65536,  0, 1.f, 393216);
    CVT(Wf2, wf2_hi, wf2_lo, 262144, 262144, 0, 1.f, 1572864);
    CVT(exw1, wex1_hi, wex1_lo, 16384, 16384, 0, 1.f, 16384);
    CVT(exw2, wex2_hi, wex2_lo, 65536, 65536, 0, 1.f, 65536);
    CVT(ow1,  wo1_hi,  wo1_lo,  65536, 65536, 0, 1.f, 65536);
#undef CVT
    // Wf1: src rows of 288 -> dest rows of 320 (row boundary 8-aligned)
    for (int i = tid; i < 1769472 / 8; i += stride) {
        int ib = i * 8;
        int ll = ib / 294912, rels = ib - ll * 294912;
        int row = rels / 288, col = rels - row * 288;
        size_t di = (size_t)ll * (1024 * UMLD) + (size_t)row * UMLD + col;
        f4 v0 = *(const f4*)(Wf1 + ib);
        f4 v1 = *(const f4*)(Wf1 + ib + 4);
        bf8 hv, lv;
#pragma unroll
        for (int q = 0; q < 4; ++q) {
            float v = v0[q];
            short hh = f2bf(v);
            hv[q] = hh;
            lv[q] = f2bf(v - bf2f(hh));
        }
#pragma unroll
        for (int q = 0; q < 4; ++q) {
            float v = v1[q];
            short hh = f2bf(v);
            hv[q + 4] = hh;
            lv[q + 4] = f2bf(v - bf2f(hh));
        }
        *(bf8*)(wf1_hi + di) = hv;
        *(bf8*)(wf1_lo + di) = lv;
    }
    // zero pad cols 288..319: wf1 (6144 rows) and um (4096 rows)
    {
        bf8 zz;
#pragma unroll
        for (int q = 0; q < 8; ++q) zz[q] = 0;
        for (int i = tid; i < 6144 * 4; i += stride) {
            int row = i >> 2, seg = i & 3;
            size_t di = (size_t)row * UMLD + UMDIM + seg * 8;
            *(bf8*)(wf1_hi + di) = zz;
            *(bf8*)(wf1_lo + di) = zz;
        }
        for (int i = tid; i < 4096 * 4; i += stride) {
            int row = i >> 2, seg = i & 3;
            size_t di = (size_t)row * UMLD + UMDIM + seg * 8;
            *(bf8*)(umhi + di) = zz;
            *(bf8*)(umlo + di) = zz;
        }
    }
    for (int idx = tid; idx < NLc * NHc * NBINSc; idx += stride) {
        int bin = idx % NBINSc;
        int tmp = idx / NBINSc;
        int hh = tmp % NHc, l = tmp / NHc;
        float s = b2d[l * NHc + hh];
        const float* pe = pos_emb + bin * PDIMc;
        const float* w  = W2d + (l * NHc + hh) * PDIMc;
        for (int p = 0; p < PDIMc; ++p) s += pe[p] * w[p];
        bb[idx] = s;
    }
    for (int tok = tid; tok < NTOK; tok += stride) {
        int n = tok / Lc, l = tok % Lc;
        const float* xp = x + (size_t)n * 20 * Lc + l;
        float best = xp[0];
        int bi = 0;
        for (int c = 1; c < 20; ++c) {
            float v = xp[c * Lc];
            if (v > best) { best = v; bi = c; }
        }
        const float* e = aa_emb + bi * E1Dc;
        bf8 hv, lv;
        for (int c8 = 0; c8 < E1Dc / 8; ++c8) {
#pragma unroll
            for (int q = 0; q < 8; ++q) {
                float v = e[c8 * 8 + q];
                short hh = f2bf(v);
                hv[q] = hh;
                lv[q] = f2bf(v - bf2f(hh));
            }
            *(bf8*)(umhi + (size_t)tok * UMLD + EMBEDc + c8 * 8) = hv;
            *(bf8*)(umlo + (size_t)tok * UMLD + EMBEDc + c8 * 8) = lv;
        }
    }
    for (int tok = tid; tok < NTOK; tok += stride) {
        int n = tok >> 9, l = tok & 511;
        bf8 hv, lv;
        for (int c8 = 0; c8 < NZc / 8; ++c8) {
#pragma unroll
            for (int q = 0; q < 8; ++q) {
                float v = z[((size_t)n * NZc + c8 * 8 + q) * Lc + l];
                short hh = f2bf(v);
                hv[q] = hh;
                lv[q] = f2bf(v - bf2f(hh));
            }
            *(bf8*)(zth + (size_t)tok * NZc + c8 * 8) = hv;
            *(bf8*)(ztl + (size_t)tok * NZc + c8 * 8) = lv;
        }
    }
}

// ---------------------------------------------------------------------------
// LDS-staged MFMA GEMM. TERMS=3: full compensated (AhBh+AhBl+AlBh).
// TERMS=2: drop AlBh (A bf16 RNE) - qkv/oproj/ffn2 (softmax- or LN-damped).
template <int EPI, int MF, int SKSHIFT, int BK, int TERMS>
__global__ __launch_bounds__(256) void k_gemm3(
    const short* __restrict__ Ahi, const short* __restrict__ Alo, int lda,
    const short* __restrict__ Bhi, const short* __restrict__ Blo, int ldb,
    int K, float* __restrict__ outf, int ldo, short* __restrict__ ohi,
    short* __restrict__ olo, int ldh, const float* __restrict__ bias,
    int gx, int gypx) {
    constexpr int PAD = BK + 8;
    __shared__ __align__(16) short Ah[MF * 64][PAD];
    __shared__ __align__(16) short Al[TERMS == 3 ? MF * 64 : 1][TERMS == 3 ? PAD : 1];
    __shared__ __align__(16) short Bh[64][PAD];
    __shared__ __align__(16) short Bl[64][PAD];

    int bid = blockIdx.x;
    int koff = 0;
    if (SKSHIFT) {
        int kh = bid >> SKSHIFT;
        bid &= (1 << SKSHIFT) - 1;
        koff = kh * K;
        outf += (size_t)kh * NTOK * EMBEDc;
    }
    int xcd = bid & 7, j = bid >> 3;
    int bx = j % gx, by = xcd * gypx + j / gx;

    int t = threadIdx.x;
    int w = t >> 6, l = t & 63, lr = l & 15, lk = l >> 4;
    int m0 = by * (MF * 64);
    int n0 = bx * 64;

    constexpr int TPR = BK / 8;
    constexpr int RP  = 256 / TPR;
    constexpr int AP  = MF * 64 / RP;
    constexpr int BP  = 64 / RP;
    int srow = t / TPR, scol = (t % TPR) * 8;

    const short* pa  = Ahi + (size_t)(m0 + srow) * lda + koff + scol;
    const short* pal = Alo + (size_t)(m0 + srow) * lda + koff + scol;
    const short* pb  = Bhi + (size_t)(n0 + srow) * ldb + koff + scol;
    const short* pbl = Blo + (size_t)(n0 + srow) * ldb + koff + scol;

    bf8 ra[AP], rla[AP], rb[BP], rlb[BP];
#pragma unroll
    for (int p = 0; p < AP; ++p) {
        ra[p] = *(const bf8*)(pa + (size_t)p * RP * lda);
        if (TERMS == 3) rla[p] = *(const bf8*)(pal + (size_t)p * RP * lda);
    }
#pragma unroll
    for (int p = 0; p < BP; ++p) {
        rb[p]  = *(const bf8*)(pb  + (size_t)p * RP * ldb);
        rlb[p] = *(const bf8*)(pbl + (size_t)p * RP * ldb);
    }

    f4 acc[MF][4];
#pragma unroll
    for (int mf = 0; mf < MF; ++mf)
#pragma unroll
        for (int nf = 0; nf < 4; ++nf) acc[mf][nf] = (f4){0.f, 0.f, 0.f, 0.f};

    for (int ks = 0; ks < K; ks += BK) {
        __syncthreads();
#pragma unroll
        for (int p = 0; p < AP; ++p) {
            *(bf8*)&Ah[p * RP + srow][scol] = ra[p];
            if (TERMS == 3) *(bf8*)&Al[p * RP + srow][scol] = rla[p];
        }
#pragma unroll
        for (int p = 0; p < BP; ++p) {
            *(bf8*)&Bh[p * RP + srow][scol] = rb[p];
            *(bf8*)&Bl[p * RP + srow][scol] = rlb[p];
        }
        __syncthreads();
        if (ks + BK < K) {
#pragma unroll
            for (int p = 0; p < AP; ++p) {
                ra[p] = *(const bf8*)(pa + (size_t)p * RP * lda + ks + BK);
                if (TERMS == 3) rla[p] = *(const bf8*)(pal + (size_t)p * RP * lda + ks + BK);
            }
#pragma unroll
            for (int p = 0; p < BP; ++p) {
                rb[p]  = *(const bf8*)(pb  + (size_t)p * RP * ldb + ks + BK);
                rlb[p] = *(const bf8*)(pbl + (size_t)p * RP * ldb + ks + BK);
            }
        }
#pragma unroll
        for (int kc = 0; kc < BK / 32; ++kc) {
            bf8 bhf[4], blf[4];
#pragma unroll
            for (int nf = 0; nf < 4; ++nf) {
                bhf[nf] = *(const bf8*)&Bh[nf * 16 + lr][kc * 32 + lk * 8];
                blf[nf] = *(const bf8*)&Bl[nf * 16 + lr][kc * 32 + lk * 8];
            }
#pragma unroll
            for (int mf = 0; mf < MF; ++mf) {
                bf8 ah = *(const bf8*)&Ah[w * MF * 16 + mf * 16 + lr][kc * 32 + lk * 8];
                bf8 al;
                if (TERMS == 3) al = *(const bf8*)&Al[w * MF * 16 + mf * 16 + lr][kc * 32 + lk * 8];
#pragma unroll
                for (int nf = 0; nf < 4; ++nf) {
                    acc[mf][nf] = MFMA(ah, bhf[nf], acc[mf][nf]);
                    acc[mf][nf] = MFMA(ah, blf[nf], acc[mf][nf]);
                    if (TERMS == 3) acc[mf][nf] = MFMA(al, bhf[nf], acc[mf][nf]);
                }
            }
        }
    }

#pragma unroll
    for (int mf = 0; mf < MF; ++mf) {
#pragma unroll
        for (int nf = 0; nf < 4; ++nf) {
            int n = n0 + nf * 16 + lr;
            int mbase = m0 + w * MF * 16 + mf * 16 + lk * 4;
            if (EPI == 0) {
#pragma unroll
                for (int r = 0; r < 4; ++r)
                    outf[(size_t)(mbase + r) * ldo + n] = acc[mf][nf][r];
            } else if (EPI == 1) {
                float bv = bias[n];
#pragma unroll
                for (int r = 0; r < 4; ++r) {
                    float y = fmaxf(acc[mf][nf][r] + bv, 0.f);
                    short hv = f2bf(y);
                    size_t oi = (size_t)(mbase + r) * ldh + n;
                    ohi[oi] = hv;
                    olo[oi] = f2bf(y - bf2f(hv));
                }
            } else if (EPI == 2) {
#pragma unroll
                for (int r = 0; r < 4; ++r) {
                    float y = acc[mf][nf][r];
                    short hv = f2bf(y);
                    size_t oi = (size_t)(mbase + r) * ldh + n;
                    ohi[oi] = hv;
                    olo[oi] = f2bf(y - bf2f(hv));
                }
            } else {
                float bv = bias[n];
#pragma unroll
                for (int r = 0; r < 4; ++r) {
                    float y = acc[mf][nf][r] + bv;
                    outf[(size_t)(mbase + r) * ldo + n] = y;
                    short hv = f2bf(y);
                    size_t oi = (size_t)(mbase + r) * ldh + n;
                    ohi[oi] = hv;
                    olo[oi] = f2bf(y - bf2f(hv));
                }
            }
        }
    }
}

// ---------------------------------------------------------------------------
// MFMA flash attention: Q and V consumed at bf16 (softmax-/oproj-damped),
// K and P stay compensated (free in the K=32 MFMA dim). 2 MFMAs/tile.
// o_lo never read downstream (oproj TERMS=2) -> only ohi written.
__global__ __launch_bounds__(512, 8) void k_attn(const short* __restrict__ qh,
                                                 const short* __restrict__ ql,
                                                 const float* __restrict__ bb,
                                                 short* __restrict__ ohi,
                                                 short* __restrict__ olo) {
    int bx = blockIdx.x;
    int qt = bx >> 7;            // 0..3; blocks sharing (n,head) same XCD
    int head = bx & 15;
    int n = (bx >> 4) & 7;
    int t = threadIdx.x;
    int w = t >> 6, l = t & 63;
    int lq = l & 15, lk = l >> 4;

    __shared__ __align__(16) short khl[256][40];   // [key][hi0-15|lo16-31|pad]
    __shared__ __align__(16) short vth[16][264];   // V^T hi: [d][key 0..255]
    __shared__ __align__(16) float pw[8][16][20];  // per-wave P[q][key] buffer
    __shared__ float biasr[64];

    if (t < NBINSc) biasr[t] = bb[head * NBINSc + t];
    float bL = bb[head * NBINSc];
    float bR = bb[head * NBINSc + 48];

    size_t base = (size_t)n * Lc * 768 + head * 16;

    int qg = qt * 128 + w * 16 + lq;             // this lane's q column
    size_t qrow = ((size_t)n * Lc + qg) * 768 + head * 16;
    bf8 B1 = *(const bf8*)(qh + qrow + (lk & 1) * 8);   // [Qh|Qh]

    f4 acc = (f4){0.f, 0.f, 0.f, 0.f};
    float m = -1e30f, lsum = 0.f;
    int rel0 = lk * 4 - qg;      // rel of s[0] at global kt=0; += 16 per tile

    for (int half = 0; half < 2; ++half) {
        __syncthreads();          // previous half fully consumed
        // stage K half (256 keys; hi+lo packed per row)
        for (int u = t; u < 1024; u += 512) {
            int key = u >> 2, seg = u & 3;
            const short* src = (seg < 2 ? qh : ql) + base + 256
                             + (size_t)(half * 256 + key) * 768 + (seg & 1) * 8;
            *(bf8*)&khl[key][seg * 8] = *(const bf8*)src;
        }
        // stage V half transposed (hi only), pair-packed b32 writes
        if (t < 256) {
            int u = t & 127;             // key pair
            int dhalf = (t >> 7) & 1;    // d 0..7 / 8..15
            int gkey = half * 256 + u * 2;
            const short* vs = qh + base + 512 + (size_t)gkey * 768 + dhalf * 8;
            bf8 A = *(const bf8*)vs;
            bf8 B = *(const bf8*)(vs + 768);
            unsigned* vw = (unsigned*)&vth[0][0];  // row stride 132 words
#pragma unroll
            for (int i = 0; i < 8; ++i)
                vw[(dhalf * 8 + i) * 132 + u] =
                    (unsigned)(unsigned short)A[i] | ((unsigned)(unsigned short)B[i] << 16);
        }
        __syncthreads();

        for (int kt = 0; kt < 16; ++kt, rel0 += 16) {
            bf8 A1 = *(const bf8*)&khl[kt * 16 + lq][lk * 8];  // [Kh|Kl]
            f4 s = (f4){0.f, 0.f, 0.f, 0.f};
            __builtin_amdgcn_s_setprio(1);
            s = MFMA(A1, B1, s);      // KhQh + KlQh  (K compensated, Q bf16)
            __builtin_amdgcn_s_setprio(0);
            if (rel0 >= PMAXLc) {
                s[0] += bR; s[1] += bR; s[2] += bR; s[3] += bR;
            } else if (rel0 + 3 <= -PMAXLc) {
                s[0] += bL; s[1] += bL; s[2] += bL; s[3] += bL;
            } else {
#pragma unroll
                for (int r = 0; r < 4; ++r) {
                    int rel = rel0 + r;
                    rel = rel < -PMAXLc ? -PMAXLc : (rel > PMAXLc ? PMAXLc : rel);
                    s[r] += biasr[rel + PMAXLc];
                }
            }
            float mt = fmaxf(fmaxf(s[0], s[1]), fmaxf(s[2], s[3]));
            mt = fmaxf(mt, __shfl_xor(mt, 16));
            mt = fmaxf(mt, __shfl_xor(mt, 32));
            if (__any(mt > m + 8.0f)) {
                float mn = fmaxf(m, mt);
                float alpha = __expf(m - mn);
                m = mn;
                lsum *= alpha;
#pragma unroll
                for (int r = 0; r < 4; ++r) acc[r] *= __shfl(alpha, lk * 4 + r);
            }
            f4 p;
#pragma unroll
            for (int r = 0; r < 4; ++r) p[r] = __expf(s[r] - m);
            lsum += p[0] + p[1] + p[2] + p[3];
            // P routed via per-wave LDS (wave-synchronous, no barrier)
            *(f4*)&pw[w][lq][lk * 4] = p;
            const float* pr = &pw[w][lq][(lk & 1) * 8];
            f4 ga = *(const f4*)pr;
            f4 gb = *(const f4*)(pr + 4);
            bf8 PA;                       // [Ph|Pl] along MFMA K-dim
            if (lk < 2) {
#pragma unroll
                for (int jj = 0; jj < 4; ++jj) {
                    PA[jj]     = (short)(__float_as_uint(ga[jj]) >> 16);
                    PA[jj + 4] = (short)(__float_as_uint(gb[jj]) >> 16);
                }
            } else {
#pragma unroll
                for (int jj = 0; jj < 4; ++jj) {
                    unsigned hu0 = __float_as_uint(ga[jj]) & 0xFFFF0000u;
                    unsigned hu1 = __float_as_uint(gb[jj]) & 0xFFFF0000u;
                    PA[jj]     = (short)(__float_as_uint(ga[jj] - __uint_as_float(hu0)) >> 16);
                    PA[jj + 4] = (short)(__float_as_uint(gb[jj] - __uint_as_float(hu1)) >> 16);
                }
            }
            bf8 VB1 = *(const bf8*)&vth[lq][kt * 16 + (lk & 1) * 8];  // [Vh|Vh]
            __builtin_amdgcn_s_setprio(1);
            acc = MFMA(PA, VB1, acc);   // (Ph+Pl)Vh  (P compensated, V bf16)
            __builtin_amdgcn_s_setprio(0);
        }
    }

    float lred = lsum + __shfl_xor(lsum, 16);
    lred += __shfl_xor(lred, 32);
    float inv = 1.0f / lred;
#pragma unroll
    for (int r = 0; r < 4; ++r) {
        float iq = __shfl(inv, lk * 4 + r);
        float y = acc[r] * iq;
        int qo = qt * 128 + w * 16 + lk * 4 + r;
        size_t oi = ((size_t)n * Lc + qo) * DMc + head * 16 + lq;
        ohi[oi] = f2bf(y);   // RNE; o_lo never read (oproj TERMS=2)
    }
}

// ---------------------------------------------------------------------------
// LN over h + s2a + s2b + sbias, fully f4-vectorized. um stride = UMLD.
__global__ __launch_bounds__(256) void k_ln(const float* __restrict__ s2a,
                                            const float* __restrict__ s2b,
                                            const float* __restrict__ sbias,
                                            const float* __restrict__ g,
                                            const float* __restrict__ bta,
                                            float* __restrict__ h,
                                            short* __restrict__ umhi,
                                            short* __restrict__ umlo) {
    int t = threadIdx.x;
    int tl = t >> 5, j = t & 31;
    size_t gtok = (size_t)blockIdx.x * 8 + tl;
    int d0 = j * 8;
    size_t off = gtok * EMBEDc + d0;
    f4 h0 = *(const f4*)(h + off);
    f4 h1 = *(const f4*)(h + off + 4);
    f4 a0 = *(const f4*)(s2a + off);
    f4 a1 = *(const f4*)(s2a + off + 4);
    f4 b0 = *(const f4*)(s2b + off);
    f4 b1 = *(const f4*)(s2b + off + 4);
    f4 sb0 = *(const f4*)(sbias + d0);
    f4 sb1 = *(const f4*)(sbias + d0 + 4);
    f4 v0 = h0 + a0 + b0 + sb0;
    f4 v1 = h1 + a1 + b1 + sb1;
    float sum = v0[0] + v0[1] + v0[2] + v0[3] + v1[0] + v1[1] + v1[2] + v1[3];
    float ssq = v0[0]*v0[0] + v0[1]*v0[1] + v0[2]*v0[2] + v0[3]*v0[3]
              + v1[0]*v1[0] + v1[1]*v1[1] + v1[2]*v1[2] + v1[3]*v1[3];
#pragma unroll
    for (int off5 = 16; off5; off5 >>= 1) {
        sum += __shfl_xor(sum, off5, 32);
        ssq += __shfl_xor(ssq, off5, 32);
    }
    float mean = sum * (1.f / EMBEDc);
    float var = ssq * (1.f / EMBEDc) - mean * mean;
    float inv = rsqrtf(var + 1e-5f);
    f4 g0 = *(const f4*)(g + d0);
    f4 g1 = *(const f4*)(g + d0 + 4);
    f4 t0 = *(const f4*)(bta + d0);
    f4 t1 = *(const f4*)(bta + d0 + 4);
    f4 y0, y1;
    bf8 hv, lv;
#pragma unroll
    for (int q = 0; q < 4; ++q) {
        float y = (v0[q] - mean) * inv * g0[q] + t0[q];
        y0[q] = y;
        short hh = f2bf(y);
        hv[q] = hh;
        lv[q] = f2bf(y - bf2f(hh));
    }
#pragma unroll
    for (int q = 0; q < 4; ++q) {
        float y = (v1[q] - mean) * inv * g1[q] + t1[q];
        y1[q] = y;
        short hh = f2bf(y);
        hv[q + 4] = hh;
        lv[q + 4] = f2bf(y - bf2f(hh));
    }
    *(f4*)(h + off) = y0;
    *(f4*)(h + off + 4) = y1;
    *(bf8*)(umhi + gtok * UMLD + d0) = hv;
    *(bf8*)(umlo + gtok * UMLD + d0) = lv;
}

// ---------------------------------------------------------------------------
__global__ __launch_bounds__(256) void k_r(const short* __restrict__ fh,
                                           const short* __restrict__ fl,
                                           const float* __restrict__ w2,
                                           const float* __restrict__ b2,
                                           float* __restrict__ r) {
    __shared__ float w[3][EMBEDc];
    int t = threadIdx.x;
    for (int u = t; u < 3 * EMBEDc; u += 256) w[u >> 8][u & 255] = w2[u];
    __syncthreads();
    int tok = blockIdx.x * 64 + (t >> 2), o = t & 3;
    if (o < 3) {
        const short* ph = fh + (size_t)tok * EMBEDc;
        const short* pl = fl + (size_t)tok * EMBEDc;
        float s = b2[o];
        for (int c8 = 0; c8 < EMBEDc / 8; ++c8) {
            bf8 vh = *(const bf8*)(ph + c8 * 8);
            bf8 vl = *(const bf8*)(pl + c8 * 8);
#pragma unroll
            for (int j = 0; j < 8; ++j)
                s += (bf2f(vh[j]) + bf2f(vl[j])) * w[o][c8 * 8 + j];
        }
        r[(size_t)tok * 3 + o] = s;
    }
}

// ---------------------------------------------------------------------------
__global__ __launch_bounds__(256) void k_dmap(const float* __restrict__ r,
                                              float* __restrict__ d) {
    int b = blockIdx.x;
    int n = b / Lc;
    float xi = r[(size_t)b * 3], yi = r[(size_t)b * 3 + 1], zi = r[(size_t)b * 3 + 2];
    const float* rn = r + (size_t)n * Lc * 3;
    for (int j = threadIdx.x; j < Lc; j += 256) {
        float dx = xi - rn[j * 3];
        float dy = yi - rn[j * 3 + 1];
        float dz = zi - rn[j * 3 + 2];
        d[(size_t)b * Lc + j] = sqrtf(dx * dx + dy * dy + dz * dz + 1e-12f);
    }
}

// ---------------------------------------------------------------------------
extern "C" void kernel_launch(void* const* d_in, const int* in_sizes, int n_in,
                              void* d_out, int out_size, void* d_ws, size_t ws_size,
                              hipStream_t stream) {
    const float* z       = (const float*)d_in[0];
    const float* x       = (const float*)d_in[1];
    const float* pos_emb = (const float*)d_in[2];
    const float* aa_emb  = (const float*)d_in[3];
    const float* ex_w1   = (const float*)d_in[4];
    const float* ex_b1   = (const float*)d_in[5];
    const float* ex_w2   = (const float*)d_in[6];
    const float* ex_b2   = (const float*)d_in[7];
    const float* Wq      = (const float*)d_in[8];
    const float* Wk      = (const float*)d_in[9];
    const float* Wv      = (const float*)d_in[10];
    const float* Wo      = (const float*)d_in[11];
    const float* bo      = (const float*)d_in[12];
    const float* W2d     = (const float*)d_in[13];
    const float* b2d     = (const float*)d_in[14];
    const float* Wf1     = (const float*)d_in[15];
    const float* bf1     = (const float*)d_in[16];
    const float* Wf2     = (const float*)d_in[17];
    const float* bf2     = (const float*)d_in[18];
    const float* ln1_g   = (const float*)d_in[19];
    const float* ln1_b   = (const float*)d_in[20];
    const float* ln2_g   = (const float*)d_in[21];
    const float* ln2_b   = (const float*)d_in[22];
    const float* o_w1    = (const float*)d_in[23];
    const float* o_b1    = (const float*)d_in[24];
    const float* o_w2    = (const float*)d_in[25];
    const float* o_b2    = (const float*)d_in[26];

    float* h    = (float*)d_ws;                    // 4096*256
    float* s2a  = h + (size_t)NTOK * EMBEDc;
    float* s2b  = s2a + (size_t)NTOK * EMBEDc;
    float* bbuf = s2b + (size_t)NTOK * EMBEDc;     // pad 8192
    float* r    = bbuf + 8192;                     // pad 16384
    short* qkvh = (short*)(r + 16384);             // 4096*768
    short* qkvl = qkvh + (size_t)NTOK * 768;
    short* um_hi = qkvl + (size_t)NTOK * 768;      // 4096*320 (padded)
    short* um_lo = um_hi + (size_t)NTOK * UMLD;
    short* o_hi  = um_lo + (size_t)NTOK * UMLD;    // 4096*256
    short* o_lo  = o_hi + (size_t)NTOK * EMBEDc;
    short* f1_hi = o_lo + (size_t)NTOK * EMBEDc;   // 4096*1024
    short* f1_lo = f1_hi + (size_t)NTOK * DFFc;
    short* wqkv_hi = f1_lo + (size_t)NTOK * DFFc;  // 6*768*256
    short* wqkv_lo = wqkv_hi + (size_t)NLc * 768 * EMBEDc;
    short* wo_hi   = wqkv_lo + (size_t)NLc * 768 * EMBEDc;   // 6*256*256
    short* wo_lo   = wo_hi + (size_t)NLc * EMBEDc * DMc;
    short* wf1_hi  = wo_lo + (size_t)NLc * EMBEDc * DMc;     // 6*1024*320 (padded)
    short* wf1_lo  = wf1_hi + (size_t)NLc * DFFc * UMLD;
    short* wf2_hi  = wf1_lo + (size_t)NLc * DFFc * UMLD;     // 6*256*1024
    short* wf2_lo  = wf2_hi + (size_t)NLc * EMBEDc * DFFc;
    short* wex1_hi = wf2_lo + (size_t)NLc * EMBEDc * DFFc;   // 256*64
    short* wex1_lo = wex1_hi + EMBEDc * NZc;
    short* wex2_hi = wex1_lo + EMBEDc * NZc;                 // 256*256
    short* wex2_lo = wex2_hi + EMBEDc * EMBEDc;
    short* wo1_hi  = wex2_lo + EMBEDc * EMBEDc;              // 256*256
    short* wo1_lo  = wo1_hi + EMBEDc * EMBEDc;
    // zt aliases the o buffer (only used in preamble, before k_attn writes o)
    short* zt_hi = o_hi;
    short* zt_lo = o_lo;

    k_pre<<<1024, 256, 0, stream>>>(Wq, Wk, Wv, Wo, Wf1, Wf2, ex_w1, ex_w2, o_w1,
                                    pos_emb, W2d, b2d, x, aa_emb, z,
                                    wqkv_hi, wqkv_lo, wo_hi, wo_lo,
                                    wf1_hi, wf1_lo, wf2_hi, wf2_lo,
                                    wex1_hi, wex1_lo, wex2_hi, wex2_lo,
                                    wo1_hi, wo1_lo, bbuf, um_hi, um_lo,
                                    zt_hi, zt_lo);

    // embed: relu GEMM -> GEMM (fp32 h + bf16 um, ldh = UMLD)
    k_gemm3<1, 1, 0, 64, 3><<<256, 256, 0, stream>>>(
        zt_hi, zt_lo, NZc, wex1_hi, wex1_lo, NZc, NZc,
        nullptr, 0, f1_hi, f1_lo, EMBEDc, ex_b1, 4, 8);
    k_gemm3<3, 1, 0, 64, 3><<<256, 256, 0, stream>>>(
        f1_hi, f1_lo, EMBEDc, wex2_hi, wex2_lo, EMBEDc, EMBEDc,
        h, EMBEDc, um_hi, um_lo, UMLD, ex_b2, 4, 8);

    for (int l = 0; l < NLc; ++l) {
        // qkv: TERMS=2 (A bf16; softmax damps the error)
        k_gemm3<2, 1, 0, 64, 2><<<768, 256, 0, stream>>>(
            um_hi, um_lo, UMLD,
            wqkv_hi + (size_t)l * 768 * EMBEDc, wqkv_lo + (size_t)l * 768 * EMBEDc, EMBEDc,
            EMBEDc, nullptr, 0, qkvh, qkvl, 768, nullptr, 12, 8);
        k_attn<<<NB * NHc * 4, 512, 0, stream>>>(qkvh, qkvl, bbuf + (size_t)l * NHc * NBINSc, o_hi, o_lo);
        // oproj: TERMS=2 (o RNE bf16; LN damps the error)
        k_gemm3<0, 1, 8, 64, 2><<<512, 256, 0, stream>>>(
            o_hi, o_lo, EMBEDc,
            wo_hi + (size_t)l * EMBEDc * DMc, wo_lo + (size_t)l * EMBEDc * DMc, DMc,
            128, s2a, EMBEDc, nullptr, nullptr, 0, nullptr, 4, 8);
        k_ln<<<NTOK / 8, 256, 0, stream>>>(s2a, s2b, bo + (size_t)l * EMBEDc,
                                           ln1_g + (size_t)l * EMBEDc, ln1_b + (size_t)l * EMBEDc,
                                           h, um_hi, um_lo);
        // ffn1: K padded 288->320, BK=64 (3-term)
        k_gemm3<1, 2, 0, 64, 3><<<512, 256, 0, stream>>>(
            um_hi, um_lo, UMLD,
            wf1_hi + (size_t)l * DFFc * UMLD, wf1_lo + (size_t)l * DFFc * UMLD, UMLD,
            UMLD, nullptr, 0, f1_hi, f1_lo, DFFc, bf1 + (size_t)l * DFFc, 16, 4);
        // ffn2: TERMS=2 (f1 RNE bf16; LN damps the error)
        k_gemm3<0, 1, 8, 64, 2><<<512, 256, 0, stream>>>(
            f1_hi, f1_lo, DFFc,
            wf2_hi + (size_t)l * EMBEDc * DFFc, wf2_lo + (size_t)l * EMBEDc * DFFc, DFFc,
            512, s2a, EMBEDc, nullptr, nullptr, 0, nullptr, 4, 8);
        k_ln<<<NTOK / 8, 256, 0, stream>>>(s2a, s2b, bf2 + (size_t)l * EMBEDc,
                                           ln2_g + (size_t)l * EMBEDc, ln2_b + (size_t)l * EMBEDc,
                                           h, um_hi, um_lo);
    }

    // final: f = relu(um @ o_w1^T + o_b1) (um cols 0..255 hold h in bf16)
    k_gemm3<1, 1, 0, 64, 3><<<256, 256, 0, stream>>>(
        um_hi, um_lo, UMLD, wo1_hi, wo1_lo, EMBEDc, EMBEDc,
        nullptr, 0, f1_hi, f1_lo, EMBEDc, o_b1, 4, 8);
    k_r<<<NTOK / 64, 256, 0, stream>>>(f1_hi, f1_lo, o_w2, o_b2, r);
    k_dmap<<<NB * Lc, 256, 0, stream>>>(r, (float*)d_out);
}

// Round 20
// 472.157 us; speedup vs baseline: 1.2764x; 1.0586x over previous
//
#include <hip/hip_runtime.h>
#include <math.h>

#define NZc     64
#define EMBEDc  256
#define DMc     256
#define NHc     16
#define HDc     16
#define DFFc    1024
#define NLc     6
#define E1Dc    32
#define PDIMc   64
#define PMAXLc  24
#define NBINSc  49
#define NB      8
#define Lc      512
#define NTOK    (NB * Lc)        // 4096
#define UMDIM   288              // logical um width
#define UMLD    320              // padded leading dim (zeros in 288..319)

typedef __attribute__((ext_vector_type(4))) float f4;
typedef __attribute__((ext_vector_type(8))) short bf8;   // 8 bf16 in 4 VGPRs

#define MFMA(a, b, c) __builtin_amdgcn_mfma_f32_16x16x32_bf16((a), (b), (c), 0, 0, 0)

__device__ __forceinline__ short f2bf(float f) {
    unsigned u = __float_as_uint(f);
    u += 0x7FFFu + ((u >> 16) & 1u);   // round-to-nearest-even
    return (short)(u >> 16);
}
__device__ __forceinline__ float bf2f(short s) {
    return __uint_as_float(((unsigned)(unsigned short)s) << 16);
}

// ---------------------------------------------------------------------------
// preamble: weight conversions (x8 vectorized) + bias bins + e_aa + z^T.
// Wf1 rows remapped 288 -> 320 stride; pad cols zero-filled (um + wf1).
__global__ void k_pre(const float* __restrict__ Wq, const float* __restrict__ Wk,
                      const float* __restrict__ Wv, const float* __restrict__ Wo,
                      const float* __restrict__ Wf1, const float* __restrict__ Wf2,
                      const float* __restrict__ exw1, const float* __restrict__ exw2,
                      const float* __restrict__ ow1,
                      const float* __restrict__ pos_emb, const float* __restrict__ W2d,
                      const float* __restrict__ b2d, const float* __restrict__ x,
                      const float* __restrict__ aa_emb, const float* __restrict__ z,
                      short* __restrict__ wqkv_hi, short* __restrict__ wqkv_lo,
                      short* __restrict__ wo_hi, short* __restrict__ wo_lo,
                      short* __restrict__ wf1_hi, short* __restrict__ wf1_lo,
                      short* __restrict__ wf2_hi, short* __restrict__ wf2_lo,
                      short* __restrict__ wex1_hi, short* __restrict__ wex1_lo,
                      short* __restrict__ wex2_hi, short* __restrict__ wex2_lo,
                      short* __restrict__ wo1_hi, short* __restrict__ wo1_lo,
                      float* __restrict__ bb,
                      short* __restrict__ umhi, short* __restrict__ umlo,
                      short* __restrict__ zth, short* __restrict__ ztl) {
    int stride = gridDim.x * blockDim.x;
    int tid = blockIdx.x * blockDim.x + threadIdx.x;
#define CVT(src, hi, lo, per_layer, dstride, doff, scale, total)               \
    for (int i = tid; i < (total) / 8; i += stride) {                          \
        int ib = i * 8;                                                        \
        int ll = ib / (per_layer), rels = ib - ll * (per_layer);               \
        size_t di = (size_t)ll * (dstride) + (doff) + rels;                    \
        f4 v0 = *(const f4*)(src + ib);                                        \
        f4 v1 = *(const f4*)(src + ib + 4);                                    \
        bf8 hv, lv;                                                            \
        _Pragma("unroll")                                                      \
        for (int q = 0; q < 4; ++q) {                                          \
            float v = v0[q] * (scale);                                         \
            short hh = f2bf(v);                                                \
            hv[q] = hh;                                                        \
            lv[q] = f2bf(v - bf2f(hh));                                        \
        }                                                                      \
        _Pragma("unroll")                                                      \
        for (int q = 0; q < 4; ++q) {                                          \
            float v = v1[q] * (scale);                                         \
            short hh = f2bf(v);                                                \
            hv[q + 4] = hh;                                                    \
            lv[q + 4] = f2bf(v - bf2f(hh));                                    \
        }                                                                      \
        *(bf8*)(hi + di) = hv;                                                 \
        *(bf8*)(lo + di) = lv;                                                 \
    }
    CVT(Wq,  wqkv_hi, wqkv_lo, 65536, 196608, 0,      0.0625f, 393216);
    CVT(Wk,  wqkv_hi, wqkv_lo, 65536, 196608, 65536,  1.f,     393216);
    CVT(Wv,  wqkv_hi, wqkv_lo, 65536, 196608, 131072, 1.f,     393216);
    CVT(Wo,  wo_hi,  wo_lo,  65536,  65536,  0, 1.f, 393216);
    CVT(Wf2, wf2_hi, wf2_lo, 262144, 262144, 0, 1.f, 1572864);
    CVT(exw1, wex1_hi, wex1_lo, 16384, 16384, 0, 1.f, 16384);
    CVT(exw2, wex2_hi, wex2_lo, 65536, 65536, 0, 1.f, 65536);
    CVT(ow1,  wo1_hi,  wo1_lo,  65536, 65536, 0, 1.f, 65536);
#undef CVT
    // Wf1: src rows of 288 -> dest rows of 320 (row boundary 8-aligned)
    for (int i = tid; i < 1769472 / 8; i += stride) {
        int ib = i * 8;
        int ll = ib / 294912, rels = ib - ll * 294912;
        int row = rels / 288, col = rels - row * 288;
        size_t di = (size_t)ll * (1024 * UMLD) + (size_t)row * UMLD + col;
        f4 v0 = *(const f4*)(Wf1 + ib);
        f4 v1 = *(const f4*)(Wf1 + ib + 4);
        bf8 hv, lv;
#pragma unroll
        for (int q = 0; q < 4; ++q) {
            float v = v0[q];
            short hh = f2bf(v);
            hv[q] = hh;
            lv[q] = f2bf(v - bf2f(hh));
        }
#pragma unroll
        for (int q = 0; q < 4; ++q) {
            float v = v1[q];
            short hh = f2bf(v);
            hv[q + 4] = hh;
            lv[q + 4] = f2bf(v - bf2f(hh));
        }
        *(bf8*)(wf1_hi + di) = hv;
        *(bf8*)(wf1_lo + di) = lv;
    }
    // zero pad cols 288..319: wf1 (6144 rows) and um (4096 rows)
    {
        bf8 zz;
#pragma unroll
        for (int q = 0; q < 8; ++q) zz[q] = 0;
        for (int i = tid; i < 6144 * 4; i += stride) {
            int row = i >> 2, seg = i & 3;
            size_t di = (size_t)row * UMLD + UMDIM + seg * 8;
            *(bf8*)(wf1_hi + di) = zz;
            *(bf8*)(wf1_lo + di) = zz;
        }
        for (int i = tid; i < 4096 * 4; i += stride) {
            int row = i >> 2, seg = i & 3;
            size_t di = (size_t)row * UMLD + UMDIM + seg * 8;
            *(bf8*)(umhi + di) = zz;
            *(bf8*)(umlo + di) = zz;
        }
    }
    for (int idx = tid; idx < NLc * NHc * NBINSc; idx += stride) {
        int bin = idx % NBINSc;
        int tmp = idx / NBINSc;
        int hh = tmp % NHc, l = tmp / NHc;
        float s = b2d[l * NHc + hh];
        const float* pe = pos_emb + bin * PDIMc;
        const float* w  = W2d + (l * NHc + hh) * PDIMc;
        for (int p = 0; p < PDIMc; ++p) s += pe[p] * w[p];
        bb[idx] = s;
    }
    for (int tok = tid; tok < NTOK; tok += stride) {
        int n = tok / Lc, l = tok % Lc;
        const float* xp = x + (size_t)n * 20 * Lc + l;
        float best = xp[0];
        int bi = 0;
        for (int c = 1; c < 20; ++c) {
            float v = xp[c * Lc];
            if (v > best) { best = v; bi = c; }
        }
        const float* e = aa_emb + bi * E1Dc;
        bf8 hv, lv;
        for (int c8 = 0; c8 < E1Dc / 8; ++c8) {
#pragma unroll
            for (int q = 0; q < 8; ++q) {
                float v = e[c8 * 8 + q];
                short hh = f2bf(v);
                hv[q] = hh;
                lv[q] = f2bf(v - bf2f(hh));
            }
            *(bf8*)(umhi + (size_t)tok * UMLD + EMBEDc + c8 * 8) = hv;
            *(bf8*)(umlo + (size_t)tok * UMLD + EMBEDc + c8 * 8) = lv;
        }
    }
    for (int tok = tid; tok < NTOK; tok += stride) {
        int n = tok >> 9, l = tok & 511;
        bf8 hv, lv;
        for (int c8 = 0; c8 < NZc / 8; ++c8) {
#pragma unroll
            for (int q = 0; q < 8; ++q) {
                float v = z[((size_t)n * NZc + c8 * 8 + q) * Lc + l];
                short hh = f2bf(v);
                hv[q] = hh;
                lv[q] = f2bf(v - bf2f(hh));
            }
            *(bf8*)(zth + (size_t)tok * NZc + c8 * 8) = hv;
            *(bf8*)(ztl + (size_t)tok * NZc + c8 * 8) = lv;
        }
    }
}

// ---------------------------------------------------------------------------
// LDS-staged MFMA GEMM. TERMS=3: full compensated (AhBh+AhBl+AlBh).
// TERMS=2: drop AlBh (A bf16 RNE) - qkv/oproj/ffn1/ffn2 (damped downstream).
// EPI 0: fp32 out. 1: relu->hi/lo. 2: ->hi/lo. 3: fp32+hi/lo. 4: relu->hi only.
template <int EPI, int MF, int SKSHIFT, int BK, int TERMS>
__global__ __launch_bounds__(256) void k_gemm3(
    const short* __restrict__ Ahi, const short* __restrict__ Alo, int lda,
    const short* __restrict__ Bhi, const short* __restrict__ Blo, int ldb,
    int K, float* __restrict__ outf, int ldo, short* __restrict__ ohi,
    short* __restrict__ olo, int ldh, const float* __restrict__ bias,
    int gx, int gypx) {
    constexpr int PAD = BK + 8;
    __shared__ __align__(16) short Ah[MF * 64][PAD];
    __shared__ __align__(16) short Al[TERMS == 3 ? MF * 64 : 1][TERMS == 3 ? PAD : 1];
    __shared__ __align__(16) short Bh[64][PAD];
    __shared__ __align__(16) short Bl[64][PAD];

    int bid = blockIdx.x;
    int koff = 0;
    if (SKSHIFT) {
        int kh = bid >> SKSHIFT;
        bid &= (1 << SKSHIFT) - 1;
        koff = kh * K;
        outf += (size_t)kh * NTOK * EMBEDc;
    }
    int xcd = bid & 7, j = bid >> 3;
    int bx = j % gx, by = xcd * gypx + j / gx;

    int t = threadIdx.x;
    int w = t >> 6, l = t & 63, lr = l & 15, lk = l >> 4;
    int m0 = by * (MF * 64);
    int n0 = bx * 64;

    constexpr int TPR = BK / 8;
    constexpr int RP  = 256 / TPR;
    constexpr int AP  = MF * 64 / RP;
    constexpr int BP  = 64 / RP;
    int srow = t / TPR, scol = (t % TPR) * 8;

    const short* pa  = Ahi + (size_t)(m0 + srow) * lda + koff + scol;
    const short* pal = Alo + (size_t)(m0 + srow) * lda + koff + scol;
    const short* pb  = Bhi + (size_t)(n0 + srow) * ldb + koff + scol;
    const short* pbl = Blo + (size_t)(n0 + srow) * ldb + koff + scol;

    bf8 ra[AP], rla[AP], rb[BP], rlb[BP];
#pragma unroll
    for (int p = 0; p < AP; ++p) {
        ra[p] = *(const bf8*)(pa + (size_t)p * RP * lda);
        if (TERMS == 3) rla[p] = *(const bf8*)(pal + (size_t)p * RP * lda);
    }
#pragma unroll
    for (int p = 0; p < BP; ++p) {
        rb[p]  = *(const bf8*)(pb  + (size_t)p * RP * ldb);
        rlb[p] = *(const bf8*)(pbl + (size_t)p * RP * ldb);
    }

    f4 acc[MF][4];
#pragma unroll
    for (int mf = 0; mf < MF; ++mf)
#pragma unroll
        for (int nf = 0; nf < 4; ++nf) acc[mf][nf] = (f4){0.f, 0.f, 0.f, 0.f};

    for (int ks = 0; ks < K; ks += BK) {
        __syncthreads();
#pragma unroll
        for (int p = 0; p < AP; ++p) {
            *(bf8*)&Ah[p * RP + srow][scol] = ra[p];
            if (TERMS == 3) *(bf8*)&Al[p * RP + srow][scol] = rla[p];
        }
#pragma unroll
        for (int p = 0; p < BP; ++p) {
            *(bf8*)&Bh[p * RP + srow][scol] = rb[p];
            *(bf8*)&Bl[p * RP + srow][scol] = rlb[p];
        }
        __syncthreads();
        if (ks + BK < K) {
#pragma unroll
            for (int p = 0; p < AP; ++p) {
                ra[p] = *(const bf8*)(pa + (size_t)p * RP * lda + ks + BK);
                if (TERMS == 3) rla[p] = *(const bf8*)(pal + (size_t)p * RP * lda + ks + BK);
            }
#pragma unroll
            for (int p = 0; p < BP; ++p) {
                rb[p]  = *(const bf8*)(pb  + (size_t)p * RP * ldb + ks + BK);
                rlb[p] = *(const bf8*)(pbl + (size_t)p * RP * ldb + ks + BK);
            }
        }
#pragma unroll
        for (int kc = 0; kc < BK / 32; ++kc) {
            bf8 bhf[4], blf[4];
#pragma unroll
            for (int nf = 0; nf < 4; ++nf) {
                bhf[nf] = *(const bf8*)&Bh[nf * 16 + lr][kc * 32 + lk * 8];
                blf[nf] = *(const bf8*)&Bl[nf * 16 + lr][kc * 32 + lk * 8];
            }
#pragma unroll
            for (int mf = 0; mf < MF; ++mf) {
                bf8 ah = *(const bf8*)&Ah[w * MF * 16 + mf * 16 + lr][kc * 32 + lk * 8];
                bf8 al;
                if (TERMS == 3) al = *(const bf8*)&Al[w * MF * 16 + mf * 16 + lr][kc * 32 + lk * 8];
#pragma unroll
                for (int nf = 0; nf < 4; ++nf) {
                    acc[mf][nf] = MFMA(ah, bhf[nf], acc[mf][nf]);
                    acc[mf][nf] = MFMA(ah, blf[nf], acc[mf][nf]);
                    if (TERMS == 3) acc[mf][nf] = MFMA(al, bhf[nf], acc[mf][nf]);
                }
            }
        }
    }

#pragma unroll
    for (int mf = 0; mf < MF; ++mf) {
#pragma unroll
        for (int nf = 0; nf < 4; ++nf) {
            int n = n0 + nf * 16 + lr;
            int mbase = m0 + w * MF * 16 + mf * 16 + lk * 4;
            if (EPI == 0) {
#pragma unroll
                for (int r = 0; r < 4; ++r)
                    outf[(size_t)(mbase + r) * ldo + n] = acc[mf][nf][r];
            } else if (EPI == 1) {
                float bv = bias[n];
#pragma unroll
                for (int r = 0; r < 4; ++r) {
                    float y = fmaxf(acc[mf][nf][r] + bv, 0.f);
                    short hv = f2bf(y);
                    size_t oi = (size_t)(mbase + r) * ldh + n;
                    ohi[oi] = hv;
                    olo[oi] = f2bf(y - bf2f(hv));
                }
            } else if (EPI == 2) {
#pragma unroll
                for (int r = 0; r < 4; ++r) {
                    float y = acc[mf][nf][r];
                    short hv = f2bf(y);
                    size_t oi = (size_t)(mbase + r) * ldh + n;
                    ohi[oi] = hv;
                    olo[oi] = f2bf(y - bf2f(hv));
                }
            } else if (EPI == 3) {
                float bv = bias[n];
#pragma unroll
                for (int r = 0; r < 4; ++r) {
                    float y = acc[mf][nf][r] + bv;
                    outf[(size_t)(mbase + r) * ldo + n] = y;
                    short hv = f2bf(y);
                    size_t oi = (size_t)(mbase + r) * ldh + n;
                    ohi[oi] = hv;
                    olo[oi] = f2bf(y - bf2f(hv));
                }
            } else {   // EPI == 4: relu(acc+bias) -> hi only (lo consumer dead)
                float bv = bias[n];
#pragma unroll
                for (int r = 0; r < 4; ++r) {
                    float y = fmaxf(acc[mf][nf][r] + bv, 0.f);
                    ohi[(size_t)(mbase + r) * ldh + n] = f2bf(y);
                }
            }
        }
    }
}

// ---------------------------------------------------------------------------
// MFMA flash attention: Q and V consumed at bf16 (softmax-/oproj-damped),
// K and P stay compensated (free in the K=32 MFMA dim). 2 MFMAs/tile.
// o_lo never read downstream (oproj TERMS=2) -> only ohi written.
__global__ __launch_bounds__(512, 8) void k_attn(const short* __restrict__ qh,
                                                 const short* __restrict__ ql,
                                                 const float* __restrict__ bb,
                                                 short* __restrict__ ohi,
                                                 short* __restrict__ olo) {
    int bx = blockIdx.x;
    int qt = bx >> 7;            // 0..3; blocks sharing (n,head) same XCD
    int head = bx & 15;
    int n = (bx >> 4) & 7;
    int t = threadIdx.x;
    int w = t >> 6, l = t & 63;
    int lq = l & 15, lk = l >> 4;

    __shared__ __align__(16) short khl[256][40];   // [key][hi0-15|lo16-31|pad]
    __shared__ __align__(16) short vth[16][264];   // V^T hi: [d][key 0..255]
    __shared__ __align__(16) float pw[8][16][20];  // per-wave P[q][key] buffer
    __shared__ float biasr[64];

    if (t < NBINSc) biasr[t] = bb[head * NBINSc + t];
    float bL = bb[head * NBINSc];
    float bR = bb[head * NBINSc + 48];

    size_t base = (size_t)n * Lc * 768 + head * 16;

    int qg = qt * 128 + w * 16 + lq;             // this lane's q column
    size_t qrow = ((size_t)n * Lc + qg) * 768 + head * 16;
    bf8 B1 = *(const bf8*)(qh + qrow + (lk & 1) * 8);   // [Qh|Qh]

    f4 acc = (f4){0.f, 0.f, 0.f, 0.f};
    float m = -1e30f, lsum = 0.f;
    int rel0 = lk * 4 - qg;      // rel of s[0] at global kt=0; += 16 per tile

    for (int half = 0; half < 2; ++half) {
        __syncthreads();          // previous half fully consumed
        // stage K half (256 keys; hi+lo packed per row)
        for (int u = t; u < 1024; u += 512) {
            int key = u >> 2, seg = u & 3;
            const short* src = (seg < 2 ? qh : ql) + base + 256
                             + (size_t)(half * 256 + key) * 768 + (seg & 1) * 8;
            *(bf8*)&khl[key][seg * 8] = *(const bf8*)src;
        }
        // stage V half transposed (hi only), pair-packed b32 writes
        if (t < 256) {
            int u = t & 127;             // key pair
            int dhalf = (t >> 7) & 1;    // d 0..7 / 8..15
            int gkey = half * 256 + u * 2;
            const short* vs = qh + base + 512 + (size_t)gkey * 768 + dhalf * 8;
            bf8 A = *(const bf8*)vs;
            bf8 B = *(const bf8*)(vs + 768);
            unsigned* vw = (unsigned*)&vth[0][0];  // row stride 132 words
#pragma unroll
            for (int i = 0; i < 8; ++i)
                vw[(dhalf * 8 + i) * 132 + u] =
                    (unsigned)(unsigned short)A[i] | ((unsigned)(unsigned short)B[i] << 16);
        }
        __syncthreads();

        for (int kt = 0; kt < 16; ++kt, rel0 += 16) {
            bf8 A1 = *(const bf8*)&khl[kt * 16 + lq][lk * 8];  // [Kh|Kl]
            f4 s = (f4){0.f, 0.f, 0.f, 0.f};
            __builtin_amdgcn_s_setprio(1);
            s = MFMA(A1, B1, s);      // KhQh + KlQh  (K compensated, Q bf16)
            __builtin_amdgcn_s_setprio(0);
            if (rel0 >= PMAXLc) {
                s[0] += bR; s[1] += bR; s[2] += bR; s[3] += bR;
            } else if (rel0 + 3 <= -PMAXLc) {
                s[0] += bL; s[1] += bL; s[2] += bL; s[3] += bL;
            } else {
#pragma unroll
                for (int r = 0; r < 4; ++r) {
                    int rel = rel0 + r;
                    rel = rel < -PMAXLc ? -PMAXLc : (rel > PMAXLc ? PMAXLc : rel);
                    s[r] += biasr[rel + PMAXLc];
                }
            }
            float mt = fmaxf(fmaxf(s[0], s[1]), fmaxf(s[2], s[3]));
            mt = fmaxf(mt, __shfl_xor(mt, 16));
            mt = fmaxf(mt, __shfl_xor(mt, 32));
            if (__any(mt > m + 8.0f)) {
                float mn = fmaxf(m, mt);
                float alpha = __expf(m - mn);
                m = mn;
                lsum *= alpha;
#pragma unroll
                for (int r = 0; r < 4; ++r) acc[r] *= __shfl(alpha, lk * 4 + r);
            }
            f4 p;
#pragma unroll
            for (int r = 0; r < 4; ++r) p[r] = __expf(s[r] - m);
            lsum += p[0] + p[1] + p[2] + p[3];
            // P routed via per-wave LDS (wave-synchronous, no barrier)
            *(f4*)&pw[w][lq][lk * 4] = p;
            const float* pr = &pw[w][lq][(lk & 1) * 8];
            f4 ga = *(const f4*)pr;
            f4 gb = *(const f4*)(pr + 4);
            bf8 PA;                       // [Ph|Pl] along MFMA K-dim
            if (lk < 2) {
#pragma unroll
                for (int jj = 0; jj < 4; ++jj) {
                    PA[jj]     = (short)(__float_as_uint(ga[jj]) >> 16);
                    PA[jj + 4] = (short)(__float_as_uint(gb[jj]) >> 16);
                }
            } else {
#pragma unroll
                for (int jj = 0; jj < 4; ++jj) {
                    unsigned hu0 = __float_as_uint(ga[jj]) & 0xFFFF0000u;
                    unsigned hu1 = __float_as_uint(gb[jj]) & 0xFFFF0000u;
                    PA[jj]     = (short)(__float_as_uint(ga[jj] - __uint_as_float(hu0)) >> 16);
                    PA[jj + 4] = (short)(__float_as_uint(gb[jj] - __uint_as_float(hu1)) >> 16);
                }
            }
            bf8 VB1 = *(const bf8*)&vth[lq][kt * 16 + (lk & 1) * 8];  // [Vh|Vh]
            __builtin_amdgcn_s_setprio(1);
            acc = MFMA(PA, VB1, acc);   // (Ph+Pl)Vh  (P compensated, V bf16)
            __builtin_amdgcn_s_setprio(0);
        }
    }

    float lred = lsum + __shfl_xor(lsum, 16);
    lred += __shfl_xor(lred, 32);
    float inv = 1.0f / lred;
#pragma unroll
    for (int r = 0; r < 4; ++r) {
        float iq = __shfl(inv, lk * 4 + r);
        float y = acc[r] * iq;
        int qo = qt * 128 + w * 16 + lk * 4 + r;
        size_t oi = ((size_t)n * Lc + qo) * DMc + head * 16 + lq;
        ohi[oi] = f2bf(y);   // RNE; o_lo never read (oproj TERMS=2)
    }
}

// ---------------------------------------------------------------------------
// LN over h + s2a + s2b + sbias, fully f4-vectorized. um stride = UMLD.
__global__ __launch_bounds__(256) void k_ln(const float* __restrict__ s2a,
                                            const float* __restrict__ s2b,
                                            const float* __restrict__ sbias,
                                            const float* __restrict__ g,
                                            const float* __restrict__ bta,
                                            float* __restrict__ h,
                                            short* __restrict__ umhi,
                                            short* __restrict__ umlo) {
    int t = threadIdx.x;
    int tl = t >> 5, j = t & 31;
    size_t gtok = (size_t)blockIdx.x * 8 + tl;
    int d0 = j * 8;
    size_t off = gtok * EMBEDc + d0;
    f4 h0 = *(const f4*)(h + off);
    f4 h1 = *(const f4*)(h + off + 4);
    f4 a0 = *(const f4*)(s2a + off);
    f4 a1 = *(const f4*)(s2a + off + 4);
    f4 b0 = *(const f4*)(s2b + off);
    f4 b1 = *(const f4*)(s2b + off + 4);
    f4 sb0 = *(const f4*)(sbias + d0);
    f4 sb1 = *(const f4*)(sbias + d0 + 4);
    f4 v0 = h0 + a0 + b0 + sb0;
    f4 v1 = h1 + a1 + b1 + sb1;
    float sum = v0[0] + v0[1] + v0[2] + v0[3] + v1[0] + v1[1] + v1[2] + v1[3];
    float ssq = v0[0]*v0[0] + v0[1]*v0[1] + v0[2]*v0[2] + v0[3]*v0[3]
              + v1[0]*v1[0] + v1[1]*v1[1] + v1[2]*v1[2] + v1[3]*v1[3];
#pragma unroll
    for (int off5 = 16; off5; off5 >>= 1) {
        sum += __shfl_xor(sum, off5, 32);
        ssq += __shfl_xor(ssq, off5, 32);
    }
    float mean = sum * (1.f / EMBEDc);
    float var = ssq * (1.f / EMBEDc) - mean * mean;
    float inv = rsqrtf(var + 1e-5f);
    f4 g0 = *(const f4*)(g + d0);
    f4 g1 = *(const f4*)(g + d0 + 4);
    f4 t0 = *(const f4*)(bta + d0);
    f4 t1 = *(const f4*)(bta + d0 + 4);
    f4 y0, y1;
    bf8 hv, lv;
#pragma unroll
    for (int q = 0; q < 4; ++q) {
        float y = (v0[q] - mean) * inv * g0[q] + t0[q];
        y0[q] = y;
        short hh = f2bf(y);
        hv[q] = hh;
        lv[q] = f2bf(y - bf2f(hh));
    }
#pragma unroll
    for (int q = 0; q < 4; ++q) {
        float y = (v1[q] - mean) * inv * g1[q] + t1[q];
        y1[q] = y;
        short hh = f2bf(y);
        hv[q + 4] = hh;
        lv[q + 4] = f2bf(y - bf2f(hh));
    }
    *(f4*)(h + off) = y0;
    *(f4*)(h + off + 4) = y1;
    *(bf8*)(umhi + gtok * UMLD + d0) = hv;
    *(bf8*)(umlo + gtok * UMLD + d0) = lv;
}

// ---------------------------------------------------------------------------
__global__ __launch_bounds__(256) void k_r(const short* __restrict__ fh,
                                           const short* __restrict__ fl,
                                           const float* __restrict__ w2,
                                           const float* __restrict__ b2,
                                           float* __restrict__ r) {
    __shared__ float w[3][EMBEDc];
    int t = threadIdx.x;
    for (int u = t; u < 3 * EMBEDc; u += 256) w[u >> 8][u & 255] = w2[u];
    __syncthreads();
    int tok = blockIdx.x * 64 + (t >> 2), o = t & 3;
    if (o < 3) {
        const short* ph = fh + (size_t)tok * EMBEDc;
        const short* pl = fl + (size_t)tok * EMBEDc;
        float s = b2[o];
        for (int c8 = 0; c8 < EMBEDc / 8; ++c8) {
            bf8 vh = *(const bf8*)(ph + c8 * 8);
            bf8 vl = *(const bf8*)(pl + c8 * 8);
#pragma unroll
            for (int j = 0; j < 8; ++j)
                s += (bf2f(vh[j]) + bf2f(vl[j])) * w[o][c8 * 8 + j];
        }
        r[(size_t)tok * 3 + o] = s;
    }
}

// ---------------------------------------------------------------------------
__global__ __launch_bounds__(256) void k_dmap(const float* __restrict__ r,
                                              float* __restrict__ d) {
    int b = blockIdx.x;
    int n = b / Lc;
    float xi = r[(size_t)b * 3], yi = r[(size_t)b * 3 + 1], zi = r[(size_t)b * 3 + 2];
    const float* rn = r + (size_t)n * Lc * 3;
    for (int j = threadIdx.x; j < Lc; j += 256) {
        float dx = xi - rn[j * 3];
        float dy = yi - rn[j * 3 + 1];
        float dz = zi - rn[j * 3 + 2];
        d[(size_t)b * Lc + j] = sqrtf(dx * dx + dy * dy + dz * dz + 1e-12f);
    }
}

// ---------------------------------------------------------------------------
extern "C" void kernel_launch(void* const* d_in, const int* in_sizes, int n_in,
                              void* d_out, int out_size, void* d_ws, size_t ws_size,
                              hipStream_t stream) {
    const float* z       = (const float*)d_in[0];
    const float* x       = (const float*)d_in[1];
    const float* pos_emb = (const float*)d_in[2];
    const float* aa_emb  = (const float*)d_in[3];
    const float* ex_w1   = (const float*)d_in[4];
    const float* ex_b1   = (const float*)d_in[5];
    const float* ex_w2   = (const float*)d_in[6];
    const float* ex_b2   = (const float*)d_in[7];
    const float* Wq      = (const float*)d_in[8];
    const float* Wk      = (const float*)d_in[9];
    const float* Wv      = (const float*)d_in[10];
    const float* Wo      = (const float*)d_in[11];
    const float* bo      = (const float*)d_in[12];
    const float* W2d     = (const float*)d_in[13];
    const float* b2d     = (const float*)d_in[14];
    const float* Wf1     = (const float*)d_in[15];
    const float* bf1     = (const float*)d_in[16];
    const float* Wf2     = (const float*)d_in[17];
    const float* bf2     = (const float*)d_in[18];
    const float* ln1_g   = (const float*)d_in[19];
    const float* ln1_b   = (const float*)d_in[20];
    const float* ln2_g   = (const float*)d_in[21];
    const float* ln2_b   = (const float*)d_in[22];
    const float* o_w1    = (const float*)d_in[23];
    const float* o_b1    = (const float*)d_in[24];
    const float* o_w2    = (const float*)d_in[25];
    const float* o_b2    = (const float*)d_in[26];

    float* h    = (float*)d_ws;                    // 4096*256
    float* s2a  = h + (size_t)NTOK * EMBEDc;
    float* s2b  = s2a + (size_t)NTOK * EMBEDc;
    float* bbuf = s2b + (size_t)NTOK * EMBEDc;     // pad 8192
    float* r    = bbuf + 8192;                     // pad 16384
    short* qkvh = (short*)(r + 16384);             // 4096*768
    short* qkvl = qkvh + (size_t)NTOK * 768;
    short* um_hi = qkvl + (size_t)NTOK * 768;      // 4096*320 (padded)
    short* um_lo = um_hi + (size_t)NTOK * UMLD;
    short* o_hi  = um_lo + (size_t)NTOK * UMLD;    // 4096*256
    short* o_lo  = o_hi + (size_t)NTOK * EMBEDc;
    short* f1_hi = o_lo + (size_t)NTOK * EMBEDc;   // 4096*1024
    short* f1_lo = f1_hi + (size_t)NTOK * DFFc;
    short* wqkv_hi = f1_lo + (size_t)NTOK * DFFc;  // 6*768*256
    short* wqkv_lo = wqkv_hi + (size_t)NLc * 768 * EMBEDc;
    short* wo_hi   = wqkv_lo + (size_t)NLc * 768 * EMBEDc;   // 6*256*256
    short* wo_lo   = wo_hi + (size_t)NLc * EMBEDc * DMc;
    short* wf1_hi  = wo_lo + (size_t)NLc * EMBEDc * DMc;     // 6*1024*320 (padded)
    short* wf1_lo  = wf1_hi + (size_t)NLc * DFFc * UMLD;
    short* wf2_hi  = wf1_lo + (size_t)NLc * DFFc * UMLD;     // 6*256*1024
    short* wf2_lo  = wf2_hi + (size_t)NLc * EMBEDc * DFFc;
    short* wex1_hi = wf2_lo + (size_t)NLc * EMBEDc * DFFc;   // 256*64
    short* wex1_lo = wex1_hi + EMBEDc * NZc;
    short* wex2_hi = wex1_lo + EMBEDc * NZc;                 // 256*256
    short* wex2_lo = wex2_hi + EMBEDc * EMBEDc;
    short* wo1_hi  = wex2_lo + EMBEDc * EMBEDc;              // 256*256
    short* wo1_lo  = wo1_hi + EMBEDc * EMBEDc;
    // zt aliases the o buffer (only used in preamble, before k_attn writes o)
    short* zt_hi = o_hi;
    short* zt_lo = o_lo;

    k_pre<<<1024, 256, 0, stream>>>(Wq, Wk, Wv, Wo, Wf1, Wf2, ex_w1, ex_w2, o_w1,
                                    pos_emb, W2d, b2d, x, aa_emb, z,
                                    wqkv_hi, wqkv_lo, wo_hi, wo_lo,
                                    wf1_hi, wf1_lo, wf2_hi, wf2_lo,
                                    wex1_hi, wex1_lo, wex2_hi, wex2_lo,
                                    wo1_hi, wo1_lo, bbuf, um_hi, um_lo,
                                    zt_hi, zt_lo);

    // embed: relu GEMM -> GEMM (fp32 h + bf16 um, ldh = UMLD)
    k_gemm3<1, 1, 0, 64, 3><<<256, 256, 0, stream>>>(
        zt_hi, zt_lo, NZc, wex1_hi, wex1_lo, NZc, NZc,
        nullptr, 0, f1_hi, f1_lo, EMBEDc, ex_b1, 4, 8);
    k_gemm3<3, 1, 0, 64, 3><<<256, 256, 0, stream>>>(
        f1_hi, f1_lo, EMBEDc, wex2_hi, wex2_lo, EMBEDc, EMBEDc,
        h, EMBEDc, um_hi, um_lo, UMLD, ex_b2, 4, 8);

    for (int l = 0; l < NLc; ++l) {
        // qkv: TERMS=2 (A bf16; softmax damps the error)
        k_gemm3<2, 1, 0, 64, 2><<<768, 256, 0, stream>>>(
            um_hi, um_lo, UMLD,
            wqkv_hi + (size_t)l * 768 * EMBEDc, wqkv_lo + (size_t)l * 768 * EMBEDc, EMBEDc,
            EMBEDc, nullptr, 0, qkvh, qkvl, 768, nullptr, 12, 8);
        k_attn<<<NB * NHc * 4, 512, 0, stream>>>(qkvh, qkvl, bbuf + (size_t)l * NHc * NBINSc, o_hi, o_lo);
        // oproj: TERMS=2 (o RNE bf16; LN damps the error)
        k_gemm3<0, 1, 8, 64, 2><<<512, 256, 0, stream>>>(
            o_hi, o_lo, EMBEDc,
            wo_hi + (size_t)l * EMBEDc * DMc, wo_lo + (size_t)l * EMBEDc * DMc, DMc,
            128, s2a, EMBEDc, nullptr, nullptr, 0, nullptr, 4, 8);
        k_ln<<<NTOK / 8, 256, 0, stream>>>(s2a, s2b, bo + (size_t)l * EMBEDc,
                                           ln1_g + (size_t)l * EMBEDc, ln1_b + (size_t)l * EMBEDc,
                                           h, um_hi, um_lo);
        // ffn1: TERMS=2 (um bf16; ReLU->ffn2->LN damps) + EPI=4 (f1_lo dead)
        k_gemm3<4, 2, 0, 64, 2><<<512, 256, 0, stream>>>(
            um_hi, um_lo, UMLD,
            wf1_hi + (size_t)l * DFFc * UMLD, wf1_lo + (size_t)l * DFFc * UMLD, UMLD,
            UMLD, nullptr, 0, f1_hi, f1_lo, DFFc, bf1 + (size_t)l * DFFc, 16, 4);
        // ffn2: TERMS=2 (f1 RNE bf16; LN damps the error)
        k_gemm3<0, 1, 8, 64, 2><<<512, 256, 0, stream>>>(
            f1_hi, f1_lo, DFFc,
            wf2_hi + (size_t)l * EMBEDc * DFFc, wf2_lo + (size_t)l * EMBEDc * DFFc, DFFc,
            512, s2a, EMBEDc, nullptr, nullptr, 0, nullptr, 4, 8);
        k_ln<<<NTOK / 8, 256, 0, stream>>>(s2a, s2b, bf2 + (size_t)l * EMBEDc,
                                           ln2_g + (size_t)l * EMBEDc, ln2_b + (size_t)l * EMBEDc,
                                           h, um_hi, um_lo);
    }

    // final: f = relu(um @ o_w1^T + o_b1) (um cols 0..255 hold h in bf16)
    k_gemm3<1, 1, 0, 64, 3><<<256, 256, 0, stream>>>(
        um_hi, um_lo, UMLD, wo1_hi, wo1_lo, EMBEDc, EMBEDc,
        nullptr, 0, f1_hi, f1_lo, EMBEDc, o_b1, 4, 8);
    k_r<<<NTOK / 64, 256, 0, stream>>>(f1_hi, f1_lo, o_w2, o_b2, r);
    k_dmap<<<NB * Lc, 256, 0, stream>>>(r, (float*)d_out);
}

// Round 21
// 466.644 us; speedup vs baseline: 1.2915x; 1.0118x over previous
//
#include <hip/hip_runtime.h>
#include <math.h>

#define NZc     64
#define EMBEDc  256
#define DMc     256
#define NHc     16
#define HDc     16
#define DFFc    1024
#define NLc     6
#define E1Dc    32
#define PDIMc   64
#define PMAXLc  24
#define NBINSc  49
#define NB      8
#define Lc      512
#define NTOK    (NB * Lc)        // 4096
#define UMDIM   288              // logical um width
#define UMLD    320              // padded leading dim (zeros in 288..319)

typedef __attribute__((ext_vector_type(4))) float f4;
typedef __attribute__((ext_vector_type(8))) short bf8;   // 8 bf16 in 4 VGPRs

#define MFMA(a, b, c) __builtin_amdgcn_mfma_f32_16x16x32_bf16((a), (b), (c), 0, 0, 0)

__device__ __forceinline__ short f2bf(float f) {
    unsigned u = __float_as_uint(f);
    u += 0x7FFFu + ((u >> 16) & 1u);   // round-to-nearest-even
    return (short)(u >> 16);
}
__device__ __forceinline__ float bf2f(short s) {
    return __uint_as_float(((unsigned)(unsigned short)s) << 16);
}

// ---------------------------------------------------------------------------
// preamble: weight conversions (x8 vectorized) + bias bins + e_aa + z^T.
// Wf1 rows remapped 288 -> 320 stride; pad cols zero-filled (um_hi + wf1).
// Dead lo-channels dropped: e_aa um_lo, um_lo pad (no consumers remain).
__global__ void k_pre(const float* __restrict__ Wq, const float* __restrict__ Wk,
                      const float* __restrict__ Wv, const float* __restrict__ Wo,
                      const float* __restrict__ Wf1, const float* __restrict__ Wf2,
                      const float* __restrict__ exw1, const float* __restrict__ exw2,
                      const float* __restrict__ ow1,
                      const float* __restrict__ pos_emb, const float* __restrict__ W2d,
                      const float* __restrict__ b2d, const float* __restrict__ x,
                      const float* __restrict__ aa_emb, const float* __restrict__ z,
                      short* __restrict__ wqkv_hi, short* __restrict__ wqkv_lo,
                      short* __restrict__ wo_hi, short* __restrict__ wo_lo,
                      short* __restrict__ wf1_hi, short* __restrict__ wf1_lo,
                      short* __restrict__ wf2_hi, short* __restrict__ wf2_lo,
                      short* __restrict__ wex1_hi, short* __restrict__ wex1_lo,
                      short* __restrict__ wex2_hi, short* __restrict__ wex2_lo,
                      short* __restrict__ wo1_hi, short* __restrict__ wo1_lo,
                      float* __restrict__ bb,
                      short* __restrict__ umhi, short* __restrict__ umlo,
                      short* __restrict__ zth, short* __restrict__ ztl) {
    int stride = gridDim.x * blockDim.x;
    int tid = blockIdx.x * blockDim.x + threadIdx.x;
#define CVT(src, hi, lo, per_layer, dstride, doff, scale, total)               \
    for (int i = tid; i < (total) / 8; i += stride) {                          \
        int ib = i * 8;                                                        \
        int ll = ib / (per_layer), rels = ib - ll * (per_layer);               \
        size_t di = (size_t)ll * (dstride) + (doff) + rels;                    \
        f4 v0 = *(const f4*)(src + ib);                                        \
        f4 v1 = *(const f4*)(src + ib + 4);                                    \
        bf8 hv, lv;                                                            \
        _Pragma("unroll")                                                      \
        for (int q = 0; q < 4; ++q) {                                          \
            float v = v0[q] * (scale);                                         \
            short hh = f2bf(v);                                                \
            hv[q] = hh;                                                        \
            lv[q] = f2bf(v - bf2f(hh));                                        \
        }                                                                      \
        _Pragma("unroll")                                                      \
        for (int q = 0; q < 4; ++q) {                                          \
            float v = v1[q] * (scale);                                         \
            short hh = f2bf(v);                                                \
            hv[q + 4] = hh;                                                    \
            lv[q + 4] = f2bf(v - bf2f(hh));                                    \
        }                                                                      \
        *(bf8*)(hi + di) = hv;                                                 \
        *(bf8*)(lo + di) = lv;                                                 \
    }
    CVT(Wq,  wqkv_hi, wqkv_lo, 65536, 196608, 0,      0.0625f, 393216);
    CVT(Wk,  wqkv_hi, wqkv_lo, 65536, 196608, 65536,  1.f,     393216);
    CVT(Wv,  wqkv_hi, wqkv_lo, 65536, 196608, 131072, 1.f,     393216);
    CVT(Wo,  wo_hi,  wo_lo,  65536,  65536,  0, 1.f, 393216);
    CVT(Wf2, wf2_hi, wf2_lo, 262144, 262144, 0, 1.f, 1572864);
    CVT(exw1, wex1_hi, wex1_lo, 16384, 16384, 0, 1.f, 16384);
    CVT(exw2, wex2_hi, wex2_lo, 65536, 65536, 0, 1.f, 65536);
    CVT(ow1,  wo1_hi,  wo1_lo,  65536, 65536, 0, 1.f, 65536);
#undef CVT
    // Wf1: src rows of 288 -> dest rows of 320 (row boundary 8-aligned)
    for (int i = tid; i < 1769472 / 8; i += stride) {
        int ib = i * 8;
        int ll = ib / 294912, rels = ib - ll * 294912;
        int row = rels / 288, col = rels - row * 288;
        size_t di = (size_t)ll * (1024 * UMLD) + (size_t)row * UMLD + col;
        f4 v0 = *(const f4*)(Wf1 + ib);
        f4 v1 = *(const f4*)(Wf1 + ib + 4);
        bf8 hv, lv;
#pragma unroll
        for (int q = 0; q < 4; ++q) {
            float v = v0[q];
            short hh = f2bf(v);
            hv[q] = hh;
            lv[q] = f2bf(v - bf2f(hh));
        }
#pragma unroll
        for (int q = 0; q < 4; ++q) {
            float v = v1[q];
            short hh = f2bf(v);
            hv[q + 4] = hh;
            lv[q + 4] = f2bf(v - bf2f(hh));
        }
        *(bf8*)(wf1_hi + di) = hv;
        *(bf8*)(wf1_lo + di) = lv;
    }
    // zero pad cols 288..319: wf1 hi/lo (B staged hi+lo) and um_hi (A hi)
    {
        bf8 zz;
#pragma unroll
        for (int q = 0; q < 8; ++q) zz[q] = 0;
        for (int i = tid; i < 6144 * 4; i += stride) {
            int row = i >> 2, seg = i & 3;
            size_t di = (size_t)row * UMLD + UMDIM + seg * 8;
            *(bf8*)(wf1_hi + di) = zz;
            *(bf8*)(wf1_lo + di) = zz;
        }
        for (int i = tid; i < 4096 * 4; i += stride) {
            int row = i >> 2, seg = i & 3;
            size_t di = (size_t)row * UMLD + UMDIM + seg * 8;
            *(bf8*)(umhi + di) = zz;
        }
    }
    for (int idx = tid; idx < NLc * NHc * NBINSc; idx += stride) {
        int bin = idx % NBINSc;
        int tmp = idx / NBINSc;
        int hh = tmp % NHc, l = tmp / NHc;
        float s = b2d[l * NHc + hh];
        const float* pe = pos_emb + bin * PDIMc;
        const float* w  = W2d + (l * NHc + hh) * PDIMc;
        for (int p = 0; p < PDIMc; ++p) s += pe[p] * w[p];
        bb[idx] = s;
    }
    // e_aa -> um_hi cols 256..287 (lo dead: ffn1 is TERMS=2)
    for (int tok = tid; tok < NTOK; tok += stride) {
        int n = tok / Lc, l = tok % Lc;
        const float* xp = x + (size_t)n * 20 * Lc + l;
        float best = xp[0];
        int bi = 0;
        for (int c = 1; c < 20; ++c) {
            float v = xp[c * Lc];
            if (v > best) { best = v; bi = c; }
        }
        const float* e = aa_emb + bi * E1Dc;
        bf8 hv;
        for (int c8 = 0; c8 < E1Dc / 8; ++c8) {
#pragma unroll
            for (int q = 0; q < 8; ++q) hv[q] = f2bf(e[c8 * 8 + q]);
            *(bf8*)(umhi + (size_t)tok * UMLD + EMBEDc + c8 * 8) = hv;
        }
    }
    for (int tok = tid; tok < NTOK; tok += stride) {
        int n = tok >> 9, l = tok & 511;
        bf8 hv, lv;
        for (int c8 = 0; c8 < NZc / 8; ++c8) {
#pragma unroll
            for (int q = 0; q < 8; ++q) {
                float v = z[((size_t)n * NZc + c8 * 8 + q) * Lc + l];
                short hh = f2bf(v);
                hv[q] = hh;
                lv[q] = f2bf(v - bf2f(hh));
            }
            *(bf8*)(zth + (size_t)tok * NZc + c8 * 8) = hv;
            *(bf8*)(ztl + (size_t)tok * NZc + c8 * 8) = lv;
        }
    }
}

// ---------------------------------------------------------------------------
// LDS-staged MFMA GEMM. TERMS=3: full compensated. TERMS=2: drop AlBh.
// EPI 0: fp32 out. 1: relu->hi/lo. 2: ->hi/lo. 3: fp32+hi/lo.
// 4: relu->hi only. 5: ->hi; lo only for cols [256,512) (qkv: K rows only).
template <int EPI, int MF, int SKSHIFT, int BK, int TERMS>
__global__ __launch_bounds__(256) void k_gemm3(
    const short* __restrict__ Ahi, const short* __restrict__ Alo, int lda,
    const short* __restrict__ Bhi, const short* __restrict__ Blo, int ldb,
    int K, float* __restrict__ outf, int ldo, short* __restrict__ ohi,
    short* __restrict__ olo, int ldh, const float* __restrict__ bias,
    int gx, int gypx) {
    constexpr int PAD = BK + 8;
    __shared__ __align__(16) short Ah[MF * 64][PAD];
    __shared__ __align__(16) short Al[TERMS == 3 ? MF * 64 : 1][TERMS == 3 ? PAD : 1];
    __shared__ __align__(16) short Bh[64][PAD];
    __shared__ __align__(16) short Bl[64][PAD];

    int bid = blockIdx.x;
    int koff = 0;
    if (SKSHIFT) {
        int kh = bid >> SKSHIFT;
        bid &= (1 << SKSHIFT) - 1;
        koff = kh * K;
        outf += (size_t)kh * NTOK * EMBEDc;
    }
    int xcd = bid & 7, j = bid >> 3;
    int bx = j % gx, by = xcd * gypx + j / gx;

    int t = threadIdx.x;
    int w = t >> 6, l = t & 63, lr = l & 15, lk = l >> 4;
    int m0 = by * (MF * 64);
    int n0 = bx * 64;

    constexpr int TPR = BK / 8;
    constexpr int RP  = 256 / TPR;
    constexpr int AP  = MF * 64 / RP;
    constexpr int BP  = 64 / RP;
    int srow = t / TPR, scol = (t % TPR) * 8;

    const short* pa  = Ahi + (size_t)(m0 + srow) * lda + koff + scol;
    const short* pal = Alo + (size_t)(m0 + srow) * lda + koff + scol;
    const short* pb  = Bhi + (size_t)(n0 + srow) * ldb + koff + scol;
    const short* pbl = Blo + (size_t)(n0 + srow) * ldb + koff + scol;

    bf8 ra[AP], rla[AP], rb[BP], rlb[BP];
#pragma unroll
    for (int p = 0; p < AP; ++p) {
        ra[p] = *(const bf8*)(pa + (size_t)p * RP * lda);
        if (TERMS == 3) rla[p] = *(const bf8*)(pal + (size_t)p * RP * lda);
    }
#pragma unroll
    for (int p = 0; p < BP; ++p) {
        rb[p]  = *(const bf8*)(pb  + (size_t)p * RP * ldb);
        rlb[p] = *(const bf8*)(pbl + (size_t)p * RP * ldb);
    }

    f4 acc[MF][4];
#pragma unroll
    for (int mf = 0; mf < MF; ++mf)
#pragma unroll
        for (int nf = 0; nf < 4; ++nf) acc[mf][nf] = (f4){0.f, 0.f, 0.f, 0.f};

    for (int ks = 0; ks < K; ks += BK) {
        __syncthreads();
#pragma unroll
        for (int p = 0; p < AP; ++p) {
            *(bf8*)&Ah[p * RP + srow][scol] = ra[p];
            if (TERMS == 3) *(bf8*)&Al[p * RP + srow][scol] = rla[p];
        }
#pragma unroll
        for (int p = 0; p < BP; ++p) {
            *(bf8*)&Bh[p * RP + srow][scol] = rb[p];
            *(bf8*)&Bl[p * RP + srow][scol] = rlb[p];
        }
        __syncthreads();
        if (ks + BK < K) {
#pragma unroll
            for (int p = 0; p < AP; ++p) {
                ra[p] = *(const bf8*)(pa + (size_t)p * RP * lda + ks + BK);
                if (TERMS == 3) rla[p] = *(const bf8*)(pal + (size_t)p * RP * lda + ks + BK);
            }
#pragma unroll
            for (int p = 0; p < BP; ++p) {
                rb[p]  = *(const bf8*)(pb  + (size_t)p * RP * ldb + ks + BK);
                rlb[p] = *(const bf8*)(pbl + (size_t)p * RP * ldb + ks + BK);
            }
        }
#pragma unroll
        for (int kc = 0; kc < BK / 32; ++kc) {
            bf8 bhf[4], blf[4];
#pragma unroll
            for (int nf = 0; nf < 4; ++nf) {
                bhf[nf] = *(const bf8*)&Bh[nf * 16 + lr][kc * 32 + lk * 8];
                blf[nf] = *(const bf8*)&Bl[nf * 16 + lr][kc * 32 + lk * 8];
            }
#pragma unroll
            for (int mf = 0; mf < MF; ++mf) {
                bf8 ah = *(const bf8*)&Ah[w * MF * 16 + mf * 16 + lr][kc * 32 + lk * 8];
                bf8 al;
                if (TERMS == 3) al = *(const bf8*)&Al[w * MF * 16 + mf * 16 + lr][kc * 32 + lk * 8];
#pragma unroll
                for (int nf = 0; nf < 4; ++nf) {
                    acc[mf][nf] = MFMA(ah, bhf[nf], acc[mf][nf]);
                    acc[mf][nf] = MFMA(ah, blf[nf], acc[mf][nf]);
                    if (TERMS == 3) acc[mf][nf] = MFMA(al, bhf[nf], acc[mf][nf]);
                }
            }
        }
    }

    bool wlo5 = (n0 >= 256 && n0 < 512);   // block-uniform: qkv K-slice only
#pragma unroll
    for (int mf = 0; mf < MF; ++mf) {
#pragma unroll
        for (int nf = 0; nf < 4; ++nf) {
            int n = n0 + nf * 16 + lr;
            int mbase = m0 + w * MF * 16 + mf * 16 + lk * 4;
            if (EPI == 0) {
#pragma unroll
                for (int r = 0; r < 4; ++r)
                    outf[(size_t)(mbase + r) * ldo + n] = acc[mf][nf][r];
            } else if (EPI == 1) {
                float bv = bias[n];
#pragma unroll
                for (int r = 0; r < 4; ++r) {
                    float y = fmaxf(acc[mf][nf][r] + bv, 0.f);
                    short hv = f2bf(y);
                    size_t oi = (size_t)(mbase + r) * ldh + n;
                    ohi[oi] = hv;
                    olo[oi] = f2bf(y - bf2f(hv));
                }
            } else if (EPI == 2) {
#pragma unroll
                for (int r = 0; r < 4; ++r) {
                    float y = acc[mf][nf][r];
                    short hv = f2bf(y);
                    size_t oi = (size_t)(mbase + r) * ldh + n;
                    ohi[oi] = hv;
                    olo[oi] = f2bf(y - bf2f(hv));
                }
            } else if (EPI == 3) {
                float bv = bias[n];
#pragma unroll
                for (int r = 0; r < 4; ++r) {
                    float y = acc[mf][nf][r] + bv;
                    outf[(size_t)(mbase + r) * ldo + n] = y;
                    short hv = f2bf(y);
                    size_t oi = (size_t)(mbase + r) * ldh + n;
                    ohi[oi] = hv;
                    olo[oi] = f2bf(y - bf2f(hv));
                }
            } else if (EPI == 4) {   // relu(acc+bias) -> hi only
                float bv = bias[n];
#pragma unroll
                for (int r = 0; r < 4; ++r) {
                    float y = fmaxf(acc[mf][nf][r] + bv, 0.f);
                    ohi[(size_t)(mbase + r) * ldh + n] = f2bf(y);
                }
            } else {   // EPI == 5: hi always; lo only for K rows (qkv)
#pragma unroll
                for (int r = 0; r < 4; ++r) {
                    float y = acc[mf][nf][r];
                    short hv = f2bf(y);
                    size_t oi = (size_t)(mbase + r) * ldh + n;
                    ohi[oi] = hv;
                    if (wlo5) olo[oi] = f2bf(y - bf2f(hv));
                }
            }
        }
    }
}

// ---------------------------------------------------------------------------
// MFMA flash attention: Q and V consumed at bf16 (softmax-/oproj-damped),
// K and P stay compensated (free in the K=32 MFMA dim). 2 MFMAs/tile.
__global__ __launch_bounds__(512, 8) void k_attn(const short* __restrict__ qh,
                                                 const short* __restrict__ ql,
                                                 const float* __restrict__ bb,
                                                 short* __restrict__ ohi,
                                                 short* __restrict__ olo) {
    int bx = blockIdx.x;
    int qt = bx >> 7;            // 0..3; blocks sharing (n,head) same XCD
    int head = bx & 15;
    int n = (bx >> 4) & 7;
    int t = threadIdx.x;
    int w = t >> 6, l = t & 63;
    int lq = l & 15, lk = l >> 4;

    __shared__ __align__(16) short khl[256][40];   // [key][hi0-15|lo16-31|pad]
    __shared__ __align__(16) short vth[16][264];   // V^T hi: [d][key 0..255]
    __shared__ __align__(16) float pw[8][16][20];  // per-wave P[q][key] buffer
    __shared__ float biasr[64];

    if (t < NBINSc) biasr[t] = bb[head * NBINSc + t];
    float bL = bb[head * NBINSc];
    float bR = bb[head * NBINSc + 48];

    size_t base = (size_t)n * Lc * 768 + head * 16;

    int qg = qt * 128 + w * 16 + lq;             // this lane's q column
    size_t qrow = ((size_t)n * Lc + qg) * 768 + head * 16;
    bf8 B1 = *(const bf8*)(qh + qrow + (lk & 1) * 8);   // [Qh|Qh]

    f4 acc = (f4){0.f, 0.f, 0.f, 0.f};
    float m = -1e30f, lsum = 0.f;
    int rel0 = lk * 4 - qg;      // rel of s[0] at global kt=0; += 16 per tile

    for (int half = 0; half < 2; ++half) {
        __syncthreads();          // previous half fully consumed
        // stage K half (256 keys; hi+lo packed per row)
        for (int u = t; u < 1024; u += 512) {
            int key = u >> 2, seg = u & 3;
            const short* src = (seg < 2 ? qh : ql) + base + 256
                             + (size_t)(half * 256 + key) * 768 + (seg & 1) * 8;
            *(bf8*)&khl[key][seg * 8] = *(const bf8*)src;
        }
        // stage V half transposed (hi only), pair-packed b32 writes
        if (t < 256) {
            int u = t & 127;             // key pair
            int dhalf = (t >> 7) & 1;    // d 0..7 / 8..15
            int gkey = half * 256 + u * 2;
            const short* vs = qh + base + 512 + (size_t)gkey * 768 + dhalf * 8;
            bf8 A = *(const bf8*)vs;
            bf8 B = *(const bf8*)(vs + 768);
            unsigned* vw = (unsigned*)&vth[0][0];  // row stride 132 words
#pragma unroll
            for (int i = 0; i < 8; ++i)
                vw[(dhalf * 8 + i) * 132 + u] =
                    (unsigned)(unsigned short)A[i] | ((unsigned)(unsigned short)B[i] << 16);
        }
        __syncthreads();

        for (int kt = 0; kt < 16; ++kt, rel0 += 16) {
            bf8 A1 = *(const bf8*)&khl[kt * 16 + lq][lk * 8];  // [Kh|Kl]
            f4 s = (f4){0.f, 0.f, 0.f, 0.f};
            __builtin_amdgcn_s_setprio(1);
            s = MFMA(A1, B1, s);      // KhQh + KlQh  (K compensated, Q bf16)
            __builtin_amdgcn_s_setprio(0);
            if (rel0 >= PMAXLc) {
                s[0] += bR; s[1] += bR; s[2] += bR; s[3] += bR;
            } else if (rel0 + 3 <= -PMAXLc) {
                s[0] += bL; s[1] += bL; s[2] += bL; s[3] += bL;
            } else {
#pragma unroll
                for (int r = 0; r < 4; ++r) {
                    int rel = rel0 + r;
                    rel = rel < -PMAXLc ? -PMAXLc : (rel > PMAXLc ? PMAXLc : rel);
                    s[r] += biasr[rel + PMAXLc];
                }
            }
            float mt = fmaxf(fmaxf(s[0], s[1]), fmaxf(s[2], s[3]));
            mt = fmaxf(mt, __shfl_xor(mt, 16));
            mt = fmaxf(mt, __shfl_xor(mt, 32));
            if (__any(mt > m + 8.0f)) {
                float mn = fmaxf(m, mt);
                float alpha = __expf(m - mn);
                m = mn;
                lsum *= alpha;
#pragma unroll
                for (int r = 0; r < 4; ++r) acc[r] *= __shfl(alpha, lk * 4 + r);
            }
            f4 p;
#pragma unroll
            for (int r = 0; r < 4; ++r) p[r] = __expf(s[r] - m);
            lsum += p[0] + p[1] + p[2] + p[3];
            // P routed via per-wave LDS (wave-synchronous, no barrier)
            *(f4*)&pw[w][lq][lk * 4] = p;
            const float* pr = &pw[w][lq][(lk & 1) * 8];
            f4 ga = *(const f4*)pr;
            f4 gb = *(const f4*)(pr + 4);
            bf8 PA;                       // [Ph|Pl] along MFMA K-dim
            if (lk < 2) {
#pragma unroll
                for (int jj = 0; jj < 4; ++jj) {
                    PA[jj]     = (short)(__float_as_uint(ga[jj]) >> 16);
                    PA[jj + 4] = (short)(__float_as_uint(gb[jj]) >> 16);
                }
            } else {
#pragma unroll
                for (int jj = 0; jj < 4; ++jj) {
                    unsigned hu0 = __float_as_uint(ga[jj]) & 0xFFFF0000u;
                    unsigned hu1 = __float_as_uint(gb[jj]) & 0xFFFF0000u;
                    PA[jj]     = (short)(__float_as_uint(ga[jj] - __uint_as_float(hu0)) >> 16);
                    PA[jj + 4] = (short)(__float_as_uint(gb[jj] - __uint_as_float(hu1)) >> 16);
                }
            }
            bf8 VB1 = *(const bf8*)&vth[lq][kt * 16 + (lk & 1) * 8];  // [Vh|Vh]
            __builtin_amdgcn_s_setprio(1);
            acc = MFMA(PA, VB1, acc);   // (Ph+Pl)Vh  (P compensated, V bf16)
            __builtin_amdgcn_s_setprio(0);
        }
    }

    float lred = lsum + __shfl_xor(lsum, 16);
    lred += __shfl_xor(lred, 32);
    float inv = 1.0f / lred;
#pragma unroll
    for (int r = 0; r < 4; ++r) {
        float iq = __shfl(inv, lk * 4 + r);
        float y = acc[r] * iq;
        int qo = qt * 128 + w * 16 + lk * 4 + r;
        size_t oi = ((size_t)n * Lc + qo) * DMc + head * 16 + lq;
        ohi[oi] = f2bf(y);   // RNE; o_lo never read (oproj TERMS=2)
    }
}

// ---------------------------------------------------------------------------
// LN over h + s2a + s2b + sbias, fully f4-vectorized. um stride = UMLD.
// WRITE_LO=1 only for the final LN (um_lo consumed only by the final GEMM).
template <int WRITE_LO>
__global__ __launch_bounds__(256) void k_ln(const float* __restrict__ s2a,
                                            const float* __restrict__ s2b,
                                            const float* __restrict__ sbias,
                                            const float* __restrict__ g,
                                            const float* __restrict__ bta,
                                            float* __restrict__ h,
                                            short* __restrict__ umhi,
                                            short* __restrict__ umlo) {
    int t = threadIdx.x;
    int tl = t >> 5, j = t & 31;
    size_t gtok = (size_t)blockIdx.x * 8 + tl;
    int d0 = j * 8;
    size_t off = gtok * EMBEDc + d0;
    f4 h0 = *(const f4*)(h + off);
    f4 h1 = *(const f4*)(h + off + 4);
    f4 a0 = *(const f4*)(s2a + off);
    f4 a1 = *(const f4*)(s2a + off + 4);
    f4 b0 = *(const f4*)(s2b + off);
    f4 b1 = *(const f4*)(s2b + off + 4);
    f4 sb0 = *(const f4*)(sbias + d0);
    f4 sb1 = *(const f4*)(sbias + d0 + 4);
    f4 v0 = h0 + a0 + b0 + sb0;
    f4 v1 = h1 + a1 + b1 + sb1;
    float sum = v0[0] + v0[1] + v0[2] + v0[3] + v1[0] + v1[1] + v1[2] + v1[3];
    float ssq = v0[0]*v0[0] + v0[1]*v0[1] + v0[2]*v0[2] + v0[3]*v0[3]
              + v1[0]*v1[0] + v1[1]*v1[1] + v1[2]*v1[2] + v1[3]*v1[3];
#pragma unroll
    for (int off5 = 16; off5; off5 >>= 1) {
        sum += __shfl_xor(sum, off5, 32);
        ssq += __shfl_xor(ssq, off5, 32);
    }
    float mean = sum * (1.f / EMBEDc);
    float var = ssq * (1.f / EMBEDc) - mean * mean;
    float inv = rsqrtf(var + 1e-5f);
    f4 g0 = *(const f4*)(g + d0);
    f4 g1 = *(const f4*)(g + d0 + 4);
    f4 t0 = *(const f4*)(bta + d0);
    f4 t1 = *(const f4*)(bta + d0 + 4);
    f4 y0, y1;
    bf8 hv, lv;
#pragma unroll
    for (int q = 0; q < 4; ++q) {
        float y = (v0[q] - mean) * inv * g0[q] + t0[q];
        y0[q] = y;
        short hh = f2bf(y);
        hv[q] = hh;
        if (WRITE_LO) lv[q] = f2bf(y - bf2f(hh));
    }
#pragma unroll
    for (int q = 0; q < 4; ++q) {
        float y = (v1[q] - mean) * inv * g1[q] + t1[q];
        y1[q] = y;
        short hh = f2bf(y);
        hv[q + 4] = hh;
        if (WRITE_LO) lv[q + 4] = f2bf(y - bf2f(hh));
    }
    *(f4*)(h + off) = y0;
    *(f4*)(h + off + 4) = y1;
    *(bf8*)(umhi + gtok * UMLD + d0) = hv;
    if (WRITE_LO) *(bf8*)(umlo + gtok * UMLD + d0) = lv;
}

// ---------------------------------------------------------------------------
__global__ __launch_bounds__(256) void k_r(const short* __restrict__ fh,
                                           const short* __restrict__ fl,
                                           const float* __restrict__ w2,
                                           const float* __restrict__ b2,
                                           float* __restrict__ r) {
    __shared__ float w[3][EMBEDc];
    int t = threadIdx.x;
    for (int u = t; u < 3 * EMBEDc; u += 256) w[u >> 8][u & 255] = w2[u];
    __syncthreads();
    int tok = blockIdx.x * 64 + (t >> 2), o = t & 3;
    if (o < 3) {
        const short* ph = fh + (size_t)tok * EMBEDc;
        const short* pl = fl + (size_t)tok * EMBEDc;
        float s = b2[o];
        for (int c8 = 0; c8 < EMBEDc / 8; ++c8) {
            bf8 vh = *(const bf8*)(ph + c8 * 8);
            bf8 vl = *(const bf8*)(pl + c8 * 8);
#pragma unroll
            for (int j = 0; j < 8; ++j)
                s += (bf2f(vh[j]) + bf2f(vl[j])) * w[o][c8 * 8 + j];
        }
        r[(size_t)tok * 3 + o] = s;
    }
}

// ---------------------------------------------------------------------------
__global__ __launch_bounds__(256) void k_dmap(const float* __restrict__ r,
                                              float* __restrict__ d) {
    int b = blockIdx.x;
    int n = b / Lc;
    float xi = r[(size_t)b * 3], yi = r[(size_t)b * 3 + 1], zi = r[(size_t)b * 3 + 2];
    const float* rn = r + (size_t)n * Lc * 3;
    for (int j = threadIdx.x; j < Lc; j += 256) {
        float dx = xi - rn[j * 3];
        float dy = yi - rn[j * 3 + 1];
        float dz = zi - rn[j * 3 + 2];
        d[(size_t)b * Lc + j] = sqrtf(dx * dx + dy * dy + dz * dz + 1e-12f);
    }
}

// ---------------------------------------------------------------------------
extern "C" void kernel_launch(void* const* d_in, const int* in_sizes, int n_in,
                              void* d_out, int out_size, void* d_ws, size_t ws_size,
                              hipStream_t stream) {
    const float* z       = (const float*)d_in[0];
    const float* x       = (const float*)d_in[1];
    const float* pos_emb = (const float*)d_in[2];
    const float* aa_emb  = (const float*)d_in[3];
    const float* ex_w1   = (const float*)d_in[4];
    const float* ex_b1   = (const float*)d_in[5];
    const float* ex_w2   = (const float*)d_in[6];
    const float* ex_b2   = (const float*)d_in[7];
    const float* Wq      = (const float*)d_in[8];
    const float* Wk      = (const float*)d_in[9];
    const float* Wv      = (const float*)d_in[10];
    const float* Wo      = (const float*)d_in[11];
    const float* bo      = (const float*)d_in[12];
    const float* W2d     = (const float*)d_in[13];
    const float* b2d     = (const float*)d_in[14];
    const float* Wf1     = (const float*)d_in[15];
    const float* bf1     = (const float*)d_in[16];
    const float* Wf2     = (const float*)d_in[17];
    const float* bf2     = (const float*)d_in[18];
    const float* ln1_g   = (const float*)d_in[19];
    const float* ln1_b   = (const float*)d_in[20];
    const float* ln2_g   = (const float*)d_in[21];
    const float* ln2_b   = (const float*)d_in[22];
    const float* o_w1    = (const float*)d_in[23];
    const float* o_b1    = (const float*)d_in[24];
    const float* o_w2    = (const float*)d_in[25];
    const float* o_b2    = (const float*)d_in[26];

    float* h    = (float*)d_ws;                    // 4096*256
    float* s2a  = h + (size_t)NTOK * EMBEDc;
    float* s2b  = s2a + (size_t)NTOK * EMBEDc;
    float* bbuf = s2b + (size_t)NTOK * EMBEDc;     // pad 8192
    float* r    = bbuf + 8192;                     // pad 16384
    short* qkvh = (short*)(r + 16384);             // 4096*768
    short* qkvl = qkvh + (size_t)NTOK * 768;
    short* um_hi = qkvl + (size_t)NTOK * 768;      // 4096*320 (padded)
    short* um_lo = um_hi + (size_t)NTOK * UMLD;
    short* o_hi  = um_lo + (size_t)NTOK * UMLD;    // 4096*256
    short* o_lo  = o_hi + (size_t)NTOK * EMBEDc;
    short* f1_hi = o_lo + (size_t)NTOK * EMBEDc;   // 4096*1024
    short* f1_lo = f1_hi + (size_t)NTOK * DFFc;
    short* wqkv_hi = f1_lo + (size_t)NTOK * DFFc;  // 6*768*256
    short* wqkv_lo = wqkv_hi + (size_t)NLc * 768 * EMBEDc;
    short* wo_hi   = wqkv_lo + (size_t)NLc * 768 * EMBEDc;   // 6*256*256
    short* wo_lo   = wo_hi + (size_t)NLc * EMBEDc * DMc;
    short* wf1_hi  = wo_lo + (size_t)NLc * EMBEDc * DMc;     // 6*1024*320 (padded)
    short* wf1_lo  = wf1_hi + (size_t)NLc * DFFc * UMLD;
    short* wf2_hi  = wf1_lo + (size_t)NLc * DFFc * UMLD;     // 6*256*1024
    short* wf2_lo  = wf2_hi + (size_t)NLc * EMBEDc * DFFc;
    short* wex1_hi = wf2_lo + (size_t)NLc * EMBEDc * DFFc;   // 256*64
    short* wex1_lo = wex1_hi + EMBEDc * NZc;
    short* wex2_hi = wex1_lo + EMBEDc * NZc;                 // 256*256
    short* wex2_lo = wex2_hi + EMBEDc * EMBEDc;
    short* wo1_hi  = wex2_lo + EMBEDc * EMBEDc;              // 256*256
    short* wo1_lo  = wo1_hi + EMBEDc * EMBEDc;
    // zt aliases the o buffer (only used in preamble, before k_attn writes o)
    short* zt_hi = o_hi;
    short* zt_lo = o_lo;

    k_pre<<<1024, 256, 0, stream>>>(Wq, Wk, Wv, Wo, Wf1, Wf2, ex_w1, ex_w2, o_w1,
                                    pos_emb, W2d, b2d, x, aa_emb, z,
                                    wqkv_hi, wqkv_lo, wo_hi, wo_lo,
                                    wf1_hi, wf1_lo, wf2_hi, wf2_lo,
                                    wex1_hi, wex1_lo, wex2_hi, wex2_lo,
                                    wo1_hi, wo1_lo, bbuf, um_hi, um_lo,
                                    zt_hi, zt_lo);

    // embed: relu GEMM -> GEMM (fp32 h + bf16 um, ldh = UMLD)
    k_gemm3<1, 1, 0, 64, 3><<<256, 256, 0, stream>>>(
        zt_hi, zt_lo, NZc, wex1_hi, wex1_lo, NZc, NZc,
        nullptr, 0, f1_hi, f1_lo, EMBEDc, ex_b1, 4, 8);
    k_gemm3<3, 1, 0, 64, 3><<<256, 256, 0, stream>>>(
        f1_hi, f1_lo, EMBEDc, wex2_hi, wex2_lo, EMBEDc, EMBEDc,
        h, EMBEDc, um_hi, um_lo, UMLD, ex_b2, 4, 8);

    for (int l = 0; l < NLc; ++l) {
        // qkv: TERMS=2, EPI=5 (lo stored only for K cols 256..511)
        k_gemm3<5, 1, 0, 64, 2><<<768, 256, 0, stream>>>(
            um_hi, um_lo, UMLD,
            wqkv_hi + (size_t)l * 768 * EMBEDc, wqkv_lo + (size_t)l * 768 * EMBEDc, EMBEDc,
            EMBEDc, nullptr, 0, qkvh, qkvl, 768, nullptr, 12, 8);
        k_attn<<<NB * NHc * 4, 512, 0, stream>>>(qkvh, qkvl, bbuf + (size_t)l * NHc * NBINSc, o_hi, o_lo);
        // oproj: TERMS=2 (o RNE bf16; LN damps the error)
        k_gemm3<0, 1, 8, 64, 2><<<512, 256, 0, stream>>>(
            o_hi, o_lo, EMBEDc,
            wo_hi + (size_t)l * EMBEDc * DMc, wo_lo + (size_t)l * EMBEDc * DMc, DMc,
            128, s2a, EMBEDc, nullptr, nullptr, 0, nullptr, 4, 8);
        k_ln<0><<<NTOK / 8, 256, 0, stream>>>(s2a, s2b, bo + (size_t)l * EMBEDc,
                                              ln1_g + (size_t)l * EMBEDc, ln1_b + (size_t)l * EMBEDc,
                                              h, um_hi, um_lo);
        // ffn1: TERMS=2 + EPI=4 (f1_lo dead)
        k_gemm3<4, 2, 0, 64, 2><<<512, 256, 0, stream>>>(
            um_hi, um_lo, UMLD,
            wf1_hi + (size_t)l * DFFc * UMLD, wf1_lo + (size_t)l * DFFc * UMLD, UMLD,
            UMLD, nullptr, 0, f1_hi, f1_lo, DFFc, bf1 + (size_t)l * DFFc, 16, 4);
        // ffn2: TERMS=2 (f1 RNE bf16; LN damps the error)
        k_gemm3<0, 1, 8, 64, 2><<<512, 256, 0, stream>>>(
            f1_hi, f1_lo, DFFc,
            wf2_hi + (size_t)l * EMBEDc * DFFc, wf2_lo + (size_t)l * EMBEDc * DFFc, DFFc,
            512, s2a, EMBEDc, nullptr, nullptr, 0, nullptr, 4, 8);
        if (l == NLc - 1) {
            k_ln<1><<<NTOK / 8, 256, 0, stream>>>(s2a, s2b, bf2 + (size_t)l * EMBEDc,
                                                  ln2_g + (size_t)l * EMBEDc, ln2_b + (size_t)l * EMBEDc,
                                                  h, um_hi, um_lo);
        } else {
            k_ln<0><<<NTOK / 8, 256, 0, stream>>>(s2a, s2b, bf2 + (size_t)l * EMBEDc,
                                                  ln2_g + (size_t)l * EMBEDc, ln2_b + (size_t)l * EMBEDc,
                                                  h, um_hi, um_lo);
        }
    }

    // final: f = relu(um @ o_w1^T + o_b1) (um cols 0..255 hold h in bf16)
    k_gemm3<1, 1, 0, 64, 3><<<256, 256, 0, stream>>>(
        um_hi, um_lo, UMLD, wo1_hi, wo1_lo, EMBEDc, EMBEDc,
        nullptr, 0, f1_hi, f1_lo, EMBEDc, o_b1, 4, 8);
    k_r<<<NTOK / 64, 256, 0, stream>>>(f1_hi, f1_lo, o_w2, o_b2, r);
    k_dmap<<<NB * Lc, 256, 0, stream>>>(r, (float*)d_out);
}

// Round 22
// 443.049 us; speedup vs baseline: 1.3603x; 1.0533x over previous
//
#include <hip/hip_runtime.h>
#include <math.h>

#define NZc     64
#define EMBEDc  256
#define DMc     256
#define NHc     16
#define HDc     16
#define DFFc    1024
#define NLc     6
#define E1Dc    32
#define PDIMc   64
#define PMAXLc  24
#define NBINSc  49
#define NB      8
#define Lc      512
#define NTOK    (NB * Lc)        // 4096
#define UMDIM   288              // logical um width
#define UMLD    320              // padded leading dim (zeros in 288..319)

typedef __attribute__((ext_vector_type(4))) float f4;
typedef __attribute__((ext_vector_type(8))) short bf8;   // 8 bf16 in 4 VGPRs

#define MFMA(a, b, c) __builtin_amdgcn_mfma_f32_16x16x32_bf16((a), (b), (c), 0, 0, 0)

__device__ __forceinline__ short f2bf(float f) {
    unsigned u = __float_as_uint(f);
    u += 0x7FFFu + ((u >> 16) & 1u);   // round-to-nearest-even
    return (short)(u >> 16);
}
__device__ __forceinline__ float bf2f(short s) {
    return __uint_as_float(((unsigned)(unsigned short)s) << 16);
}

// ---------------------------------------------------------------------------
// preamble: weight conversions (x8 vectorized) + bias bins + e_aa + z^T.
__global__ void k_pre(const float* __restrict__ Wq, const float* __restrict__ Wk,
                      const float* __restrict__ Wv, const float* __restrict__ Wo,
                      const float* __restrict__ Wf1, const float* __restrict__ Wf2,
                      const float* __restrict__ exw1, const float* __restrict__ exw2,
                      const float* __restrict__ ow1,
                      const float* __restrict__ pos_emb, const float* __restrict__ W2d,
                      const float* __restrict__ b2d, const float* __restrict__ x,
                      const float* __restrict__ aa_emb, const float* __restrict__ z,
                      short* __restrict__ wqkv_hi, short* __restrict__ wqkv_lo,
                      short* __restrict__ wo_hi, short* __restrict__ wo_lo,
                      short* __restrict__ wf1_hi, short* __restrict__ wf1_lo,
                      short* __restrict__ wf2_hi, short* __restrict__ wf2_lo,
                      short* __restrict__ wex1_hi, short* __restrict__ wex1_lo,
                      short* __restrict__ wex2_hi, short* __restrict__ wex2_lo,
                      short* __restrict__ wo1_hi, short* __restrict__ wo1_lo,
                      float* __restrict__ bb,
                      short* __restrict__ umhi, short* __restrict__ umlo,
                      short* __restrict__ zth, short* __restrict__ ztl) {
    int stride = gridDim.x * blockDim.x;
    int tid = blockIdx.x * blockDim.x + threadIdx.x;
#define CVT(src, hi, lo, per_layer, dstride, doff, scale, total)               \
    for (int i = tid; i < (total) / 8; i += stride) {                          \
        int ib = i * 8;                                                        \
        int ll = ib / (per_layer), rels = ib - ll * (per_layer);               \
        size_t di = (size_t)ll * (dstride) + (doff) + rels;                    \
        f4 v0 = *(const f4*)(src + ib);                                        \
        f4 v1 = *(const f4*)(src + ib + 4);                                    \
        bf8 hv, lv;                                                            \
        _Pragma("unroll")                                                      \
        for (int q = 0; q < 4; ++q) {                                          \
            float v = v0[q] * (scale);                                         \
            short hh = f2bf(v);                                                \
            hv[q] = hh;                                                        \
            lv[q] = f2bf(v - bf2f(hh));                                        \
        }                                                                      \
        _Pragma("unroll")                                                      \
        for (int q = 0; q < 4; ++q) {                                          \
            float v = v1[q] * (scale);                                         \
            short hh = f2bf(v);                                                \
            hv[q + 4] = hh;                                                    \
            lv[q + 4] = f2bf(v - bf2f(hh));                                    \
        }                                                                      \
        *(bf8*)(hi + di) = hv;                                                 \
        *(bf8*)(lo + di) = lv;                                                 \
    }
    CVT(Wq,  wqkv_hi, wqkv_lo, 65536, 196608, 0,      0.0625f, 393216);
    CVT(Wk,  wqkv_hi, wqkv_lo, 65536, 196608, 65536,  1.f,     393216);
    CVT(Wv,  wqkv_hi, wqkv_lo, 65536, 196608, 131072, 1.f,     393216);
    CVT(Wo,  wo_hi,  wo_lo,  65536,  65536,  0, 1.f, 393216);
    CVT(Wf2, wf2_hi, wf2_lo, 262144, 262144, 0, 1.f, 1572864);
    CVT(exw1, wex1_hi, wex1_lo, 16384, 16384, 0, 1.f, 16384);
    CVT(exw2, wex2_hi, wex2_lo, 65536, 65536, 0, 1.f, 65536);
    CVT(ow1,  wo1_hi,  wo1_lo,  65536, 65536, 0, 1.f, 65536);
#undef CVT
    // Wf1: src rows of 288 -> dest rows of 320 (row boundary 8-aligned)
    for (int i = tid; i < 1769472 / 8; i += stride) {
        int ib = i * 8;
        int ll = ib / 294912, rels = ib - ll * 294912;
        int row = rels / 288, col = rels - row * 288;
        size_t di = (size_t)ll * (1024 * UMLD) + (size_t)row * UMLD + col;
        f4 v0 = *(const f4*)(Wf1 + ib);
        f4 v1 = *(const f4*)(Wf1 + ib + 4);
        bf8 hv, lv;
#pragma unroll
        for (int q = 0; q < 4; ++q) {
            float v = v0[q];
            short hh = f2bf(v);
            hv[q] = hh;
            lv[q] = f2bf(v - bf2f(hh));
        }
#pragma unroll
        for (int q = 0; q < 4; ++q) {
            float v = v1[q];
            short hh = f2bf(v);
            hv[q + 4] = hh;
            lv[q + 4] = f2bf(v - bf2f(hh));
        }
        *(bf8*)(wf1_hi + di) = hv;
        *(bf8*)(wf1_lo + di) = lv;
    }
    // zero pad cols 288..319: wf1 hi/lo (B staged hi+lo) and um_hi (A hi)
    {
        bf8 zz;
#pragma unroll
        for (int q = 0; q < 8; ++q) zz[q] = 0;
        for (int i = tid; i < 6144 * 4; i += stride) {
            int row = i >> 2, seg = i & 3;
            size_t di = (size_t)row * UMLD + UMDIM + seg * 8;
            *(bf8*)(wf1_hi + di) = zz;
            *(bf8*)(wf1_lo + di) = zz;
        }
        for (int i = tid; i < 4096 * 4; i += stride) {
            int row = i >> 2, seg = i & 3;
            size_t di = (size_t)row * UMLD + UMDIM + seg * 8;
            *(bf8*)(umhi + di) = zz;
        }
    }
    for (int idx = tid; idx < NLc * NHc * NBINSc; idx += stride) {
        int bin = idx % NBINSc;
        int tmp = idx / NBINSc;
        int hh = tmp % NHc, l = tmp / NHc;
        float s = b2d[l * NHc + hh];
        const float* pe = pos_emb + bin * PDIMc;
        const float* w  = W2d + (l * NHc + hh) * PDIMc;
        for (int p = 0; p < PDIMc; ++p) s += pe[p] * w[p];
        bb[idx] = s;
    }
    // e_aa -> um_hi cols 256..287 (lo dead: ffn1 is TERMS=2)
    for (int tok = tid; tok < NTOK; tok += stride) {
        int n = tok / Lc, l = tok % Lc;
        const float* xp = x + (size_t)n * 20 * Lc + l;
        float best = xp[0];
        int bi = 0;
        for (int c = 1; c < 20; ++c) {
            float v = xp[c * Lc];
            if (v > best) { best = v; bi = c; }
        }
        const float* e = aa_emb + bi * E1Dc;
        bf8 hv;
        for (int c8 = 0; c8 < E1Dc / 8; ++c8) {
#pragma unroll
            for (int q = 0; q < 8; ++q) hv[q] = f2bf(e[c8 * 8 + q]);
            *(bf8*)(umhi + (size_t)tok * UMLD + EMBEDc + c8 * 8) = hv;
        }
    }
    for (int tok = tid; tok < NTOK; tok += stride) {
        int n = tok >> 9, l = tok & 511;
        bf8 hv, lv;
        for (int c8 = 0; c8 < NZc / 8; ++c8) {
#pragma unroll
            for (int q = 0; q < 8; ++q) {
                float v = z[((size_t)n * NZc + c8 * 8 + q) * Lc + l];
                short hh = f2bf(v);
                hv[q] = hh;
                lv[q] = f2bf(v - bf2f(hh));
            }
            *(bf8*)(zth + (size_t)tok * NZc + c8 * 8) = hv;
            *(bf8*)(ztl + (size_t)tok * NZc + c8 * 8) = lv;
        }
    }
}

// ---------------------------------------------------------------------------
// LDS-staged MFMA GEMM. TERMS=3: full compensated. TERMS=2: drop AlBh.
// EPI 0: fp32 out. 1: relu->hi/lo. 2: ->hi/lo. 3: fp32+hi/lo.
// 4: relu->hi only. 6: ->hi only (split-K-aware: kh offsets ohi).
template <int EPI, int MF, int SKSHIFT, int BK, int TERMS>
__global__ __launch_bounds__(256) void k_gemm3(
    const short* __restrict__ Ahi, const short* __restrict__ Alo, int lda,
    const short* __restrict__ Bhi, const short* __restrict__ Blo, int ldb,
    int K, float* __restrict__ outf, int ldo, short* __restrict__ ohi,
    short* __restrict__ olo, int ldh, const float* __restrict__ bias,
    int gx, int gypx) {
    constexpr int PAD = BK + 8;
    __shared__ __align__(16) short Ah[MF * 64][PAD];
    __shared__ __align__(16) short Al[TERMS == 3 ? MF * 64 : 1][TERMS == 3 ? PAD : 1];
    __shared__ __align__(16) short Bh[64][PAD];
    __shared__ __align__(16) short Bl[64][PAD];

    int bid = blockIdx.x;
    int koff = 0;
    if (SKSHIFT) {
        int kh = bid >> SKSHIFT;
        bid &= (1 << SKSHIFT) - 1;
        koff = kh * K;
        if (EPI == 6) ohi += (size_t)kh * NTOK * EMBEDc;
        else outf += (size_t)kh * NTOK * EMBEDc;
    }
    int xcd = bid & 7, j = bid >> 3;
    int bx = j % gx, by = xcd * gypx + j / gx;

    int t = threadIdx.x;
    int w = t >> 6, l = t & 63, lr = l & 15, lk = l >> 4;
    int m0 = by * (MF * 64);
    int n0 = bx * 64;

    constexpr int TPR = BK / 8;
    constexpr int RP  = 256 / TPR;
    constexpr int AP  = MF * 64 / RP;
    constexpr int BP  = 64 / RP;
    int srow = t / TPR, scol = (t % TPR) * 8;

    const short* pa  = Ahi + (size_t)(m0 + srow) * lda + koff + scol;
    const short* pal = Alo + (size_t)(m0 + srow) * lda + koff + scol;
    const short* pb  = Bhi + (size_t)(n0 + srow) * ldb + koff + scol;
    const short* pbl = Blo + (size_t)(n0 + srow) * ldb + koff + scol;

    bf8 ra[AP], rla[AP], rb[BP], rlb[BP];
#pragma unroll
    for (int p = 0; p < AP; ++p) {
        ra[p] = *(const bf8*)(pa + (size_t)p * RP * lda);
        if (TERMS == 3) rla[p] = *(const bf8*)(pal + (size_t)p * RP * lda);
    }
#pragma unroll
    for (int p = 0; p < BP; ++p) {
        rb[p]  = *(const bf8*)(pb  + (size_t)p * RP * ldb);
        rlb[p] = *(const bf8*)(pbl + (size_t)p * RP * ldb);
    }

    f4 acc[MF][4];
#pragma unroll
    for (int mf = 0; mf < MF; ++mf)
#pragma unroll
        for (int nf = 0; nf < 4; ++nf) acc[mf][nf] = (f4){0.f, 0.f, 0.f, 0.f};

    for (int ks = 0; ks < K; ks += BK) {
        __syncthreads();
#pragma unroll
        for (int p = 0; p < AP; ++p) {
            *(bf8*)&Ah[p * RP + srow][scol] = ra[p];
            if (TERMS == 3) *(bf8*)&Al[p * RP + srow][scol] = rla[p];
        }
#pragma unroll
        for (int p = 0; p < BP; ++p) {
            *(bf8*)&Bh[p * RP + srow][scol] = rb[p];
            *(bf8*)&Bl[p * RP + srow][scol] = rlb[p];
        }
        __syncthreads();
        if (ks + BK < K) {
#pragma unroll
            for (int p = 0; p < AP; ++p) {
                ra[p] = *(const bf8*)(pa + (size_t)p * RP * lda + ks + BK);
                if (TERMS == 3) rla[p] = *(const bf8*)(pal + (size_t)p * RP * lda + ks + BK);
            }
#pragma unroll
            for (int p = 0; p < BP; ++p) {
                rb[p]  = *(const bf8*)(pb  + (size_t)p * RP * ldb + ks + BK);
                rlb[p] = *(const bf8*)(pbl + (size_t)p * RP * ldb + ks + BK);
            }
        }
#pragma unroll
        for (int kc = 0; kc < BK / 32; ++kc) {
            bf8 bhf[4], blf[4];
#pragma unroll
            for (int nf = 0; nf < 4; ++nf) {
                bhf[nf] = *(const bf8*)&Bh[nf * 16 + lr][kc * 32 + lk * 8];
                blf[nf] = *(const bf8*)&Bl[nf * 16 + lr][kc * 32 + lk * 8];
            }
#pragma unroll
            for (int mf = 0; mf < MF; ++mf) {
                bf8 ah = *(const bf8*)&Ah[w * MF * 16 + mf * 16 + lr][kc * 32 + lk * 8];
                bf8 al;
                if (TERMS == 3) al = *(const bf8*)&Al[w * MF * 16 + mf * 16 + lr][kc * 32 + lk * 8];
#pragma unroll
                for (int nf = 0; nf < 4; ++nf) {
                    acc[mf][nf] = MFMA(ah, bhf[nf], acc[mf][nf]);
                    acc[mf][nf] = MFMA(ah, blf[nf], acc[mf][nf]);
                    if (TERMS == 3) acc[mf][nf] = MFMA(al, bhf[nf], acc[mf][nf]);
                }
            }
        }
    }

#pragma unroll
    for (int mf = 0; mf < MF; ++mf) {
#pragma unroll
        for (int nf = 0; nf < 4; ++nf) {
            int n = n0 + nf * 16 + lr;
            int mbase = m0 + w * MF * 16 + mf * 16 + lk * 4;
            if (EPI == 0) {
#pragma unroll
                for (int r = 0; r < 4; ++r)
                    outf[(size_t)(mbase + r) * ldo + n] = acc[mf][nf][r];
            } else if (EPI == 1) {
                float bv = bias[n];
#pragma unroll
                for (int r = 0; r < 4; ++r) {
                    float y = fmaxf(acc[mf][nf][r] + bv, 0.f);
                    short hv = f2bf(y);
                    size_t oi = (size_t)(mbase + r) * ldh + n;
                    ohi[oi] = hv;
                    olo[oi] = f2bf(y - bf2f(hv));
                }
            } else if (EPI == 2) {
#pragma unroll
                for (int r = 0; r < 4; ++r) {
                    float y = acc[mf][nf][r];
                    short hv = f2bf(y);
                    size_t oi = (size_t)(mbase + r) * ldh + n;
                    ohi[oi] = hv;
                    olo[oi] = f2bf(y - bf2f(hv));
                }
            } else if (EPI == 3) {
                float bv = bias[n];
#pragma unroll
                for (int r = 0; r < 4; ++r) {
                    float y = acc[mf][nf][r] + bv;
                    outf[(size_t)(mbase + r) * ldo + n] = y;
                    short hv = f2bf(y);
                    size_t oi = (size_t)(mbase + r) * ldh + n;
                    ohi[oi] = hv;
                    olo[oi] = f2bf(y - bf2f(hv));
                }
            } else if (EPI == 4) {   // relu(acc+bias) -> hi only
                float bv = bias[n];
#pragma unroll
                for (int r = 0; r < 4; ++r) {
                    float y = fmaxf(acc[mf][nf][r] + bv, 0.f);
                    ohi[(size_t)(mbase + r) * ldh + n] = f2bf(y);
                }
            } else {   // EPI == 6: plain bf16 hi-only store
#pragma unroll
                for (int r = 0; r < 4; ++r)
                    ohi[(size_t)(mbase + r) * ldh + n] = f2bf(acc[mf][nf][r]);
            }
        }
    }
}

// ---------------------------------------------------------------------------
// MFMA flash attention: Q, K, V all consumed at bf16 (softmax-/oproj-damped),
// P stays compensated (free in the K=32 MFMA dim). khl lo half zeroed once
// so A = [Kh|0] x B = [Qh|Qh] = Kh.Qh exactly.
__global__ __launch_bounds__(512, 8) void k_attn(const short* __restrict__ qh,
                                                 const float* __restrict__ bb,
                                                 short* __restrict__ ohi) {
    int bx = blockIdx.x;
    int qt = bx >> 7;            // 0..3; blocks sharing (n,head) same XCD
    int head = bx & 15;
    int n = (bx >> 4) & 7;
    int t = threadIdx.x;
    int w = t >> 6, l = t & 63;
    int lq = l & 15, lk = l >> 4;

    __shared__ __align__(16) short khl[256][40];   // [key][hi0-15|zeros|pad]
    __shared__ __align__(16) short vth[16][264];   // V^T hi: [d][key 0..255]
    __shared__ __align__(16) float pw[8][16][20];  // per-wave P[q][key] buffer
    __shared__ float biasr[64];

    if (t < NBINSc) biasr[t] = bb[head * NBINSc + t];
    float bL = bb[head * NBINSc];
    float bR = bb[head * NBINSc + 48];

    // zero khl lo halves once (cols 16..31 of each row)
    {
        bf8 zz;
#pragma unroll
        for (int i = 0; i < 8; ++i) zz[i] = 0;
        int row = t >> 1, seg = t & 1;
        *(bf8*)&khl[row][16 + seg * 8] = zz;
    }

    size_t base = (size_t)n * Lc * 768 + head * 16;

    int qg = qt * 128 + w * 16 + lq;             // this lane's q column
    size_t qrow = ((size_t)n * Lc + qg) * 768 + head * 16;
    bf8 B1 = *(const bf8*)(qh + qrow + (lk & 1) * 8);   // [Qh|Qh]

    f4 acc = (f4){0.f, 0.f, 0.f, 0.f};
    float m = -1e30f, lsum = 0.f;
    int rel0 = lk * 4 - qg;      // rel of s[0] at global kt=0; += 16 per tile

    for (int half = 0; half < 2; ++half) {
        __syncthreads();          // previous half fully consumed
        // stage K half (256 keys, hi only): 1 bf8 per thread
        {
            int key = t >> 1, seg = t & 1;
            const short* src = qh + base + 256
                             + (size_t)(half * 256 + key) * 768 + seg * 8;
            *(bf8*)&khl[key][seg * 8] = *(const bf8*)src;
        }
        // stage V half transposed (hi only), pair-packed b32 writes
        if (t < 256) {
            int u = t & 127;             // key pair
            int dhalf = (t >> 7) & 1;    // d 0..7 / 8..15
            int gkey = half * 256 + u * 2;
            const short* vs = qh + base + 512 + (size_t)gkey * 768 + dhalf * 8;
            bf8 A = *(const bf8*)vs;
            bf8 B = *(const bf8*)(vs + 768);
            unsigned* vw = (unsigned*)&vth[0][0];  // row stride 132 words
#pragma unroll
            for (int i = 0; i < 8; ++i)
                vw[(dhalf * 8 + i) * 132 + u] =
                    (unsigned)(unsigned short)A[i] | ((unsigned)(unsigned short)B[i] << 16);
        }
        __syncthreads();

        for (int kt = 0; kt < 16; ++kt, rel0 += 16) {
            bf8 A1 = *(const bf8*)&khl[kt * 16 + lq][lk * 8];  // [Kh|0]
            f4 s = (f4){0.f, 0.f, 0.f, 0.f};
            __builtin_amdgcn_s_setprio(1);
            s = MFMA(A1, B1, s);      // Kh.Qh (both bf16)
            __builtin_amdgcn_s_setprio(0);
            if (rel0 >= PMAXLc) {
                s[0] += bR; s[1] += bR; s[2] += bR; s[3] += bR;
            } else if (rel0 + 3 <= -PMAXLc) {
                s[0] += bL; s[1] += bL; s[2] += bL; s[3] += bL;
            } else {
#pragma unroll
                for (int r = 0; r < 4; ++r) {
                    int rel = rel0 + r;
                    rel = rel < -PMAXLc ? -PMAXLc : (rel > PMAXLc ? PMAXLc : rel);
                    s[r] += biasr[rel + PMAXLc];
                }
            }
            float mt = fmaxf(fmaxf(s[0], s[1]), fmaxf(s[2], s[3]));
            mt = fmaxf(mt, __shfl_xor(mt, 16));
            mt = fmaxf(mt, __shfl_xor(mt, 32));
            if (__any(mt > m + 8.0f)) {
                float mn = fmaxf(m, mt);
                float alpha = __expf(m - mn);
                m = mn;
                lsum *= alpha;
#pragma unroll
                for (int r = 0; r < 4; ++r) acc[r] *= __shfl(alpha, lk * 4 + r);
            }
            f4 p;
#pragma unroll
            for (int r = 0; r < 4; ++r) p[r] = __expf(s[r] - m);
            lsum += p[0] + p[1] + p[2] + p[3];
            // P routed via per-wave LDS (wave-synchronous, no barrier)
            *(f4*)&pw[w][lq][lk * 4] = p;
            const float* pr = &pw[w][lq][(lk & 1) * 8];
            f4 ga = *(const f4*)pr;
            f4 gb = *(const f4*)(pr + 4);
            bf8 PA;                       // [Ph|Pl] along MFMA K-dim
            if (lk < 2) {
#pragma unroll
                for (int jj = 0; jj < 4; ++jj) {
                    PA[jj]     = (short)(__float_as_uint(ga[jj]) >> 16);
                    PA[jj + 4] = (short)(__float_as_uint(gb[jj]) >> 16);
                }
            } else {
#pragma unroll
                for (int jj = 0; jj < 4; ++jj) {
                    unsigned hu0 = __float_as_uint(ga[jj]) & 0xFFFF0000u;
                    unsigned hu1 = __float_as_uint(gb[jj]) & 0xFFFF0000u;
                    PA[jj]     = (short)(__float_as_uint(ga[jj] - __uint_as_float(hu0)) >> 16);
                    PA[jj + 4] = (short)(__float_as_uint(gb[jj] - __uint_as_float(hu1)) >> 16);
                }
            }
            bf8 VB1 = *(const bf8*)&vth[lq][kt * 16 + (lk & 1) * 8];  // [Vh|Vh]
            __builtin_amdgcn_s_setprio(1);
            acc = MFMA(PA, VB1, acc);   // (Ph+Pl)Vh  (P compensated, V bf16)
            __builtin_amdgcn_s_setprio(0);
        }
    }

    float lred = lsum + __shfl_xor(lsum, 16);
    lred += __shfl_xor(lred, 32);
    float inv = 1.0f / lred;
#pragma unroll
    for (int r = 0; r < 4; ++r) {
        float iq = __shfl(inv, lk * 4 + r);
        float y = acc[r] * iq;
        int qo = qt * 128 + w * 16 + lk * 4 + r;
        size_t oi = ((size_t)n * Lc + qo) * DMc + head * 16 + lq;
        ohi[oi] = f2bf(y);   // RNE; o_lo never read (oproj TERMS=2)
    }
}

// ---------------------------------------------------------------------------
// LN over h + s2a + s2b + sbias; s2 partials are bf16 (EPI=6 split-K output).
// WRITE_LO=1 only for the final LN (um_lo consumed only by the final GEMM).
template <int WRITE_LO>
__global__ __launch_bounds__(256) void k_ln(const short* __restrict__ s2a,
                                            const short* __restrict__ s2b,
                                            const float* __restrict__ sbias,
                                            const float* __restrict__ g,
                                            const float* __restrict__ bta,
                                            float* __restrict__ h,
                                            short* __restrict__ umhi,
                                            short* __restrict__ umlo) {
    int t = threadIdx.x;
    int tl = t >> 5, j = t & 31;
    size_t gtok = (size_t)blockIdx.x * 8 + tl;
    int d0 = j * 8;
    size_t off = gtok * EMBEDc + d0;
    f4 h0 = *(const f4*)(h + off);
    f4 h1 = *(const f4*)(h + off + 4);
    bf8 pa = *(const bf8*)(s2a + off);
    bf8 pb = *(const bf8*)(s2b + off);
    f4 sb0 = *(const f4*)(sbias + d0);
    f4 sb1 = *(const f4*)(sbias + d0 + 4);
    f4 v0, v1;
#pragma unroll
    for (int q = 0; q < 4; ++q) {
        v0[q] = h0[q] + bf2f(pa[q])     + bf2f(pb[q])     + sb0[q];
        v1[q] = h1[q] + bf2f(pa[q + 4]) + bf2f(pb[q + 4]) + sb1[q];
    }
    float sum = v0[0] + v0[1] + v0[2] + v0[3] + v1[0] + v1[1] + v1[2] + v1[3];
    float ssq = v0[0]*v0[0] + v0[1]*v0[1] + v0[2]*v0[2] + v0[3]*v0[3]
              + v1[0]*v1[0] + v1[1]*v1[1] + v1[2]*v1[2] + v1[3]*v1[3];
#pragma unroll
    for (int off5 = 16; off5; off5 >>= 1) {
        sum += __shfl_xor(sum, off5, 32);
        ssq += __shfl_xor(ssq, off5, 32);
    }
    float mean = sum * (1.f / EMBEDc);
    float var = ssq * (1.f / EMBEDc) - mean * mean;
    float inv = rsqrtf(var + 1e-5f);
    f4 g0 = *(const f4*)(g + d0);
    f4 g1 = *(const f4*)(g + d0 + 4);
    f4 t0 = *(const f4*)(bta + d0);
    f4 t1 = *(const f4*)(bta + d0 + 4);
    f4 y0, y1;
    bf8 hv, lv;
#pragma unroll
    for (int q = 0; q < 4; ++q) {
        float y = (v0[q] - mean) * inv * g0[q] + t0[q];
        y0[q] = y;
        short hh = f2bf(y);
        hv[q] = hh;
        if (WRITE_LO) lv[q] = f2bf(y - bf2f(hh));
    }
#pragma unroll
    for (int q = 0; q < 4; ++q) {
        float y = (v1[q] - mean) * inv * g1[q] + t1[q];
        y1[q] = y;
        short hh = f2bf(y);
        hv[q + 4] = hh;
        if (WRITE_LO) lv[q + 4] = f2bf(y - bf2f(hh));
    }
    *(f4*)(h + off) = y0;
    *(f4*)(h + off + 4) = y1;
    *(bf8*)(umhi + gtok * UMLD + d0) = hv;
    if (WRITE_LO) *(bf8*)(umlo + gtok * UMLD + d0) = lv;
}

// ---------------------------------------------------------------------------
__global__ __launch_bounds__(256) void k_r(const short* __restrict__ fh,
                                           const short* __restrict__ fl,
                                           const float* __restrict__ w2,
                                           const float* __restrict__ b2,
                                           float* __restrict__ r) {
    __shared__ float w[3][EMBEDc];
    int t = threadIdx.x;
    for (int u = t; u < 3 * EMBEDc; u += 256) w[u >> 8][u & 255] = w2[u];
    __syncthreads();
    int tok = blockIdx.x * 64 + (t >> 2), o = t & 3;
    if (o < 3) {
        const short* ph = fh + (size_t)tok * EMBEDc;
        const short* pl = fl + (size_t)tok * EMBEDc;
        float s = b2[o];
        for (int c8 = 0; c8 < EMBEDc / 8; ++c8) {
            bf8 vh = *(const bf8*)(ph + c8 * 8);
            bf8 vl = *(const bf8*)(pl + c8 * 8);
#pragma unroll
            for (int j = 0; j < 8; ++j)
                s += (bf2f(vh[j]) + bf2f(vl[j])) * w[o][c8 * 8 + j];
        }
        r[(size_t)tok * 3 + o] = s;
    }
}

// ---------------------------------------------------------------------------
__global__ __launch_bounds__(256) void k_dmap(const float* __restrict__ r,
                                              float* __restrict__ d) {
    int b = blockIdx.x;
    int n = b / Lc;
    float xi = r[(size_t)b * 3], yi = r[(size_t)b * 3 + 1], zi = r[(size_t)b * 3 + 2];
    const float* rn = r + (size_t)n * Lc * 3;
    for (int j = threadIdx.x; j < Lc; j += 256) {
        float dx = xi - rn[j * 3];
        float dy = yi - rn[j * 3 + 1];
        float dz = zi - rn[j * 3 + 2];
        d[(size_t)b * Lc + j] = sqrtf(dx * dx + dy * dy + dz * dz + 1e-12f);
    }
}

// ---------------------------------------------------------------------------
extern "C" void kernel_launch(void* const* d_in, const int* in_sizes, int n_in,
                              void* d_out, int out_size, void* d_ws, size_t ws_size,
                              hipStream_t stream) {
    const float* z       = (const float*)d_in[0];
    const float* x       = (const float*)d_in[1];
    const float* pos_emb = (const float*)d_in[2];
    const float* aa_emb  = (const float*)d_in[3];
    const float* ex_w1   = (const float*)d_in[4];
    const float* ex_b1   = (const float*)d_in[5];
    const float* ex_w2   = (const float*)d_in[6];
    const float* ex_b2   = (const float*)d_in[7];
    const float* Wq      = (const float*)d_in[8];
    const float* Wk      = (const float*)d_in[9];
    const float* Wv      = (const float*)d_in[10];
    const float* Wo      = (const float*)d_in[11];
    const float* bo      = (const float*)d_in[12];
    const float* W2d     = (const float*)d_in[13];
    const float* b2d     = (const float*)d_in[14];
    const float* Wf1     = (const float*)d_in[15];
    const float* bf1     = (const float*)d_in[16];
    const float* Wf2     = (const float*)d_in[17];
    const float* bf2     = (const float*)d_in[18];
    const float* ln1_g   = (const float*)d_in[19];
    const float* ln1_b   = (const float*)d_in[20];
    const float* ln2_g   = (const float*)d_in[21];
    const float* ln2_b   = (const float*)d_in[22];
    const float* o_w1    = (const float*)d_in[23];
    const float* o_b1    = (const float*)d_in[24];
    const float* o_w2    = (const float*)d_in[25];
    const float* o_b2    = (const float*)d_in[26];

    float* h    = (float*)d_ws;                    // 4096*256 fp32
    // s2 partials now bf16: reuse the two former fp32 regions (contiguous,
    // so the split-K kh offset from s2a lands exactly on s2b)
    short* s2a  = (short*)(h + (size_t)NTOK * EMBEDc);
    short* s2b  = s2a + (size_t)NTOK * EMBEDc;
    float* bbuf = (float*)(h + (size_t)3 * NTOK * EMBEDc);  // pad 8192
    float* r    = bbuf + 8192;                     // pad 16384
    short* qkvh = (short*)(r + 16384);             // 4096*768
    short* qkvl = qkvh + (size_t)NTOK * 768;       // (dead; kept for layout)
    short* um_hi = qkvl + (size_t)NTOK * 768;      // 4096*320 (padded)
    short* um_lo = um_hi + (size_t)NTOK * UMLD;
    short* o_hi  = um_lo + (size_t)NTOK * UMLD;    // 4096*256
    short* o_lo  = o_hi + (size_t)NTOK * EMBEDc;
    short* f1_hi = o_lo + (size_t)NTOK * EMBEDc;   // 4096*1024
    short* f1_lo = f1_hi + (size_t)NTOK * DFFc;
    short* wqkv_hi = f1_lo + (size_t)NTOK * DFFc;  // 6*768*256
    short* wqkv_lo = wqkv_hi + (size_t)NLc * 768 * EMBEDc;
    short* wo_hi   = wqkv_lo + (size_t)NLc * 768 * EMBEDc;   // 6*256*256
    short* wo_lo   = wo_hi + (size_t)NLc * EMBEDc * DMc;
    short* wf1_hi  = wo_lo + (size_t)NLc * EMBEDc * DMc;     // 6*1024*320 (padded)
    short* wf1_lo  = wf1_hi + (size_t)NLc * DFFc * UMLD;
    short* wf2_hi  = wf1_lo + (size_t)NLc * DFFc * UMLD;     // 6*256*1024
    short* wf2_lo  = wf2_hi + (size_t)NLc * EMBEDc * DFFc;
    short* wex1_hi = wf2_lo + (size_t)NLc * EMBEDc * DFFc;   // 256*64
    short* wex1_lo = wex1_hi + EMBEDc * NZc;
    short* wex2_hi = wex1_lo + EMBEDc * NZc;                 // 256*256
    short* wex2_lo = wex2_hi + EMBEDc * EMBEDc;
    short* wo1_hi  = wex2_lo + EMBEDc * EMBEDc;              // 256*256
    short* wo1_lo  = wo1_hi + EMBEDc * EMBEDc;
    // zt aliases the o buffer (only used in preamble, before k_attn writes o)
    short* zt_hi = o_hi;
    short* zt_lo = o_lo;

    k_pre<<<1024, 256, 0, stream>>>(Wq, Wk, Wv, Wo, Wf1, Wf2, ex_w1, ex_w2, o_w1,
                                    pos_emb, W2d, b2d, x, aa_emb, z,
                                    wqkv_hi, wqkv_lo, wo_hi, wo_lo,
                                    wf1_hi, wf1_lo, wf2_hi, wf2_lo,
                                    wex1_hi, wex1_lo, wex2_hi, wex2_lo,
                                    wo1_hi, wo1_lo, bbuf, um_hi, um_lo,
                                    zt_hi, zt_lo);

    // embed: relu GEMM -> GEMM (fp32 h + bf16 um, ldh = UMLD)
    k_gemm3<1, 1, 0, 64, 3><<<256, 256, 0, stream>>>(
        zt_hi, zt_lo, NZc, wex1_hi, wex1_lo, NZc, NZc,
        nullptr, 0, f1_hi, f1_lo, EMBEDc, ex_b1, 4, 8);
    k_gemm3<3, 1, 0, 64, 3><<<256, 256, 0, stream>>>(
        f1_hi, f1_lo, EMBEDc, wex2_hi, wex2_lo, EMBEDc, EMBEDc,
        h, EMBEDc, um_hi, um_lo, UMLD, ex_b2, 4, 8);

    for (int l = 0; l < NLc; ++l) {
        // qkv: TERMS=2, EPI=6 (hi only; K consumed at bf16 in attention)
        k_gemm3<6, 1, 0, 64, 2><<<768, 256, 0, stream>>>(
            um_hi, um_lo, UMLD,
            wqkv_hi + (size_t)l * 768 * EMBEDc, wqkv_lo + (size_t)l * 768 * EMBEDc, EMBEDc,
            EMBEDc, nullptr, 0, qkvh, nullptr, 768, nullptr, 12, 8);
        k_attn<<<NB * NHc * 4, 512, 0, stream>>>(qkvh, bbuf + (size_t)l * NHc * NBINSc, o_hi);
        // oproj: TERMS=2, EPI=6 split-K -> bf16 partials s2a/s2b
        k_gemm3<6, 1, 8, 64, 2><<<512, 256, 0, stream>>>(
            o_hi, o_hi, EMBEDc,
            wo_hi + (size_t)l * EMBEDc * DMc, wo_lo + (size_t)l * EMBEDc * DMc, DMc,
            128, nullptr, 0, s2a, nullptr, EMBEDc, nullptr, 4, 8);
        k_ln<0><<<NTOK / 8, 256, 0, stream>>>(s2a, s2b, bo + (size_t)l * EMBEDc,
                                              ln1_g + (size_t)l * EMBEDc, ln1_b + (size_t)l * EMBEDc,
                                              h, um_hi, um_lo);
        // ffn1: TERMS=2 + EPI=4 (f1_lo dead)
        k_gemm3<4, 2, 0, 64, 2><<<512, 256, 0, stream>>>(
            um_hi, um_lo, UMLD,
            wf1_hi + (size_t)l * DFFc * UMLD, wf1_lo + (size_t)l * DFFc * UMLD, UMLD,
            UMLD, nullptr, 0, f1_hi, f1_lo, DFFc, bf1 + (size_t)l * DFFc, 16, 4);
        // ffn2: TERMS=2, EPI=6 split-K -> bf16 partials s2a/s2b
        k_gemm3<6, 1, 8, 64, 2><<<512, 256, 0, stream>>>(
            f1_hi, f1_hi, DFFc,
            wf2_hi + (size_t)l * EMBEDc * DFFc, wf2_lo + (size_t)l * EMBEDc * DFFc, DFFc,
            512, nullptr, 0, s2a, nullptr, EMBEDc, nullptr, 4, 8);
        if (l == NLc - 1) {
            k_ln<1><<<NTOK / 8, 256, 0, stream>>>(s2a, s2b, bf2 + (size_t)l * EMBEDc,
                                                  ln2_g + (size_t)l * EMBEDc, ln2_b + (size_t)l * EMBEDc,
                                                  h, um_hi, um_lo);
        } else {
            k_ln<0><<<NTOK / 8, 256, 0, stream>>>(s2a, s2b, bf2 + (size_t)l * EMBEDc,
                                                  ln2_g + (size_t)l * EMBEDc, ln2_b + (size_t)l * EMBEDc,
                                                  h, um_hi, um_lo);
        }
    }

    // final: f = relu(um @ o_w1^T + o_b1) (um cols 0..255 hold h in bf16)
    k_gemm3<1, 1, 0, 64, 3><<<256, 256, 0, stream>>>(
        um_hi, um_lo, UMLD, wo1_hi, wo1_lo, EMBEDc, EMBEDc,
        nullptr, 0, f1_hi, f1_lo, EMBEDc, o_b1, 4, 8);
    k_r<<<NTOK / 64, 256, 0, stream>>>(f1_hi, f1_lo, o_w2, o_b2, r);
    k_dmap<<<NB * Lc, 256, 0, stream>>>(r, (float*)d_out);
}

// Round 23
// 429.001 us; speedup vs baseline: 1.4048x; 1.0327x over previous
//
#include <hip/hip_runtime.h>
#include <math.h>

#define NZc     64
#define EMBEDc  256
#define DMc     256
#define NHc     16
#define HDc     16
#define DFFc    1024
#define NLc     6
#define E1Dc    32
#define PDIMc   64
#define PMAXLc  24
#define NBINSc  49
#define NB      8
#define Lc      512
#define NTOK    (NB * Lc)        // 4096
#define UMDIM   288              // logical um width
#define UMLD    320              // padded leading dim (zeros in 288..319)

typedef __attribute__((ext_vector_type(4))) float f4;
typedef __attribute__((ext_vector_type(8))) short bf8;   // 8 bf16 in 4 VGPRs

#define MFMA(a, b, c) __builtin_amdgcn_mfma_f32_16x16x32_bf16((a), (b), (c), 0, 0, 0)

__device__ __forceinline__ short f2bf(float f) {
    unsigned u = __float_as_uint(f);
    u += 0x7FFFu + ((u >> 16) & 1u);   // round-to-nearest-even
    return (short)(u >> 16);
}
__device__ __forceinline__ float bf2f(short s) {
    return __uint_as_float(((unsigned)(unsigned short)s) << 16);
}

// ---------------------------------------------------------------------------
// preamble: weight conversions (x8 vectorized) + bias bins + e_aa + z^T.
__global__ void k_pre(const float* __restrict__ Wq, const float* __restrict__ Wk,
                      const float* __restrict__ Wv, const float* __restrict__ Wo,
                      const float* __restrict__ Wf1, const float* __restrict__ Wf2,
                      const float* __restrict__ exw1, const float* __restrict__ exw2,
                      const float* __restrict__ ow1,
                      const float* __restrict__ pos_emb, const float* __restrict__ W2d,
                      const float* __restrict__ b2d, const float* __restrict__ x,
                      const float* __restrict__ aa_emb, const float* __restrict__ z,
                      short* __restrict__ wqkv_hi, short* __restrict__ wqkv_lo,
                      short* __restrict__ wo_hi, short* __restrict__ wo_lo,
                      short* __restrict__ wf1_hi, short* __restrict__ wf1_lo,
                      short* __restrict__ wf2_hi, short* __restrict__ wf2_lo,
                      short* __restrict__ wex1_hi, short* __restrict__ wex1_lo,
                      short* __restrict__ wex2_hi, short* __restrict__ wex2_lo,
                      short* __restrict__ wo1_hi, short* __restrict__ wo1_lo,
                      float* __restrict__ bb,
                      short* __restrict__ umhi, short* __restrict__ umlo,
                      short* __restrict__ zth, short* __restrict__ ztl) {
    int stride = gridDim.x * blockDim.x;
    int tid = blockIdx.x * blockDim.x + threadIdx.x;
#define CVT(src, hi, lo, per_layer, dstride, doff, scale, total)               \
    for (int i = tid; i < (total) / 8; i += stride) {                          \
        int ib = i * 8;                                                        \
        int ll = ib / (per_layer), rels = ib - ll * (per_layer);               \
        size_t di = (size_t)ll * (dstride) + (doff) + rels;                    \
        f4 v0 = *(const f4*)(src + ib);                                        \
        f4 v1 = *(const f4*)(src + ib + 4);                                    \
        bf8 hv, lv;                                                            \
        _Pragma("unroll")                                                      \
        for (int q = 0; q < 4; ++q) {                                          \
            float v = v0[q] * (scale);                                         \
            short hh = f2bf(v);                                                \
            hv[q] = hh;                                                        \
            lv[q] = f2bf(v - bf2f(hh));                                        \
        }                                                                      \
        _Pragma("unroll")                                                      \
        for (int q = 0; q < 4; ++q) {                                          \
            float v = v1[q] * (scale);                                         \
            short hh = f2bf(v);                                                \
            hv[q + 4] = hh;                                                    \
            lv[q + 4] = f2bf(v - bf2f(hh));                                    \
        }                                                                      \
        *(bf8*)(hi + di) = hv;                                                 \
        *(bf8*)(lo + di) = lv;                                                 \
    }
    CVT(Wq,  wqkv_hi, wqkv_lo, 65536, 196608, 0,      0.0625f, 393216);
    CVT(Wk,  wqkv_hi, wqkv_lo, 65536, 196608, 65536,  1.f,     393216);
    CVT(Wv,  wqkv_hi, wqkv_lo, 65536, 196608, 131072, 1.f,     393216);
    CVT(Wo,  wo_hi,  wo_lo,  65536,  65536,  0, 1.f, 393216);
    CVT(Wf2, wf2_hi, wf2_lo, 262144, 262144, 0, 1.f, 1572864);
    CVT(exw1, wex1_hi, wex1_lo, 16384, 16384, 0, 1.f, 16384);
    CVT(exw2, wex2_hi, wex2_lo, 65536, 65536, 0, 1.f, 65536);
    CVT(ow1,  wo1_hi,  wo1_lo,  65536, 65536, 0, 1.f, 65536);
#undef CVT
    // Wf1: src rows of 288 -> dest rows of 320 (row boundary 8-aligned)
    for (int i = tid; i < 1769472 / 8; i += stride) {
        int ib = i * 8;
        int ll = ib / 294912, rels = ib - ll * 294912;
        int row = rels / 288, col = rels - row * 288;
        size_t di = (size_t)ll * (1024 * UMLD) + (size_t)row * UMLD + col;
        f4 v0 = *(const f4*)(Wf1 + ib);
        f4 v1 = *(const f4*)(Wf1 + ib + 4);
        bf8 hv, lv;
#pragma unroll
        for (int q = 0; q < 4; ++q) {
            float v = v0[q];
            short hh = f2bf(v);
            hv[q] = hh;
            lv[q] = f2bf(v - bf2f(hh));
        }
#pragma unroll
        for (int q = 0; q < 4; ++q) {
            float v = v1[q];
            short hh = f2bf(v);
            hv[q + 4] = hh;
            lv[q + 4] = f2bf(v - bf2f(hh));
        }
        *(bf8*)(wf1_hi + di) = hv;
        *(bf8*)(wf1_lo + di) = lv;
    }
    // zero pad cols 288..319: wf1 hi/lo (B staged hi+lo) and um_hi (A hi)
    {
        bf8 zz;
#pragma unroll
        for (int q = 0; q < 8; ++q) zz[q] = 0;
        for (int i = tid; i < 6144 * 4; i += stride) {
            int row = i >> 2, seg = i & 3;
            size_t di = (size_t)row * UMLD + UMDIM + seg * 8;
            *(bf8*)(wf1_hi + di) = zz;
            *(bf8*)(wf1_lo + di) = zz;
        }
        for (int i = tid; i < 4096 * 4; i += stride) {
            int row = i >> 2, seg = i & 3;
            size_t di = (size_t)row * UMLD + UMDIM + seg * 8;
            *(bf8*)(umhi + di) = zz;
        }
    }
    for (int idx = tid; idx < NLc * NHc * NBINSc; idx += stride) {
        int bin = idx % NBINSc;
        int tmp = idx / NBINSc;
        int hh = tmp % NHc, l = tmp / NHc;
        float s = b2d[l * NHc + hh];
        const float* pe = pos_emb + bin * PDIMc;
        const float* w  = W2d + (l * NHc + hh) * PDIMc;
        for (int p = 0; p < PDIMc; ++p) s += pe[p] * w[p];
        bb[idx] = s;
    }
    // e_aa -> um_hi cols 256..287 (lo dead: ffn1 is TERMS=2)
    for (int tok = tid; tok < NTOK; tok += stride) {
        int n = tok / Lc, l = tok % Lc;
        const float* xp = x + (size_t)n * 20 * Lc + l;
        float best = xp[0];
        int bi = 0;
        for (int c = 1; c < 20; ++c) {
            float v = xp[c * Lc];
            if (v > best) { best = v; bi = c; }
        }
        const float* e = aa_emb + bi * E1Dc;
        bf8 hv;
        for (int c8 = 0; c8 < E1Dc / 8; ++c8) {
#pragma unroll
            for (int q = 0; q < 8; ++q) hv[q] = f2bf(e[c8 * 8 + q]);
            *(bf8*)(umhi + (size_t)tok * UMLD + EMBEDc + c8 * 8) = hv;
        }
    }
    for (int tok = tid; tok < NTOK; tok += stride) {
        int n = tok >> 9, l = tok & 511;
        bf8 hv, lv;
        for (int c8 = 0; c8 < NZc / 8; ++c8) {
#pragma unroll
            for (int q = 0; q < 8; ++q) {
                float v = z[((size_t)n * NZc + c8 * 8 + q) * Lc + l];
                short hh = f2bf(v);
                hv[q] = hh;
                lv[q] = f2bf(v - bf2f(hh));
            }
            *(bf8*)(zth + (size_t)tok * NZc + c8 * 8) = hv;
            *(bf8*)(ztl + (size_t)tok * NZc + c8 * 8) = lv;
        }
    }
}

// ---------------------------------------------------------------------------
// LDS-staged MFMA GEMM. TERMS=3: full compensated. TERMS=2: drop AlBh.
// EPI 0: fp32 out. 1: relu->hi/lo. 2: ->hi/lo. 3: fp32+hi/lo.
// 4: relu->hi only. 6: ->hi only (split-K-aware: kh offsets ohi).
template <int EPI, int MF, int SKSHIFT, int BK, int TERMS>
__global__ __launch_bounds__(256) void k_gemm3(
    const short* __restrict__ Ahi, const short* __restrict__ Alo, int lda,
    const short* __restrict__ Bhi, const short* __restrict__ Blo, int ldb,
    int K, float* __restrict__ outf, int ldo, short* __restrict__ ohi,
    short* __restrict__ olo, int ldh, const float* __restrict__ bias,
    int gx, int gypx) {
    constexpr int PAD = BK + 8;
    __shared__ __align__(16) short Ah[MF * 64][PAD];
    __shared__ __align__(16) short Al[TERMS == 3 ? MF * 64 : 1][TERMS == 3 ? PAD : 1];
    __shared__ __align__(16) short Bh[64][PAD];
    __shared__ __align__(16) short Bl[64][PAD];

    int bid = blockIdx.x;
    int koff = 0;
    if (SKSHIFT) {
        int kh = bid >> SKSHIFT;
        bid &= (1 << SKSHIFT) - 1;
        koff = kh * K;
        if (EPI == 6) ohi += (size_t)kh * NTOK * EMBEDc;
        else outf += (size_t)kh * NTOK * EMBEDc;
    }
    int xcd = bid & 7, j = bid >> 3;
    int bx = j % gx, by = xcd * gypx + j / gx;

    int t = threadIdx.x;
    int w = t >> 6, l = t & 63, lr = l & 15, lk = l >> 4;
    int m0 = by * (MF * 64);
    int n0 = bx * 64;

    constexpr int TPR = BK / 8;
    constexpr int RP  = 256 / TPR;
    constexpr int AP  = MF * 64 / RP;
    constexpr int BP  = 64 / RP;
    int srow = t / TPR, scol = (t % TPR) * 8;

    const short* pa  = Ahi + (size_t)(m0 + srow) * lda + koff + scol;
    const short* pal = Alo + (size_t)(m0 + srow) * lda + koff + scol;
    const short* pb  = Bhi + (size_t)(n0 + srow) * ldb + koff + scol;
    const short* pbl = Blo + (size_t)(n0 + srow) * ldb + koff + scol;

    bf8 ra[AP], rla[AP], rb[BP], rlb[BP];
#pragma unroll
    for (int p = 0; p < AP; ++p) {
        ra[p] = *(const bf8*)(pa + (size_t)p * RP * lda);
        if (TERMS == 3) rla[p] = *(const bf8*)(pal + (size_t)p * RP * lda);
    }
#pragma unroll
    for (int p = 0; p < BP; ++p) {
        rb[p]  = *(const bf8*)(pb  + (size_t)p * RP * ldb);
        rlb[p] = *(const bf8*)(pbl + (size_t)p * RP * ldb);
    }

    f4 acc[MF][4];
#pragma unroll
    for (int mf = 0; mf < MF; ++mf)
#pragma unroll
        for (int nf = 0; nf < 4; ++nf) acc[mf][nf] = (f4){0.f, 0.f, 0.f, 0.f};

    for (int ks = 0; ks < K; ks += BK) {
        __syncthreads();
#pragma unroll
        for (int p = 0; p < AP; ++p) {
            *(bf8*)&Ah[p * RP + srow][scol] = ra[p];
            if (TERMS == 3) *(bf8*)&Al[p * RP + srow][scol] = rla[p];
        }
#pragma unroll
        for (int p = 0; p < BP; ++p) {
            *(bf8*)&Bh[p * RP + srow][scol] = rb[p];
            *(bf8*)&Bl[p * RP + srow][scol] = rlb[p];
        }
        __syncthreads();
        if (ks + BK < K) {
#pragma unroll
            for (int p = 0; p < AP; ++p) {
                ra[p] = *(const bf8*)(pa + (size_t)p * RP * lda + ks + BK);
                if (TERMS == 3) rla[p] = *(const bf8*)(pal + (size_t)p * RP * lda + ks + BK);
            }
#pragma unroll
            for (int p = 0; p < BP; ++p) {
                rb[p]  = *(const bf8*)(pb  + (size_t)p * RP * ldb + ks + BK);
                rlb[p] = *(const bf8*)(pbl + (size_t)p * RP * ldb + ks + BK);
            }
        }
#pragma unroll
        for (int kc = 0; kc < BK / 32; ++kc) {
            bf8 bhf[4], blf[4];
#pragma unroll
            for (int nf = 0; nf < 4; ++nf) {
                bhf[nf] = *(const bf8*)&Bh[nf * 16 + lr][kc * 32 + lk * 8];
                blf[nf] = *(const bf8*)&Bl[nf * 16 + lr][kc * 32 + lk * 8];
            }
#pragma unroll
            for (int mf = 0; mf < MF; ++mf) {
                bf8 ah = *(const bf8*)&Ah[w * MF * 16 + mf * 16 + lr][kc * 32 + lk * 8];
                bf8 al;
                if (TERMS == 3) al = *(const bf8*)&Al[w * MF * 16 + mf * 16 + lr][kc * 32 + lk * 8];
#pragma unroll
                for (int nf = 0; nf < 4; ++nf) {
                    acc[mf][nf] = MFMA(ah, bhf[nf], acc[mf][nf]);
                    acc[mf][nf] = MFMA(ah, blf[nf], acc[mf][nf]);
                    if (TERMS == 3) acc[mf][nf] = MFMA(al, bhf[nf], acc[mf][nf]);
                }
            }
        }
    }

#pragma unroll
    for (int mf = 0; mf < MF; ++mf) {
#pragma unroll
        for (int nf = 0; nf < 4; ++nf) {
            int n = n0 + nf * 16 + lr;
            int mbase = m0 + w * MF * 16 + mf * 16 + lk * 4;
            if (EPI == 0) {
#pragma unroll
                for (int r = 0; r < 4; ++r)
                    outf[(size_t)(mbase + r) * ldo + n] = acc[mf][nf][r];
            } else if (EPI == 1) {
                float bv = bias[n];
#pragma unroll
                for (int r = 0; r < 4; ++r) {
                    float y = fmaxf(acc[mf][nf][r] + bv, 0.f);
                    short hv = f2bf(y);
                    size_t oi = (size_t)(mbase + r) * ldh + n;
                    ohi[oi] = hv;
                    olo[oi] = f2bf(y - bf2f(hv));
                }
            } else if (EPI == 2) {
#pragma unroll
                for (int r = 0; r < 4; ++r) {
                    float y = acc[mf][nf][r];
                    short hv = f2bf(y);
                    size_t oi = (size_t)(mbase + r) * ldh + n;
                    ohi[oi] = hv;
                    olo[oi] = f2bf(y - bf2f(hv));
                }
            } else if (EPI == 3) {
                float bv = bias[n];
#pragma unroll
                for (int r = 0; r < 4; ++r) {
                    float y = acc[mf][nf][r] + bv;
                    outf[(size_t)(mbase + r) * ldo + n] = y;
                    short hv = f2bf(y);
                    size_t oi = (size_t)(mbase + r) * ldh + n;
                    ohi[oi] = hv;
                    olo[oi] = f2bf(y - bf2f(hv));
                }
            } else if (EPI == 4) {   // relu(acc+bias) -> hi only
                float bv = bias[n];
#pragma unroll
                for (int r = 0; r < 4; ++r) {
                    float y = fmaxf(acc[mf][nf][r] + bv, 0.f);
                    ohi[(size_t)(mbase + r) * ldh + n] = f2bf(y);
                }
            } else {   // EPI == 6: plain bf16 hi-only store
#pragma unroll
                for (int r = 0; r < 4; ++r)
                    ohi[(size_t)(mbase + r) * ldh + n] = f2bf(acc[mf][nf][r]);
            }
        }
    }
}

// ---------------------------------------------------------------------------
// MFMA flash attention, dual key-tile iterations: 2 tiles (32 keys) share one
// joint max-reduce + defer-max branch per iteration. Q/K/V bf16, P compensated.
__global__ __launch_bounds__(512, 8) void k_attn(const short* __restrict__ qh,
                                                 const float* __restrict__ bb,
                                                 short* __restrict__ ohi) {
    int bx = blockIdx.x;
    int qt = bx >> 7;            // 0..3; blocks sharing (n,head) same XCD
    int head = bx & 15;
    int n = (bx >> 4) & 7;
    int t = threadIdx.x;
    int w = t >> 6, l = t & 63;
    int lq = l & 15, lk = l >> 4;

    __shared__ __align__(16) short khl[256][40];   // [key][hi0-15|zeros|pad]
    __shared__ __align__(16) short vth[16][264];   // V^T hi: [d][key 0..255]
    __shared__ __align__(16) float pw[8][16][20];  // per-wave P[q][key] buffer
    __shared__ float biasr[64];

    if (t < NBINSc) biasr[t] = bb[head * NBINSc + t];
    float bL = bb[head * NBINSc];
    float bR = bb[head * NBINSc + 48];

    // zero khl lo halves once (cols 16..31 of each row)
    {
        bf8 zz;
#pragma unroll
        for (int i = 0; i < 8; ++i) zz[i] = 0;
        int row = t >> 1, seg = t & 1;
        *(bf8*)&khl[row][16 + seg * 8] = zz;
    }

    size_t base = (size_t)n * Lc * 768 + head * 16;

    int qg = qt * 128 + w * 16 + lq;             // this lane's q column
    size_t qrow = ((size_t)n * Lc + qg) * 768 + head * 16;
    bf8 B1 = *(const bf8*)(qh + qrow + (lk & 1) * 8);   // [Qh|Qh]

    f4 acc = (f4){0.f, 0.f, 0.f, 0.f};
    float m = -1e30f, lsum = 0.f;
    int rel0 = lk * 4 - qg;      // rel of sA[0] at kt=0; += 32 per iteration

    for (int half = 0; half < 2; ++half) {
        __syncthreads();          // previous half fully consumed
        // stage K half (256 keys, hi only): 1 bf8 per thread
        {
            int key = t >> 1, seg = t & 1;
            const short* src = qh + base + 256
                             + (size_t)(half * 256 + key) * 768 + seg * 8;
            *(bf8*)&khl[key][seg * 8] = *(const bf8*)src;
        }
        // stage V half transposed (hi only), pair-packed b32 writes
        if (t < 256) {
            int u = t & 127;             // key pair
            int dhalf = (t >> 7) & 1;    // d 0..7 / 8..15
            int gkey = half * 256 + u * 2;
            const short* vs = qh + base + 512 + (size_t)gkey * 768 + dhalf * 8;
            bf8 A = *(const bf8*)vs;
            bf8 B = *(const bf8*)(vs + 768);
            unsigned* vw = (unsigned*)&vth[0][0];  // row stride 132 words
#pragma unroll
            for (int i = 0; i < 8; ++i)
                vw[(dhalf * 8 + i) * 132 + u] =
                    (unsigned)(unsigned short)A[i] | ((unsigned)(unsigned short)B[i] << 16);
        }
        __syncthreads();

        for (int it = 0; it < 8; ++it, rel0 += 32) {
            bf8 A1 = *(const bf8*)&khl[it * 32 + lq][lk * 8];        // [Kh|0]
            bf8 A2 = *(const bf8*)&khl[it * 32 + 16 + lq][lk * 8];   // [Kh|0]
            f4 sA = (f4){0.f, 0.f, 0.f, 0.f};
            f4 sB = (f4){0.f, 0.f, 0.f, 0.f};
            __builtin_amdgcn_s_setprio(1);
            sA = MFMA(A1, B1, sA);
            sB = MFMA(A2, B1, sB);
            __builtin_amdgcn_s_setprio(0);
            // bias tile A (rel0) and tile B (rel0+16), each with fast paths
            if (rel0 >= PMAXLc) {
                sA[0] += bR; sA[1] += bR; sA[2] += bR; sA[3] += bR;
            } else if (rel0 + 3 <= -PMAXLc) {
                sA[0] += bL; sA[1] += bL; sA[2] += bL; sA[3] += bL;
            } else {
#pragma unroll
                for (int r = 0; r < 4; ++r) {
                    int rel = rel0 + r;
                    rel = rel < -PMAXLc ? -PMAXLc : (rel > PMAXLc ? PMAXLc : rel);
                    sA[r] += biasr[rel + PMAXLc];
                }
            }
            int rel1 = rel0 + 16;
            if (rel1 >= PMAXLc) {
                sB[0] += bR; sB[1] += bR; sB[2] += bR; sB[3] += bR;
            } else if (rel1 + 3 <= -PMAXLc) {
                sB[0] += bL; sB[1] += bL; sB[2] += bL; sB[3] += bL;
            } else {
#pragma unroll
                for (int r = 0; r < 4; ++r) {
                    int rel = rel1 + r;
                    rel = rel < -PMAXLc ? -PMAXLc : (rel > PMAXLc ? PMAXLc : rel);
                    sB[r] += biasr[rel + PMAXLc];
                }
            }
            // joint max over both tiles (2 shuffles, 1 defer-max branch)
            float mt = fmaxf(fmaxf(fmaxf(sA[0], sA[1]), fmaxf(sA[2], sA[3])),
                             fmaxf(fmaxf(sB[0], sB[1]), fmaxf(sB[2], sB[3])));
            mt = fmaxf(mt, __shfl_xor(mt, 16));
            mt = fmaxf(mt, __shfl_xor(mt, 32));
            if (__any(mt > m + 8.0f)) {
                float mn = fmaxf(m, mt);
                float alpha = __expf(m - mn);
                m = mn;
                lsum *= alpha;
#pragma unroll
                for (int r = 0; r < 4; ++r) acc[r] *= __shfl(alpha, lk * 4 + r);
            }
            f4 pA, pB;
#pragma unroll
            for (int r = 0; r < 4; ++r) {
                pA[r] = __expf(sA[r] - m);
                pB[r] = __expf(sB[r] - m);
            }
            lsum += pA[0] + pA[1] + pA[2] + pA[3]
                  + pB[0] + pB[1] + pB[2] + pB[3];

            // ---- PV tile A (pw round-trip; wave-synchronous) ----
            *(f4*)&pw[w][lq][lk * 4] = pA;
            {
                const float* pr = &pw[w][lq][(lk & 1) * 8];
                f4 ga = *(const f4*)pr;
                f4 gb = *(const f4*)(pr + 4);
                bf8 PA;
                if (lk < 2) {
#pragma unroll
                    for (int jj = 0; jj < 4; ++jj) {
                        PA[jj]     = (short)(__float_as_uint(ga[jj]) >> 16);
                        PA[jj + 4] = (short)(__float_as_uint(gb[jj]) >> 16);
                    }
                } else {
#pragma unroll
                    for (int jj = 0; jj < 4; ++jj) {
                        unsigned hu0 = __float_as_uint(ga[jj]) & 0xFFFF0000u;
                        unsigned hu1 = __float_as_uint(gb[jj]) & 0xFFFF0000u;
                        PA[jj]     = (short)(__float_as_uint(ga[jj] - __uint_as_float(hu0)) >> 16);
                        PA[jj + 4] = (short)(__float_as_uint(gb[jj] - __uint_as_float(hu1)) >> 16);
                    }
                }
                bf8 VB = *(const bf8*)&vth[lq][it * 32 + (lk & 1) * 8];
                __builtin_amdgcn_s_setprio(1);
                acc = MFMA(PA, VB, acc);
                __builtin_amdgcn_s_setprio(0);
            }
            // ---- PV tile B ----
            *(f4*)&pw[w][lq][lk * 4] = pB;
            {
                const float* pr = &pw[w][lq][(lk & 1) * 8];
                f4 ga = *(const f4*)pr;
                f4 gb = *(const f4*)(pr + 4);
                bf8 PB;
                if (lk < 2) {
#pragma unroll
                    for (int jj = 0; jj < 4; ++jj) {
                        PB[jj]     = (short)(__float_as_uint(ga[jj]) >> 16);
                        PB[jj + 4] = (short)(__float_as_uint(gb[jj]) >> 16);
                    }
                } else {
#pragma unroll
                    for (int jj = 0; jj < 4; ++jj) {
                        unsigned hu0 = __float_as_uint(ga[jj]) & 0xFFFF0000u;
                        unsigned hu1 = __float_as_uint(gb[jj]) & 0xFFFF0000u;
                        PB[jj]     = (short)(__float_as_uint(ga[jj] - __uint_as_float(hu0)) >> 16);
                        PB[jj + 4] = (short)(__float_as_uint(gb[jj] - __uint_as_float(hu1)) >> 16);
                    }
                }
                bf8 VB = *(const bf8*)&vth[lq][it * 32 + 16 + (lk & 1) * 8];
                __builtin_amdgcn_s_setprio(1);
                acc = MFMA(PB, VB, acc);
                __builtin_amdgcn_s_setprio(0);
            }
        }
    }

    float lred = lsum + __shfl_xor(lsum, 16);
    lred += __shfl_xor(lred, 32);
    float inv = 1.0f / lred;
#pragma unroll
    for (int r = 0; r < 4; ++r) {
        float iq = __shfl(inv, lk * 4 + r);
        float y = acc[r] * iq;
        int qo = qt * 128 + w * 16 + lk * 4 + r;
        size_t oi = ((size_t)n * Lc + qo) * DMc + head * 16 + lq;
        ohi[oi] = f2bf(y);   // RNE; o_lo never read (oproj TERMS=2)
    }
}

// ---------------------------------------------------------------------------
// LN over h + s2a + s2b + sbias; s2 partials are bf16 (EPI=6 split-K output).
// WRITE_LO=1 only for the final LN (um_lo consumed only by the final GEMM).
template <int WRITE_LO>
__global__ __launch_bounds__(256) void k_ln(const short* __restrict__ s2a,
                                            const short* __restrict__ s2b,
                                            const float* __restrict__ sbias,
                                            const float* __restrict__ g,
                                            const float* __restrict__ bta,
                                            float* __restrict__ h,
                                            short* __restrict__ umhi,
                                            short* __restrict__ umlo) {
    int t = threadIdx.x;
    int tl = t >> 5, j = t & 31;
    size_t gtok = (size_t)blockIdx.x * 8 + tl;
    int d0 = j * 8;
    size_t off = gtok * EMBEDc + d0;
    f4 h0 = *(const f4*)(h + off);
    f4 h1 = *(const f4*)(h + off + 4);
    bf8 pa = *(const bf8*)(s2a + off);
    bf8 pb = *(const bf8*)(s2b + off);
    f4 sb0 = *(const f4*)(sbias + d0);
    f4 sb1 = *(const f4*)(sbias + d0 + 4);
    f4 v0, v1;
#pragma unroll
    for (int q = 0; q < 4; ++q) {
        v0[q] = h0[q] + bf2f(pa[q])     + bf2f(pb[q])     + sb0[q];
        v1[q] = h1[q] + bf2f(pa[q + 4]) + bf2f(pb[q + 4]) + sb1[q];
    }
    float sum = v0[0] + v0[1] + v0[2] + v0[3] + v1[0] + v1[1] + v1[2] + v1[3];
    float ssq = v0[0]*v0[0] + v0[1]*v0[1] + v0[2]*v0[2] + v0[3]*v0[3]
              + v1[0]*v1[0] + v1[1]*v1[1] + v1[2]*v1[2] + v1[3]*v1[3];
#pragma unroll
    for (int off5 = 16; off5; off5 >>= 1) {
        sum += __shfl_xor(sum, off5, 32);
        ssq += __shfl_xor(ssq, off5, 32);
    }
    float mean = sum * (1.f / EMBEDc);
    float var = ssq * (1.f / EMBEDc) - mean * mean;
    float inv = rsqrtf(var + 1e-5f);
    f4 g0 = *(const f4*)(g + d0);
    f4 g1 = *(const f4*)(g + d0 + 4);
    f4 t0 = *(const f4*)(bta + d0);
    f4 t1 = *(const f4*)(bta + d0 + 4);
    f4 y0, y1;
    bf8 hv, lv;
#pragma unroll
    for (int q = 0; q < 4; ++q) {
        float y = (v0[q] - mean) * inv * g0[q] + t0[q];
        y0[q] = y;
        short hh = f2bf(y);
        hv[q] = hh;
        if (WRITE_LO) lv[q] = f2bf(y - bf2f(hh));
    }
#pragma unroll
    for (int q = 0; q < 4; ++q) {
        float y = (v1[q] - mean) * inv * g1[q] + t1[q];
        y1[q] = y;
        short hh = f2bf(y);
        hv[q + 4] = hh;
        if (WRITE_LO) lv[q + 4] = f2bf(y - bf2f(hh));
    }
    *(f4*)(h + off) = y0;
    *(f4*)(h + off + 4) = y1;
    *(bf8*)(umhi + gtok * UMLD + d0) = hv;
    if (WRITE_LO) *(bf8*)(umlo + gtok * UMLD + d0) = lv;
}

// ---------------------------------------------------------------------------
__global__ __launch_bounds__(256) void k_r(const short* __restrict__ fh,
                                           const short* __restrict__ fl,
                                           const float* __restrict__ w2,
                                           const float* __restrict__ b2,
                                           float* __restrict__ r) {
    __shared__ float w[3][EMBEDc];
    int t = threadIdx.x;
    for (int u = t; u < 3 * EMBEDc; u += 256) w[u >> 8][u & 255] = w2[u];
    __syncthreads();
    int tok = blockIdx.x * 64 + (t >> 2), o = t & 3;
    if (o < 3) {
        const short* ph = fh + (size_t)tok * EMBEDc;
        const short* pl = fl + (size_t)tok * EMBEDc;
        float s = b2[o];
        for (int c8 = 0; c8 < EMBEDc / 8; ++c8) {
            bf8 vh = *(const bf8*)(ph + c8 * 8);
            bf8 vl = *(const bf8*)(pl + c8 * 8);
#pragma unroll
            for (int j = 0; j < 8; ++j)
                s += (bf2f(vh[j]) + bf2f(vl[j])) * w[o][c8 * 8 + j];
        }
        r[(size_t)tok * 3 + o] = s;
    }
}

// ---------------------------------------------------------------------------
__global__ __launch_bounds__(256) void k_dmap(const float* __restrict__ r,
                                              float* __restrict__ d) {
    int b = blockIdx.x;
    int n = b / Lc;
    float xi = r[(size_t)b * 3], yi = r[(size_t)b * 3 + 1], zi = r[(size_t)b * 3 + 2];
    const float* rn = r + (size_t)n * Lc * 3;
    for (int j = threadIdx.x; j < Lc; j += 256) {
        float dx = xi - rn[j * 3];
        float dy = yi - rn[j * 3 + 1];
        float dz = zi - rn[j * 3 + 2];
        d[(size_t)b * Lc + j] = sqrtf(dx * dx + dy * dy + dz * dz + 1e-12f);
    }
}

// ---------------------------------------------------------------------------
extern "C" void kernel_launch(void* const* d_in, const int* in_sizes, int n_in,
                              void* d_out, int out_size, void* d_ws, size_t ws_size,
                              hipStream_t stream) {
    const float* z       = (const float*)d_in[0];
    const float* x       = (const float*)d_in[1];
    const float* pos_emb = (const float*)d_in[2];
    const float* aa_emb  = (const float*)d_in[3];
    const float* ex_w1   = (const float*)d_in[4];
    const float* ex_b1   = (const float*)d_in[5];
    const float* ex_w2   = (const float*)d_in[6];
    const float* ex_b2   = (const float*)d_in[7];
    const float* Wq      = (const float*)d_in[8];
    const float* Wk      = (const float*)d_in[9];
    const float* Wv      = (const float*)d_in[10];
    const float* Wo      = (const float*)d_in[11];
    const float* bo      = (const float*)d_in[12];
    const float* W2d     = (const float*)d_in[13];
    const float* b2d     = (const float*)d_in[14];
    const float* Wf1     = (const float*)d_in[15];
    const float* bf1     = (const float*)d_in[16];
    const float* Wf2     = (const float*)d_in[17];
    const float* bf2     = (const float*)d_in[18];
    const float* ln1_g   = (const float*)d_in[19];
    const float* ln1_b   = (const float*)d_in[20];
    const float* ln2_g   = (const float*)d_in[21];
    const float* ln2_b   = (const float*)d_in[22];
    const float* o_w1    = (const float*)d_in[23];
    const float* o_b1    = (const float*)d_in[24];
    const float* o_w2    = (const float*)d_in[25];
    const float* o_b2    = (const float*)d_in[26];

    float* h    = (float*)d_ws;                    // 4096*256 fp32
    short* s2a  = (short*)(h + (size_t)NTOK * EMBEDc);
    short* s2b  = s2a + (size_t)NTOK * EMBEDc;
    float* bbuf = (float*)(h + (size_t)3 * NTOK * EMBEDc);  // pad 8192
    float* r    = bbuf + 8192;                     // pad 16384
    short* qkvh = (short*)(r + 16384);             // 4096*768
    short* qkvl = qkvh + (size_t)NTOK * 768;       // (dead; kept for layout)
    short* um_hi = qkvl + (size_t)NTOK * 768;      // 4096*320 (padded)
    short* um_lo = um_hi + (size_t)NTOK * UMLD;
    short* o_hi  = um_lo + (size_t)NTOK * UMLD;    // 4096*256
    short* o_lo  = o_hi + (size_t)NTOK * EMBEDc;
    short* f1_hi = o_lo + (size_t)NTOK * EMBEDc;   // 4096*1024
    short* f1_lo = f1_hi + (size_t)NTOK * DFFc;
    short* wqkv_hi = f1_lo + (size_t)NTOK * DFFc;  // 6*768*256
    short* wqkv_lo = wqkv_hi + (size_t)NLc * 768 * EMBEDc;
    short* wo_hi   = wqkv_lo + (size_t)NLc * 768 * EMBEDc;   // 6*256*256
    short* wo_lo   = wo_hi + (size_t)NLc * EMBEDc * DMc;
    short* wf1_hi  = wo_lo + (size_t)NLc * EMBEDc * DMc;     // 6*1024*320 (padded)
    short* wf1_lo  = wf1_hi + (size_t)NLc * DFFc * UMLD;
    short* wf2_hi  = wf1_lo + (size_t)NLc * DFFc * UMLD;     // 6*256*1024
    short* wf2_lo  = wf2_hi + (size_t)NLc * EMBEDc * DFFc;
    short* wex1_hi = wf2_lo + (size_t)NLc * EMBEDc * DFFc;   // 256*64
    short* wex1_lo = wex1_hi + EMBEDc * NZc;
    short* wex2_hi = wex1_lo + EMBEDc * NZc;                 // 256*256
    short* wex2_lo = wex2_hi + EMBEDc * EMBEDc;
    short* wo1_hi  = wex2_lo + EMBEDc * EMBEDc;              // 256*256
    short* wo1_lo  = wo1_hi + EMBEDc * EMBEDc;
    // zt aliases the o buffer (only used in preamble, before k_attn writes o)
    short* zt_hi = o_hi;
    short* zt_lo = o_lo;

    k_pre<<<1024, 256, 0, stream>>>(Wq, Wk, Wv, Wo, Wf1, Wf2, ex_w1, ex_w2, o_w1,
                                    pos_emb, W2d, b2d, x, aa_emb, z,
                                    wqkv_hi, wqkv_lo, wo_hi, wo_lo,
                                    wf1_hi, wf1_lo, wf2_hi, wf2_lo,
                                    wex1_hi, wex1_lo, wex2_hi, wex2_lo,
                                    wo1_hi, wo1_lo, bbuf, um_hi, um_lo,
                                    zt_hi, zt_lo);

    // embed: relu GEMM -> GEMM (fp32 h + bf16 um, ldh = UMLD)
    k_gemm3<1, 1, 0, 64, 3><<<256, 256, 0, stream>>>(
        zt_hi, zt_lo, NZc, wex1_hi, wex1_lo, NZc, NZc,
        nullptr, 0, f1_hi, f1_lo, EMBEDc, ex_b1, 4, 8);
    k_gemm3<3, 1, 0, 64, 3><<<256, 256, 0, stream>>>(
        f1_hi, f1_lo, EMBEDc, wex2_hi, wex2_lo, EMBEDc, EMBEDc,
        h, EMBEDc, um_hi, um_lo, UMLD, ex_b2, 4, 8);

    for (int l = 0; l < NLc; ++l) {
        // qkv: TERMS=2, EPI=6 (hi only; K consumed at bf16 in attention)
        k_gemm3<6, 1, 0, 64, 2><<<768, 256, 0, stream>>>(
            um_hi, um_lo, UMLD,
            wqkv_hi + (size_t)l * 768 * EMBEDc, wqkv_lo + (size_t)l * 768 * EMBEDc, EMBEDc,
            EMBEDc, nullptr, 0, qkvh, nullptr, 768, nullptr, 12, 8);
        k_attn<<<NB * NHc * 4, 512, 0, stream>>>(qkvh, bbuf + (size_t)l * NHc * NBINSc, o_hi);
        // oproj: TERMS=2, EPI=6 split-K -> bf16 partials s2a/s2b
        k_gemm3<6, 1, 8, 64, 2><<<512, 256, 0, stream>>>(
            o_hi, o_hi, EMBEDc,
            wo_hi + (size_t)l * EMBEDc * DMc, wo_lo + (size_t)l * EMBEDc * DMc, DMc,
            128, nullptr, 0, s2a, nullptr, EMBEDc, nullptr, 4, 8);
        k_ln<0><<<NTOK / 8, 256, 0, stream>>>(s2a, s2b, bo + (size_t)l * EMBEDc,
                                              ln1_g + (size_t)l * EMBEDc, ln1_b + (size_t)l * EMBEDc,
                                              h, um_hi, um_lo);
        // ffn1: TERMS=2 + EPI=4 (f1_lo dead)
        k_gemm3<4, 2, 0, 64, 2><<<512, 256, 0, stream>>>(
            um_hi, um_lo, UMLD,
            wf1_hi + (size_t)l * DFFc * UMLD, wf1_lo + (size_t)l * DFFc * UMLD, UMLD,
            UMLD, nullptr, 0, f1_hi, f1_lo, DFFc, bf1 + (size_t)l * DFFc, 16, 4);
        // ffn2: TERMS=2, EPI=6 split-K -> bf16 partials s2a/s2b
        k_gemm3<6, 1, 8, 64, 2><<<512, 256, 0, stream>>>(
            f1_hi, f1_hi, DFFc,
            wf2_hi + (size_t)l * EMBEDc * DFFc, wf2_lo + (size_t)l * EMBEDc * DFFc, DFFc,
            512, nullptr, 0, s2a, nullptr, EMBEDc, nullptr, 4, 8);
        if (l == NLc - 1) {
            k_ln<1><<<NTOK / 8, 256, 0, stream>>>(s2a, s2b, bf2 + (size_t)l * EMBEDc,
                                                  ln2_g + (size_t)l * EMBEDc, ln2_b + (size_t)l * EMBEDc,
                                                  h, um_hi, um_lo);
        } else {
            k_ln<0><<<NTOK / 8, 256, 0, stream>>>(s2a, s2b, bf2 + (size_t)l * EMBEDc,
                                                  ln2_g + (size_t)l * EMBEDc, ln2_b + (size_t)l * EMBEDc,
                                                  h, um_hi, um_lo);
        }
    }

    // final: f = relu(um @ o_w1^T + o_b1) (um cols 0..255 hold h in bf16)
    k_gemm3<1, 1, 0, 64, 3><<<256, 256, 0, stream>>>(
        um_hi, um_lo, UMLD, wo1_hi, wo1_lo, EMBEDc, EMBEDc,
        nullptr, 0, f1_hi, f1_lo, EMBEDc, o_b1, 4, 8);
    k_r<<<NTOK / 64, 256, 0, stream>>>(f1_hi, f1_lo, o_w2, o_b2, r);
    k_dmap<<<NB * Lc, 256, 0, stream>>>(r, (float*)d_out);
}